// Round 1
// baseline (2007.844 us; speedup 1.0000x reference)
//
#include <hip/hip_runtime.h>
#include <hip/hip_bf16.h>

// ---------------- constants ----------------
// B=4, L=2048, D=512, DI=1024, DS=16, DC=4, DTR=32, H=4, DH=128
#define BB 4
#define LL 2048
#define DD 512
#define DI 1024
#define DS 16
#define DTR 32
#define BL (BB*LL)   // 8192

// ---------------- helpers ----------------
__device__ __forceinline__ float geluf(float x) {
    return 0.5f * x * (1.f + erff(x * 0.7071067811865476f));
}

__device__ __forceinline__ void block_reduce_sum2(float& a, float& b, float* sred) {
    // blockDim.x == 256 (4 waves of 64)
    for (int off = 32; off > 0; off >>= 1) {
        a += __shfl_down(a, off);
        b += __shfl_down(b, off);
    }
    const int lane = threadIdx.x & 63, wid = threadIdx.x >> 6;
    if (lane == 0) { sred[wid*2] = a; sred[wid*2+1] = b; }
    __syncthreads();
    a = sred[0] + sred[2] + sred[4] + sred[6];
    b = sred[1] + sred[3] + sred[5] + sred[7];
    __syncthreads();
}

__device__ __forceinline__ float block_reduce_max(float v, float* sred) {
    for (int off = 32; off > 0; off >>= 1) v = fmaxf(v, __shfl_down(v, off));
    const int lane = threadIdx.x & 63, wid = threadIdx.x >> 6;
    if (lane == 0) sred[wid] = v;
    __syncthreads();
    v = fmaxf(fmaxf(sred[0], sred[1]), fmaxf(sred[2], sred[3]));
    __syncthreads();
    return v;
}

__device__ __forceinline__ float block_reduce_sum1(float v, float* sred) {
    for (int off = 32; off > 0; off >>= 1) v += __shfl_down(v, off);
    const int lane = threadIdx.x & 63, wid = threadIdx.x >> 6;
    if (lane == 0) sred[wid] = v;
    __syncthreads();
    v = sred[0] + sred[1] + sred[2] + sred[3];
    __syncthreads();
    return v;
}

// ---------------- tiled f32 GEMM: C[M,N] = A[M,K] * W[N,K]^T (+bias) ----------------
// 128x128 tile, BK=8, 256 threads, 8x8 acc per thread.
__global__ __launch_bounds__(256) void gemm_nt(
    const float* __restrict__ A, const float* __restrict__ W,
    float* __restrict__ C, const float* __restrict__ bias,
    int M, int N, int K, int lda, int ldw, int ldc)
{
    __shared__ float As[8][132];
    __shared__ float Ws[8][132];
    const int tid = threadIdx.x;
    const int bm = blockIdx.y * 128, bn = blockIdx.x * 128;
    const int tx = tid & 15, ty = tid >> 4;
    const int lrow = tid & 127;
    const float* src = (tid < 128) ? (A + (size_t)(bm + lrow) * lda)
                                   : (W + (size_t)(bn + lrow) * ldw);
    float acc[8][8] = {};
    for (int k0 = 0; k0 < K; k0 += 8) {
        float4 r0 = *(const float4*)(src + k0);
        float4 r1 = *(const float4*)(src + k0 + 4);
        __syncthreads();
        float (*dst)[132] = (tid < 128) ? As : Ws;
        dst[0][lrow] = r0.x; dst[1][lrow] = r0.y; dst[2][lrow] = r0.z; dst[3][lrow] = r0.w;
        dst[4][lrow] = r1.x; dst[5][lrow] = r1.y; dst[6][lrow] = r1.z; dst[7][lrow] = r1.w;
        __syncthreads();
#pragma unroll
        for (int kk = 0; kk < 8; ++kk) {
            float a[8], w[8];
            *(float4*)&a[0] = *(const float4*)&As[kk][ty*8];
            *(float4*)&a[4] = *(const float4*)&As[kk][ty*8+4];
            *(float4*)&w[0] = *(const float4*)&Ws[kk][tx*8];
            *(float4*)&w[4] = *(const float4*)&Ws[kk][tx*8+4];
#pragma unroll
            for (int i = 0; i < 8; ++i)
#pragma unroll
                for (int j = 0; j < 8; ++j)
                    acc[i][j] = fmaf(a[i], w[j], acc[i][j]);
        }
    }
    float bj[8];
#pragma unroll
    for (int j = 0; j < 8; ++j) bj[j] = bias ? bias[bn + tx*8 + j] : 0.f;
#pragma unroll
    for (int i = 0; i < 8; ++i) {
        float* cp = C + (size_t)(bm + ty*8 + i) * ldc + bn + tx*8;
        float4 o0 = { acc[i][0]+bj[0], acc[i][1]+bj[1], acc[i][2]+bj[2], acc[i][3]+bj[3] };
        float4 o1 = { acc[i][4]+bj[4], acc[i][5]+bj[5], acc[i][6]+bj[6], acc[i][7]+bj[7] };
        *(float4*)cp     = o0;
        *(float4*)(cp+4) = o1;
    }
}

// ---------------- small per-output-thread GEMM ----------------
// EPI: 0 none, 1 gelu, 2 sigmoid, 3 softplus
template<int EPI>
__global__ __launch_bounds__(256) void small_nt(
    const float* __restrict__ A, const float* __restrict__ W,
    const float* __restrict__ bias, float* __restrict__ C,
    int M, int N, int K, int lda)
{
    const int idx = blockIdx.x * 256 + threadIdx.x;
    if (idx >= M * N) return;
    const int r = idx / N, c = idx - r * N;
    const float* a = A + (size_t)r * lda;
    const float* w = W + (size_t)c * K;
    float acc = 0.f;
    for (int k = 0; k < K; k += 4) {
        float4 av = *(const float4*)(a + k);
        float4 wv = *(const float4*)(w + k);
        acc += av.x*wv.x + av.y*wv.y + av.z*wv.z + av.w*wv.w;
    }
    if (bias) acc += bias[c];
    if (EPI == 1)      acc = geluf(acc);
    else if (EPI == 2) acc = 1.f / (1.f + __expf(-acc));
    else if (EPI == 3) acc = (acc > 20.f) ? acc : log1pf(__expf(acc));
    C[(size_t)r * N + c] = acc;
}

// ---------------- causal depthwise conv (k=4) + SiLU ----------------
__global__ void dwconv_silu(const float* __restrict__ u, const float* __restrict__ cw,
                            const float* __restrict__ cb, float* __restrict__ out)
{
    const int idx = blockIdx.x * 256 + threadIdx.x;   // < BL*DI
    const int c = idx & (DI-1);
    const int row = idx >> 10;        // b*L + t
    const int t = row & (LL-1);
    const float* w = cw + c*4;
    float s = cb[c];
#pragma unroll
    for (int j = 0; j < 4; ++j) {
        const int tt = t - 3 + j;
        if (tt >= 0) s = fmaf(u[(size_t)(row - 3 + j) * DI + c], w[j], s);
    }
    out[idx] = s / (1.f + __expf(-s));   // silu
}

// ---------------- SSM selective scan ----------------
// grid: B * (DI/16) blocks; block 256 = 16 ch * 16 states; lane = chl*16 + s
__global__ __launch_bounds__(256) void ssm_scan(
    const float* __restrict__ delta, const float* __restrict__ uact,
    const float* __restrict__ z, const float* __restrict__ xdbl,
    const float* __restrict__ A_log, const float* __restrict__ ssm_D,
    float* __restrict__ y)
{
    const int tid = threadIdx.x;
    const int s = tid & 15, chl = tid >> 4;
    const int b = blockIdx.x >> 6, cg = blockIdx.x & 63;
    const int ch = cg*16 + chl;
    __shared__ float sd[16][65], su[16][65], sz[16][65], sB[16][65], sC[16][65];
    const float Av = -__expf(A_log[ch*DS + s]);
    const float Dc = ssm_D[ch];
    float h = 0.f;
    const size_t rb = (size_t)b * LL;
    for (int t0 = 0; t0 < LL; t0 += 64) {
        __syncthreads();
        for (int i = tid; i < 1024; i += 256) {
            const int cc = i & 15, tt = i >> 4;
            const size_t r = rb + t0 + tt;
            sd[cc][tt] = delta[r*DI + cg*16 + cc];
            su[cc][tt] = uact [r*DI + cg*16 + cc];
            sz[cc][tt] = z    [r*DI + cg*16 + cc];
            sB[cc][tt] = xdbl[r*64 + 32 + cc];
            sC[cc][tt] = xdbl[r*64 + 48 + cc];
        }
        __syncthreads();
        for (int tl = 0; tl < 64; ++tl) {
            const float d  = sd[chl][tl];
            const float uu = su[chl][tl];
            const float e  = __expf(d * Av);
            h = fmaf(e, h, d * uu * sB[s][tl]);
            float p = h * sC[s][tl];
            p += __shfl_xor(p, 1);
            p += __shfl_xor(p, 2);
            p += __shfl_xor(p, 4);
            p += __shfl_xor(p, 8);
            if (s == 0) {
                const float zz = sz[chl][tl];
                y[(rb + t0 + tl)*DI + ch] = (p + uu*Dc) * (zz / (1.f + __expf(-zz)));
            }
        }
    }
}

// ---------------- ln1 * (1+g) + residual -> ln2 ----------------
__global__ __launch_bounds__(256) void ln_gate_res_ln2(
    const float* __restrict__ x1raw, const float* __restrict__ xres,
    const float* __restrict__ g,
    const float* __restrict__ w1, const float* __restrict__ b1,
    const float* __restrict__ w2, const float* __restrict__ b2,
    float* __restrict__ x2)
{
    __shared__ float sred[8];
    const int row = blockIdx.x;
    const int b = row >> 11;
    const int c = threadIdx.x * 2;
    const size_t base = (size_t)row * DD;
    float2 v = *(const float2*)(x1raw + base + c);
    float s = v.x + v.y, ss = v.x*v.x + v.y*v.y;
    block_reduce_sum2(s, ss, sred);
    float mean = s * (1.f/DD);
    float rs = rsqrtf(fmaxf(ss * (1.f/DD) - mean*mean, 0.f) + 1e-5f);
    float2 xr = *(const float2*)(xres + base + c);
    float y0 = ((v.x - mean)*rs*w1[c]   + b1[c]  ) * (1.f + g[b*DD + c])   + xr.x;
    float y1 = ((v.y - mean)*rs*w1[c+1] + b1[c+1]) * (1.f + g[b*DD + c+1]) + xr.y;
    s = y0 + y1; ss = y0*y0 + y1*y1;
    block_reduce_sum2(s, ss, sred);
    mean = s * (1.f/DD);
    rs = rsqrtf(fmaxf(ss * (1.f/DD) - mean*mean, 0.f) + 1e-5f);
    float2 o;
    o.x = (y0 - mean)*rs*w2[c]   + b2[c];
    o.y = (y1 - mean)*rs*w2[c+1] + b2[c+1];
    *(float2*)(x2 + base + c) = o;
}

// ---------------- x + broadcast(add[b]) -> LN ----------------
__global__ __launch_bounds__(256) void add_bcast_ln(
    const float* __restrict__ xin, const float* __restrict__ addb,
    const float* __restrict__ w, const float* __restrict__ bb,
    float* __restrict__ out)
{
    __shared__ float sred[8];
    const int row = blockIdx.x, b = row >> 11, c = threadIdx.x * 2;
    const size_t base = (size_t)row * DD;
    float2 v = *(const float2*)(xin + base + c);
    v.x += addb[b*DD + c];
    v.y += addb[b*DD + c + 1];
    float s = v.x + v.y, ss = v.x*v.x + v.y*v.y;
    block_reduce_sum2(s, ss, sred);
    float mean = s * (1.f/DD);
    float rs = rsqrtf(fmaxf(ss * (1.f/DD) - mean*mean, 0.f) + 1e-5f);
    float2 o = { (v.x - mean)*rs*w[c] + bb[c], (v.y - mean)*rs*w[c+1] + bb[c+1] };
    *(float2*)(out + base + c) = o;
}

// ---------------- cross-attention (q_len = 1) ----------------
// grid = B*H blocks; kv layout [BL, 1024]: cols 0..511 = k, 512..1023 = v
__global__ __launch_bounds__(256) void attn_kernel(
    const float* __restrict__ q, const float* __restrict__ kv, float* __restrict__ o)
{
    const int b = blockIdx.x >> 2, h = blockIdx.x & 3;
    const int tid = threadIdx.x;
    __shared__ float sc[LL];
    __shared__ float sq[128];
    __shared__ float sred[8];
    __shared__ float opart[2][128];
    if (tid < 128) sq[tid] = q[b*DD + h*128 + tid];
    __syncthreads();
    float lmax = -1e30f;
    for (int t = tid; t < LL; t += 256) {
        const float* kr = kv + ((size_t)(b*LL + t)) * 1024 + h*128;
        float dot = 0.f;
        for (int d = 0; d < 128; d += 4) {
            float4 k4 = *(const float4*)(kr + d);
            dot += sq[d]*k4.x + sq[d+1]*k4.y + sq[d+2]*k4.z + sq[d+3]*k4.w;
        }
        dot *= 0.088388347648318447f;  // 1/sqrt(128)
        sc[t] = dot;
        lmax = fmaxf(lmax, dot);
    }
    const float m = block_reduce_max(lmax, sred);
    float lsum = 0.f;
    for (int t = tid; t < LL; t += 256) {
        const float e = __expf(sc[t] - m);
        sc[t] = e;
        lsum += e;
    }
    const float inv = 1.f / block_reduce_sum1(lsum, sred);
    const int dh = tid & 127, td = tid >> 7;
    float acc = 0.f;
    for (int t = td; t < LL; t += 2)
        acc = fmaf(sc[t], kv[((size_t)(b*LL + t))*1024 + 512 + h*128 + dh], acc);
    opart[td][dh] = acc;
    __syncthreads();
    if (tid < 128) o[b*DD + h*128 + tid] = (opart[0][tid] + opart[1][tid]) * inv;
}

// ---------------- grouped temporal conv (k=3,pad=1,groups=4) + BN + GELU + residual ----------------
// grid: (L/32, B*4); block 256 = 128 o * 2 t-halves; each thread 16 t's
__global__ __launch_bounds__(256) void teconv_bn_gelu(
    const float* __restrict__ x3, const float* __restrict__ tw,
    const float* __restrict__ tb,
    const float* __restrict__ bng, const float* __restrict__ bnb,
    const float* __restrict__ bnm, const float* __restrict__ bnv,
    float* __restrict__ out)
{
    const int b = blockIdx.y >> 2, gg = blockIdx.y & 3;
    const int t0 = blockIdx.x * 32;
    const int tid = threadIdx.x;
    const int o = tid & 127, th = tid >> 7;
    __shared__ float xs[16][35];
    __shared__ float ws[128][49];
    float acc[16] = {};
    const int og = gg*128 + o;
    for (int i0 = 0; i0 < 128; i0 += 16) {
        __syncthreads();
        for (int i = tid; i < 16*34; i += 256) {
            const int ii = i / 34, tt = i - ii*34;
            const int t = t0 - 1 + tt;
            xs[ii][tt] = (t >= 0 && t < LL)
                       ? x3[((size_t)b*LL + t)*DD + gg*128 + i0 + ii] : 0.f;
        }
        for (int i = tid; i < 128*48; i += 256) {
            const int oo = i / 48, cc = i - oo*48;
            ws[oo][cc] = tw[(size_t)(gg*128 + oo)*384 + i0*3 + cc];
        }
        __syncthreads();
#pragma unroll
        for (int ii = 0; ii < 16; ++ii) {
            const float w0 = ws[o][ii*3+0], w1 = ws[o][ii*3+1], w2 = ws[o][ii*3+2];
            float xv[18];
#pragma unroll
            for (int j = 0; j < 18; ++j) xv[j] = xs[ii][th*16 + j];
#pragma unroll
            for (int j = 0; j < 16; ++j)
                acc[j] = fmaf(w0, xv[j], fmaf(w1, xv[j+1], fmaf(w2, xv[j+2], acc[j])));
        }
    }
    const float scale = bng[og] * rsqrtf(bnv[og] + 1e-5f);
    const float shift = bnb[og] - bnm[og]*scale;
    const float cbv = tb[og];
#pragma unroll
    for (int j = 0; j < 16; ++j) {
        const int t = t0 + th*16 + j;
        const float v = (acc[j] + cbv)*scale + shift;
        const size_t oi = ((size_t)b*LL + t)*DD + og;
        out[oi] = x3[oi] + geluf(v);
    }
}

// ---------------- launch ----------------
extern "C" void kernel_launch(void* const* d_in, const int* in_sizes, int n_in,
                              void* d_out, int out_size, void* d_ws, size_t ws_size,
                              hipStream_t stream)
{
    (void)in_sizes; (void)n_in; (void)out_size; (void)ws_size;
    const float* x         = (const float*)d_in[0];
    const float* freq      = (const float*)d_in[1];
    const float* in_proj_w = (const float*)d_in[2];
    const float* conv_w    = (const float*)d_in[3];
    const float* conv_b    = (const float*)d_in[4];
    const float* x_proj_w  = (const float*)d_in[5];
    const float* dt_proj_w = (const float*)d_in[6];
    const float* dt_proj_b = (const float*)d_in[7];
    const float* A_log     = (const float*)d_in[8];
    const float* ssm_D     = (const float*)d_in[9];
    const float* out_proj_w= (const float*)d_in[10];
    const float* fg_w1     = (const float*)d_in[11];
    const float* fg_b1     = (const float*)d_in[12];
    const float* fg_w2     = (const float*)d_in[13];
    const float* fg_b2     = (const float*)d_in[14];
    const float* attn_in_w = (const float*)d_in[15];
    const float* attn_in_b = (const float*)d_in[16];
    const float* attn_out_w= (const float*)d_in[17];
    const float* attn_out_b= (const float*)d_in[18];
    const float* te_w      = (const float*)d_in[19];
    const float* te_b      = (const float*)d_in[20];
    const float* bn_g      = (const float*)d_in[21];
    const float* bn_b      = (const float*)d_in[22];
    const float* bn_m      = (const float*)d_in[23];
    const float* bn_v      = (const float*)d_in[24];
    const float* ln1w = (const float*)d_in[25];
    const float* ln1b = (const float*)d_in[26];
    const float* ln2w = (const float*)d_in[27];
    const float* ln2b = (const float*)d_in[28];
    const float* ln3w = (const float*)d_in[29];
    const float* ln3b = (const float*)d_in[30];
    float* out = (float*)d_out;

    // ---- workspace layout (lifetime-overlapped), total 136.4 MB ----
    float* ws = (float*)d_ws;
    const size_t SEG = 8388608;                 // 8192*1024
    float* S1 = ws;                             // u_raw -> delta
    float* S2 = ws + SEG;                       // z_raw -> x1 | x3
    float* S3 = ws + 2*SEG;                     // u_act -> x2
    float* S4 = ws + 3*SEG;                     // y -> kv
    float* xdbl = ws + 4*SEG;                   // 524288
    float* sm   = ws + 4*SEG + 524288;          // small scalars
    float* u_raw = S1;  float* deltab = S1;
    float* z_raw = S2;  float* x1 = S2;  float* x3 = S2 + 4194304;
    float* u_act = S3;  float* x2 = S3;
    float* ybuf  = S4;  float* kv = S4;
    float* hidden = sm;        // 4096
    float* g  = sm + 4096;     // 2048
    float* qb = sm + 6144;     // 2048
    float* ob = sm + 8192;     // 2048
    float* ao = sm + 10240;    // 2048

    dim3 blk(256);

    // 1) in_proj: u and z halves
    gemm_nt<<<dim3(8,64), blk, 0, stream>>>(x, in_proj_w,          u_raw, nullptr, BL, DI, DD, DD, DD, DI);
    gemm_nt<<<dim3(8,64), blk, 0, stream>>>(x, in_proj_w + 524288, z_raw, nullptr, BL, DI, DD, DD, DD, DI);
    // 2) causal depthwise conv + silu
    dwconv_silu<<<(BL*DI)/256, blk, 0, stream>>>(u_raw, conv_w, conv_b, u_act);
    // 3) x_dbl = u @ x_proj^T
    small_nt<0><<<(BL*64)/256, blk, 0, stream>>>(u_act, x_proj_w, nullptr, xdbl, BL, 64, DI, DI);
    // 4) delta = softplus(dt @ dt_proj^T + b)
    small_nt<3><<<(BL*DI)/256, blk, 0, stream>>>(xdbl, dt_proj_w, dt_proj_b, deltab, BL, DI, DTR, 64);
    // 5) selective scan (+ *silu(z) + u*D fused)
    ssm_scan<<<BB*(DI/16), blk, 0, stream>>>(deltab, u_act, z_raw, xdbl, A_log, ssm_D, ybuf);
    // 6) out_proj
    gemm_nt<<<dim3(4,64), blk, 0, stream>>>(ybuf, out_proj_w, x1, nullptr, BL, DD, DI, DI, DI, DD);
    // 7) freq gate MLP
    small_nt<1><<<16, blk, 0, stream>>>(freq,   fg_w1, fg_b1, hidden, BB, 2*DD, DD, DD);
    small_nt<2><<<8,  blk, 0, stream>>>(hidden, fg_w2, fg_b2, g,      BB, DD, 2*DD, 2*DD);
    // 8) ln1 * (1+g) + residual -> ln2
    ln_gate_res_ln2<<<BL, blk, 0, stream>>>(x1, x, g, ln1w, ln1b, ln2w, ln2b, x2);
    // 9) attention: q, k|v GEMM, softmax-weighted sum, out proj
    small_nt<0><<<8, blk, 0, stream>>>(freq, attn_in_w, attn_in_b, qb, BB, DD, DD, DD);
    gemm_nt<<<dim3(8,64), blk, 0, stream>>>(x2, attn_in_w + 262144, kv, attn_in_b + 512, BL, 2*DD, DD, DD, DD, 2*DD);
    attn_kernel<<<BB*4, blk, 0, stream>>>(qb, kv, ob);
    small_nt<0><<<8, blk, 0, stream>>>(ob, attn_out_w, attn_out_b, ao, BB, DD, DD, DD);
    // 10) ln3(x2 + attn_broadcast)
    add_bcast_ln<<<BL, blk, 0, stream>>>(x2, ao, ln3w, ln3b, x3);
    // 11) temporal conv + BN + gelu + residual
    teconv_bn_gelu<<<dim3(LL/32, BB*4), blk, 0, stream>>>(x3, te_w, te_b, bn_g, bn_b, bn_m, bn_v, out);
}

// Round 2
// 1549.421 us; speedup vs baseline: 1.2959x; 1.2959x over previous
//
#include <hip/hip_runtime.h>
#include <hip/hip_bf16.h>

// ---------------- constants ----------------
// B=4, L=2048, D=512, DI=1024, DS=16, DC=4, DTR=32, H=4, DH=128
#define BB 4
#define LL 2048
#define DD 512
#define DI 1024
#define DS 16
#define DTR 32
#define BL (BB*LL)   // 8192
#define NSEG 32
#define TSEG 64      // NSEG*TSEG == LL

// ---------------- helpers ----------------
__device__ __forceinline__ float geluf(float x) {
    return 0.5f * x * (1.f + erff(x * 0.7071067811865476f));
}

__device__ __forceinline__ void block_reduce_sum2(float& a, float& b, float* sred) {
    // blockDim.x == 256 (4 waves of 64)
    for (int off = 32; off > 0; off >>= 1) {
        a += __shfl_down(a, off);
        b += __shfl_down(b, off);
    }
    const int lane = threadIdx.x & 63, wid = threadIdx.x >> 6;
    if (lane == 0) { sred[wid*2] = a; sred[wid*2+1] = b; }
    __syncthreads();
    a = sred[0] + sred[2] + sred[4] + sred[6];
    b = sred[1] + sred[3] + sred[5] + sred[7];
    __syncthreads();
}

__device__ __forceinline__ float block_reduce_max(float v, float* sred) {
    for (int off = 32; off > 0; off >>= 1) v = fmaxf(v, __shfl_down(v, off));
    const int lane = threadIdx.x & 63, wid = threadIdx.x >> 6;
    if (lane == 0) sred[wid] = v;
    __syncthreads();
    v = fmaxf(fmaxf(sred[0], sred[1]), fmaxf(sred[2], sred[3]));
    __syncthreads();
    return v;
}

__device__ __forceinline__ float block_reduce_sum1(float v, float* sred) {
    for (int off = 32; off > 0; off >>= 1) v += __shfl_down(v, off);
    const int lane = threadIdx.x & 63, wid = threadIdx.x >> 6;
    if (lane == 0) sred[wid] = v;
    __syncthreads();
    v = sred[0] + sred[1] + sred[2] + sred[3];
    __syncthreads();
    return v;
}

// ---------------- tiled f32 GEMM: C[M,N] = A[M,K] * W[N,K]^T (+bias) ----------------
// 128x128 tile, BK=8, 256 threads, 8x8 acc per thread.
__global__ __launch_bounds__(256) void gemm_nt(
    const float* __restrict__ A, const float* __restrict__ W,
    float* __restrict__ C, const float* __restrict__ bias,
    int M, int N, int K, int lda, int ldw, int ldc)
{
    __shared__ float As[8][132];
    __shared__ float Ws[8][132];
    const int tid = threadIdx.x;
    const int bm = blockIdx.y * 128, bn = blockIdx.x * 128;
    const int tx = tid & 15, ty = tid >> 4;
    const int lrow = tid & 127;
    const float* src = (tid < 128) ? (A + (size_t)(bm + lrow) * lda)
                                   : (W + (size_t)(bn + lrow) * ldw);
    float acc[8][8] = {};
    for (int k0 = 0; k0 < K; k0 += 8) {
        float4 r0 = *(const float4*)(src + k0);
        float4 r1 = *(const float4*)(src + k0 + 4);
        __syncthreads();
        float (*dst)[132] = (tid < 128) ? As : Ws;
        dst[0][lrow] = r0.x; dst[1][lrow] = r0.y; dst[2][lrow] = r0.z; dst[3][lrow] = r0.w;
        dst[4][lrow] = r1.x; dst[5][lrow] = r1.y; dst[6][lrow] = r1.z; dst[7][lrow] = r1.w;
        __syncthreads();
#pragma unroll
        for (int kk = 0; kk < 8; ++kk) {
            float a[8], w[8];
            *(float4*)&a[0] = *(const float4*)&As[kk][ty*8];
            *(float4*)&a[4] = *(const float4*)&As[kk][ty*8+4];
            *(float4*)&w[0] = *(const float4*)&Ws[kk][tx*8];
            *(float4*)&w[4] = *(const float4*)&Ws[kk][tx*8+4];
#pragma unroll
            for (int i = 0; i < 8; ++i)
#pragma unroll
                for (int j = 0; j < 8; ++j)
                    acc[i][j] = fmaf(a[i], w[j], acc[i][j]);
        }
    }
    float bj[8];
#pragma unroll
    for (int j = 0; j < 8; ++j) bj[j] = bias ? bias[bn + tx*8 + j] : 0.f;
#pragma unroll
    for (int i = 0; i < 8; ++i) {
        float* cp = C + (size_t)(bm + ty*8 + i) * ldc + bn + tx*8;
        float4 o0 = { acc[i][0]+bj[0], acc[i][1]+bj[1], acc[i][2]+bj[2], acc[i][3]+bj[3] };
        float4 o1 = { acc[i][4]+bj[4], acc[i][5]+bj[5], acc[i][6]+bj[6], acc[i][7]+bj[7] };
        *(float4*)cp     = o0;
        *(float4*)(cp+4) = o1;
    }
}

// ---------------- small per-output-thread GEMM ----------------
// EPI: 0 none, 1 gelu, 2 sigmoid, 3 softplus
template<int EPI>
__global__ __launch_bounds__(256) void small_nt(
    const float* __restrict__ A, const float* __restrict__ W,
    const float* __restrict__ bias, float* __restrict__ C,
    int M, int N, int K, int lda)
{
    const int idx = blockIdx.x * 256 + threadIdx.x;
    if (idx >= M * N) return;
    const int r = idx / N, c = idx - r * N;
    const float* a = A + (size_t)r * lda;
    const float* w = W + (size_t)c * K;
    float acc = 0.f;
    for (int k = 0; k < K; k += 4) {
        float4 av = *(const float4*)(a + k);
        float4 wv = *(const float4*)(w + k);
        acc += av.x*wv.x + av.y*wv.y + av.z*wv.z + av.w*wv.w;
    }
    if (bias) acc += bias[c];
    if (EPI == 1)      acc = geluf(acc);
    else if (EPI == 2) acc = 1.f / (1.f + __expf(-acc));
    else if (EPI == 3) acc = (acc > 20.f) ? acc : log1pf(__expf(acc));
    C[(size_t)r * N + c] = acc;
}

// ---------------- causal depthwise conv (k=4) + SiLU ----------------
__global__ void dwconv_silu(const float* __restrict__ u, const float* __restrict__ cw,
                            const float* __restrict__ cb, float* __restrict__ out)
{
    const int idx = blockIdx.x * 256 + threadIdx.x;   // < BL*DI
    const int c = idx & (DI-1);
    const int row = idx >> 10;        // b*L + t
    const int t = row & (LL-1);
    const float* w = cw + c*4;
    float s = cb[c];
#pragma unroll
    for (int j = 0; j < 4; ++j) {
        const int tt = t - 3 + j;
        if (tt >= 0) s = fmaf(u[(size_t)(row - 3 + j) * DI + c], w[j], s);
    }
    out[idx] = s / (1.f + __expf(-s));   // silu
}

// ---------------- SSM chunked scan ----------------
// Linear recurrence h_t = a_t h_{t-1} + b_t with a_t = exp(delta_t*A_s),
// b_t = delta_t*u_t*B_{t,s}. Segment transfer coeff = exp(A_s * sum(delta)).
// pass1: per (b,seg,ch) thread, local scan (h_in = 0) -> hseg, dsum.
__global__ __launch_bounds__(256) void ssm_pass1(
    const float* __restrict__ delta, const float* __restrict__ uact,
    const float* __restrict__ xdbl, const float* __restrict__ A_log,
    float* __restrict__ hseg, float* __restrict__ dsum)
{
    const int tid = threadIdx.x;
    const int ch = blockIdx.x * 256 + tid;
    const int seg = blockIdx.y, b = blockIdx.z;
    const size_t rb = (size_t)b * LL + seg * TSEG;   // first row of segment
    __shared__ float sB[TSEG][16];
    for (int i = tid; i < TSEG*16; i += 256) {
        const int tt = i >> 4, s = i & 15;
        sB[tt][s] = xdbl[(rb + tt)*64 + 32 + s];
    }
    float Av[16];
#pragma unroll
    for (int s = 0; s < 16; ++s) Av[s] = -__expf(A_log[ch*16 + s]);
    __syncthreads();
    float h[16] = {};
    float ds = 0.f;
    float d  = delta[rb*DI + ch];
    float uu = uact [rb*DI + ch];
    for (int t = 0; t < TSEG; ++t) {
        const int tn = (t + 1 < TSEG) ? t + 1 : t;
        const float dn = delta[(rb + tn)*DI + ch];
        const float un = uact [(rb + tn)*DI + ch];
        ds += d;
        const float du = d * uu;
#pragma unroll
        for (int s = 0; s < 16; ++s) {
            const float a = __expf(d * Av[s]);
            h[s] = fmaf(a, h[s], du * sB[t][s]);
        }
        d = dn; uu = un;
    }
    float* hp = hseg + (((size_t)b*NSEG + seg)*DI + ch)*16;
    float4 o0 = {h[0],h[1],h[2],h[3]},   o1 = {h[4],h[5],h[6],h[7]};
    float4 o2 = {h[8],h[9],h[10],h[11]}, o3 = {h[12],h[13],h[14],h[15]};
    *(float4*)(hp)    = o0; *(float4*)(hp+4)  = o1;
    *(float4*)(hp+8)  = o2; *(float4*)(hp+12) = o3;
    dsum[((size_t)b*NSEG + seg)*DI + ch] = ds;
}

// inter-segment scan, in place: hseg[b,seg,ch,s] -> h_in entering each segment
__global__ __launch_bounds__(256) void ssm_seg_scan(
    const float* __restrict__ A_log, const float* __restrict__ dsum,
    float* __restrict__ hseg)
{
    const int idx = blockIdx.x * 256 + threadIdx.x;   // (b*DI+ch)*16+s
    const int s = idx & 15;
    const int bc = idx >> 4;
    const int ch = bc & (DI-1);
    const int b = bc >> 10;
    const float Av = -__expf(A_log[ch*16 + s]);
    float g = 0.f;
    for (int seg = 0; seg < NSEG; ++seg) {
        const size_t soff = ((size_t)b*NSEG + seg)*DI + ch;
        const float hloc = hseg[soff*16 + s];
        const float a = __expf(Av * dsum[soff]);
        hseg[soff*16 + s] = g;
        g = fmaf(a, g, hloc);
    }
}

// pass2: seeded local scan + C-dot + u*D + silu(z) gate -> y
__global__ __launch_bounds__(256) void ssm_pass2(
    const float* __restrict__ delta, const float* __restrict__ uact,
    const float* __restrict__ z, const float* __restrict__ xdbl,
    const float* __restrict__ A_log, const float* __restrict__ ssm_D,
    const float* __restrict__ hin, float* __restrict__ y)
{
    const int tid = threadIdx.x;
    const int ch = blockIdx.x * 256 + tid;
    const int seg = blockIdx.y, b = blockIdx.z;
    const size_t rb = (size_t)b * LL + seg * TSEG;
    __shared__ float sB[TSEG][16], sC[TSEG][16];
    for (int i = tid; i < TSEG*16; i += 256) {
        const int tt = i >> 4, s = i & 15;
        sB[tt][s] = xdbl[(rb + tt)*64 + 32 + s];
        sC[tt][s] = xdbl[(rb + tt)*64 + 48 + s];
    }
    float Av[16];
#pragma unroll
    for (int s = 0; s < 16; ++s) Av[s] = -__expf(A_log[ch*16 + s]);
    float h[16];
    const float* hp = hin + (((size_t)b*NSEG + seg)*DI + ch)*16;
#pragma unroll
    for (int s = 0; s < 16; ++s) h[s] = hp[s];
    const float Dc = ssm_D[ch];
    __syncthreads();
    float d  = delta[rb*DI + ch];
    float uu = uact [rb*DI + ch];
    float zz = z    [rb*DI + ch];
    for (int t = 0; t < TSEG; ++t) {
        const int tn = (t + 1 < TSEG) ? t + 1 : t;
        const float dn = delta[(rb + tn)*DI + ch];
        const float un = uact [(rb + tn)*DI + ch];
        const float zn = z    [(rb + tn)*DI + ch];
        const float du = d * uu;
        float p = 0.f;
#pragma unroll
        for (int s = 0; s < 16; ++s) {
            const float a = __expf(d * Av[s]);
            h[s] = fmaf(a, h[s], du * sB[t][s]);
            p = fmaf(h[s], sC[t][s], p);
        }
        const float sil = zz / (1.f + __expf(-zz));
        y[(rb + t)*DI + ch] = (p + uu*Dc) * sil;
        d = dn; uu = un; zz = zn;
    }
}

// ---------------- ln1 * (1+g) + residual -> ln2 ----------------
__global__ __launch_bounds__(256) void ln_gate_res_ln2(
    const float* __restrict__ x1raw, const float* __restrict__ xres,
    const float* __restrict__ g,
    const float* __restrict__ w1, const float* __restrict__ b1,
    const float* __restrict__ w2, const float* __restrict__ b2,
    float* __restrict__ x2)
{
    __shared__ float sred[8];
    const int row = blockIdx.x;
    const int b = row >> 11;
    const int c = threadIdx.x * 2;
    const size_t base = (size_t)row * DD;
    float2 v = *(const float2*)(x1raw + base + c);
    float s = v.x + v.y, ss = v.x*v.x + v.y*v.y;
    block_reduce_sum2(s, ss, sred);
    float mean = s * (1.f/DD);
    float rs = rsqrtf(fmaxf(ss * (1.f/DD) - mean*mean, 0.f) + 1e-5f);
    float2 xr = *(const float2*)(xres + base + c);
    float y0 = ((v.x - mean)*rs*w1[c]   + b1[c]  ) * (1.f + g[b*DD + c])   + xr.x;
    float y1 = ((v.y - mean)*rs*w1[c+1] + b1[c+1]) * (1.f + g[b*DD + c+1]) + xr.y;
    s = y0 + y1; ss = y0*y0 + y1*y1;
    block_reduce_sum2(s, ss, sred);
    mean = s * (1.f/DD);
    rs = rsqrtf(fmaxf(ss * (1.f/DD) - mean*mean, 0.f) + 1e-5f);
    float2 o;
    o.x = (y0 - mean)*rs*w2[c]   + b2[c];
    o.y = (y1 - mean)*rs*w2[c+1] + b2[c+1];
    *(float2*)(x2 + base + c) = o;
}

// ---------------- x + broadcast(add[b]) -> LN ----------------
__global__ __launch_bounds__(256) void add_bcast_ln(
    const float* __restrict__ xin, const float* __restrict__ addb,
    const float* __restrict__ w, const float* __restrict__ bb,
    float* __restrict__ out)
{
    __shared__ float sred[8];
    const int row = blockIdx.x, b = row >> 11, c = threadIdx.x * 2;
    const size_t base = (size_t)row * DD;
    float2 v = *(const float2*)(xin + base + c);
    v.x += addb[b*DD + c];
    v.y += addb[b*DD + c + 1];
    float s = v.x + v.y, ss = v.x*v.x + v.y*v.y;
    block_reduce_sum2(s, ss, sred);
    float mean = s * (1.f/DD);
    float rs = rsqrtf(fmaxf(ss * (1.f/DD) - mean*mean, 0.f) + 1e-5f);
    float2 o = { (v.x - mean)*rs*w[c] + bb[c], (v.y - mean)*rs*w[c+1] + bb[c+1] };
    *(float2*)(out + base + c) = o;
}

// ---------------- cross-attention (q_len = 1) ----------------
// grid = B*H blocks; kv layout [BL, 1024]: cols 0..511 = k, 512..1023 = v
__global__ __launch_bounds__(256) void attn_kernel(
    const float* __restrict__ q, const float* __restrict__ kv, float* __restrict__ o)
{
    const int b = blockIdx.x >> 2, h = blockIdx.x & 3;
    const int tid = threadIdx.x;
    __shared__ float sc[LL];
    __shared__ float sq[128];
    __shared__ float sred[8];
    __shared__ float opart[2][128];
    if (tid < 128) sq[tid] = q[b*DD + h*128 + tid];
    __syncthreads();
    float lmax = -1e30f;
    for (int t = tid; t < LL; t += 256) {
        const float* kr = kv + ((size_t)(b*LL + t)) * 1024 + h*128;
        float dot = 0.f;
        for (int d = 0; d < 128; d += 4) {
            float4 k4 = *(const float4*)(kr + d);
            dot += sq[d]*k4.x + sq[d+1]*k4.y + sq[d+2]*k4.z + sq[d+3]*k4.w;
        }
        dot *= 0.088388347648318447f;  // 1/sqrt(128)
        sc[t] = dot;
        lmax = fmaxf(lmax, dot);
    }
    const float m = block_reduce_max(lmax, sred);
    float lsum = 0.f;
    for (int t = tid; t < LL; t += 256) {
        const float e = __expf(sc[t] - m);
        sc[t] = e;
        lsum += e;
    }
    const float inv = 1.f / block_reduce_sum1(lsum, sred);
    const int dh = tid & 127, td = tid >> 7;
    float acc = 0.f;
    for (int t = td; t < LL; t += 2)
        acc = fmaf(sc[t], kv[((size_t)(b*LL + t))*1024 + 512 + h*128 + dh], acc);
    opart[td][dh] = acc;
    __syncthreads();
    if (tid < 128) o[b*DD + h*128 + tid] = (opart[0][tid] + opart[1][tid]) * inv;
}

// ---------------- grouped temporal conv (k=3,pad=1,groups=4) + BN + GELU + residual ----------------
// grid: (L/32, B*4); block 256 = 128 o * 2 t-halves; each thread 16 t's
__global__ __launch_bounds__(256) void teconv_bn_gelu(
    const float* __restrict__ x3, const float* __restrict__ tw,
    const float* __restrict__ tb,
    const float* __restrict__ bng, const float* __restrict__ bnb,
    const float* __restrict__ bnm, const float* __restrict__ bnv,
    float* __restrict__ out)
{
    const int b = blockIdx.y >> 2, gg = blockIdx.y & 3;
    const int t0 = blockIdx.x * 32;
    const int tid = threadIdx.x;
    const int o = tid & 127, th = tid >> 7;
    __shared__ float xs[16][35];
    __shared__ float ws[128][49];
    float acc[16] = {};
    const int og = gg*128 + o;
    for (int i0 = 0; i0 < 128; i0 += 16) {
        __syncthreads();
        for (int i = tid; i < 16*34; i += 256) {
            const int ii = i / 34, tt = i - ii*34;
            const int t = t0 - 1 + tt;
            xs[ii][tt] = (t >= 0 && t < LL)
                       ? x3[((size_t)b*LL + t)*DD + gg*128 + i0 + ii] : 0.f;
        }
        for (int i = tid; i < 128*48; i += 256) {
            const int oo = i / 48, cc = i - oo*48;
            ws[oo][cc] = tw[(size_t)(gg*128 + oo)*384 + i0*3 + cc];
        }
        __syncthreads();
#pragma unroll
        for (int ii = 0; ii < 16; ++ii) {
            const float w0 = ws[o][ii*3+0], w1 = ws[o][ii*3+1], w2 = ws[o][ii*3+2];
            float xv[18];
#pragma unroll
            for (int j = 0; j < 18; ++j) xv[j] = xs[ii][th*16 + j];
#pragma unroll
            for (int j = 0; j < 16; ++j)
                acc[j] = fmaf(w0, xv[j], fmaf(w1, xv[j+1], fmaf(w2, xv[j+2], acc[j])));
        }
    }
    const float scale = bng[og] * rsqrtf(bnv[og] + 1e-5f);
    const float shift = bnb[og] - bnm[og]*scale;
    const float cbv = tb[og];
#pragma unroll
    for (int j = 0; j < 16; ++j) {
        const int t = t0 + th*16 + j;
        const float v = (acc[j] + cbv)*scale + shift;
        const size_t oi = ((size_t)b*LL + t)*DD + og;
        out[oi] = x3[oi] + geluf(v);
    }
}

// ---------------- launch ----------------
extern "C" void kernel_launch(void* const* d_in, const int* in_sizes, int n_in,
                              void* d_out, int out_size, void* d_ws, size_t ws_size,
                              hipStream_t stream)
{
    (void)in_sizes; (void)n_in; (void)out_size; (void)ws_size;
    const float* x         = (const float*)d_in[0];
    const float* freq      = (const float*)d_in[1];
    const float* in_proj_w = (const float*)d_in[2];
    const float* conv_w    = (const float*)d_in[3];
    const float* conv_b    = (const float*)d_in[4];
    const float* x_proj_w  = (const float*)d_in[5];
    const float* dt_proj_w = (const float*)d_in[6];
    const float* dt_proj_b = (const float*)d_in[7];
    const float* A_log     = (const float*)d_in[8];
    const float* ssm_D     = (const float*)d_in[9];
    const float* out_proj_w= (const float*)d_in[10];
    const float* fg_w1     = (const float*)d_in[11];
    const float* fg_b1     = (const float*)d_in[12];
    const float* fg_w2     = (const float*)d_in[13];
    const float* fg_b2     = (const float*)d_in[14];
    const float* attn_in_w = (const float*)d_in[15];
    const float* attn_in_b = (const float*)d_in[16];
    const float* attn_out_w= (const float*)d_in[17];
    const float* attn_out_b= (const float*)d_in[18];
    const float* te_w      = (const float*)d_in[19];
    const float* te_b      = (const float*)d_in[20];
    const float* bn_g      = (const float*)d_in[21];
    const float* bn_b      = (const float*)d_in[22];
    const float* bn_m      = (const float*)d_in[23];
    const float* bn_v      = (const float*)d_in[24];
    const float* ln1w = (const float*)d_in[25];
    const float* ln1b = (const float*)d_in[26];
    const float* ln2w = (const float*)d_in[27];
    const float* ln2b = (const float*)d_in[28];
    const float* ln3w = (const float*)d_in[29];
    const float* ln3b = (const float*)d_in[30];
    float* out = (float*)d_out;

    // ---- workspace layout (lifetime-overlapped), total ~145 MB ----
    float* ws = (float*)d_ws;
    const size_t SEG = 8388608;                 // 8192*1024
    float* S1 = ws;                             // u_raw -> delta
    float* S2 = ws + SEG;                       // z_raw -> x1 | x3
    float* S3 = ws + 2*SEG;                     // u_act -> x2
    float* S4 = ws + 3*SEG;                     // y -> kv
    float* xdbl = ws + 4*SEG;                   // 524288
    float* sm   = ws + 4*SEG + 524288;          // small scalars (16384)
    float* hseg = sm + 16384;                   // 4*32*1024*16 = 2097152 floats
    float* dsum = hseg + 2097152;               // 4*32*1024   = 131072 floats
    float* u_raw = S1;  float* deltab = S1;
    float* z_raw = S2;  float* x1 = S2;  float* x3 = S2 + 4194304;
    float* u_act = S3;  float* x2 = S3;
    float* ybuf  = S4;  float* kv = S4;
    float* hidden = sm;        // 4096
    float* g  = sm + 4096;     // 2048
    float* qb = sm + 6144;     // 2048
    float* ob = sm + 8192;     // 2048
    float* ao = sm + 10240;    // 2048

    dim3 blk(256);

    // 1) in_proj: u and z halves
    gemm_nt<<<dim3(8,64), blk, 0, stream>>>(x, in_proj_w,          u_raw, nullptr, BL, DI, DD, DD, DD, DI);
    gemm_nt<<<dim3(8,64), blk, 0, stream>>>(x, in_proj_w + 524288, z_raw, nullptr, BL, DI, DD, DD, DD, DI);
    // 2) causal depthwise conv + silu
    dwconv_silu<<<(BL*DI)/256, blk, 0, stream>>>(u_raw, conv_w, conv_b, u_act);
    // 3) x_dbl = u @ x_proj^T
    small_nt<0><<<(BL*64)/256, blk, 0, stream>>>(u_act, x_proj_w, nullptr, xdbl, BL, 64, DI, DI);
    // 4) delta = softplus(dt @ dt_proj^T + b)
    small_nt<3><<<(BL*DI)/256, blk, 0, stream>>>(xdbl, dt_proj_w, dt_proj_b, deltab, BL, DI, DTR, 64);
    // 5) selective scan, chunked: local scans -> inter-segment scan -> seeded scans
    ssm_pass1<<<dim3(4, NSEG, BB), blk, 0, stream>>>(deltab, u_act, xdbl, A_log, hseg, dsum);
    ssm_seg_scan<<<256, blk, 0, stream>>>(A_log, dsum, hseg);
    ssm_pass2<<<dim3(4, NSEG, BB), blk, 0, stream>>>(deltab, u_act, z_raw, xdbl, A_log, ssm_D, hseg, ybuf);
    // 6) out_proj
    gemm_nt<<<dim3(4,64), blk, 0, stream>>>(ybuf, out_proj_w, x1, nullptr, BL, DD, DI, DI, DI, DD);
    // 7) freq gate MLP
    small_nt<1><<<16, blk, 0, stream>>>(freq,   fg_w1, fg_b1, hidden, BB, 2*DD, DD, DD);
    small_nt<2><<<8,  blk, 0, stream>>>(hidden, fg_w2, fg_b2, g,      BB, DD, 2*DD, 2*DD);
    // 8) ln1 * (1+g) + residual -> ln2
    ln_gate_res_ln2<<<BL, blk, 0, stream>>>(x1, x, g, ln1w, ln1b, ln2w, ln2b, x2);
    // 9) attention: q, k|v GEMM, softmax-weighted sum, out proj
    small_nt<0><<<8, blk, 0, stream>>>(freq, attn_in_w, attn_in_b, qb, BB, DD, DD, DD);
    gemm_nt<<<dim3(8,64), blk, 0, stream>>>(x2, attn_in_w + 262144, kv, attn_in_b + 512, BL, 2*DD, DD, DD, DD, 2*DD);
    attn_kernel<<<BB*4, blk, 0, stream>>>(qb, kv, ob);
    small_nt<0><<<8, blk, 0, stream>>>(ob, attn_out_w, attn_out_b, ao, BB, DD, DD, DD);
    // 10) ln3(x2 + attn_broadcast)
    add_bcast_ln<<<BL, blk, 0, stream>>>(x2, ao, ln3w, ln3b, x3);
    // 11) temporal conv + BN + gelu + residual
    teconv_bn_gelu<<<dim3(LL/32, BB*4), blk, 0, stream>>>(x3, te_w, te_b, bn_g, bn_b, bn_m, bn_v, out);
}

// Round 3
// 1162.883 us; speedup vs baseline: 1.7266x; 1.3324x over previous
//
#include <hip/hip_runtime.h>
#include <hip/hip_bf16.h>

// ---------------- constants ----------------
// B=4, L=2048, D=512, DI=1024, DS=16, DC=4, DTR=32, H=4, DH=128
#define BB 4
#define LL 2048
#define DD 512
#define DI 1024
#define DS 16
#define DTR 32
#define BL (BB*LL)   // 8192
#define NSEG 32
#define TSEG 64      // NSEG*TSEG == LL

using bf16x8 = __attribute__((ext_vector_type(8))) short;
using f32x4  = __attribute__((ext_vector_type(4))) float;

// ---------------- helpers ----------------
__device__ __forceinline__ float geluf(float x) {
    return 0.5f * x * (1.f + erff(x * 0.7071067811865476f));
}

__device__ __forceinline__ unsigned short f2bf(float f) {
    unsigned u = __float_as_uint(f);
    u += 0x7FFFu + ((u >> 16) & 1u);   // round-to-nearest-even
    return (unsigned short)(u >> 16);
}

__device__ __forceinline__ void block_reduce_sum2(float& a, float& b, float* sred) {
    for (int off = 32; off > 0; off >>= 1) {
        a += __shfl_down(a, off);
        b += __shfl_down(b, off);
    }
    const int lane = threadIdx.x & 63, wid = threadIdx.x >> 6;
    if (lane == 0) { sred[wid*2] = a; sred[wid*2+1] = b; }
    __syncthreads();
    a = sred[0] + sred[2] + sred[4] + sred[6];
    b = sred[1] + sred[3] + sred[5] + sred[7];
    __syncthreads();
}

__device__ __forceinline__ float block_reduce_max(float v, float* sred) {
    for (int off = 32; off > 0; off >>= 1) v = fmaxf(v, __shfl_down(v, off));
    const int lane = threadIdx.x & 63, wid = threadIdx.x >> 6;
    if (lane == 0) sred[wid] = v;
    __syncthreads();
    v = fmaxf(fmaxf(sred[0], sred[1]), fmaxf(sred[2], sred[3]));
    __syncthreads();
    return v;
}

__device__ __forceinline__ float block_reduce_sum1(float v, float* sred) {
    for (int off = 32; off > 0; off >>= 1) v += __shfl_down(v, off);
    const int lane = threadIdx.x & 63, wid = threadIdx.x >> 6;
    if (lane == 0) sred[wid] = v;
    __syncthreads();
    v = sred[0] + sred[1] + sred[2] + sred[3];
    __syncthreads();
    return v;
}

// ---------------- bf16 MFMA GEMM: C[M,N] = A[M,K] * W[N,K]^T (+bias) ----------------
// f32 inputs, convert-on-stage to bf16 LDS (XOR-swizzled), mfma_f32_16x16x32_bf16.
// Wave grid WGM x WGN (WGM*WGN==4), each wave computes 64x64 via 4x4 16x16 frags.
// BM=WGM*64, BN=WGN*64, BK=64. Dims must divide tiles exactly.
template<int WGM, int WGN>
__global__ __launch_bounds__(256) void gemm_bf16(
    const float* __restrict__ A, const float* __restrict__ W,
    float* __restrict__ C, const float* __restrict__ bias,
    int K, int lda, int ldw, int ldc)
{
    constexpr int BM = WGM*64, BN = WGN*64, ROWS = BM + BN;
    __shared__ unsigned short lds[ROWS * 64];   // row stride 64 bf16 = 128B
    const int tid = threadIdx.x;
    const int bm = blockIdx.y * BM, bn = blockIdx.x * BN;
    const int wid = tid >> 6, lane = tid & 63;
    const int wr = wid / WGN, wc = wid % WGN;
    const int l16 = lane & 15, lq = lane >> 4;
    const int swz = (l16 & 7) << 3;             // ushort-unit XOR swizzle for frag reads

    f32x4 acc[4][4];
#pragma unroll
    for (int mi = 0; mi < 4; ++mi)
#pragma unroll
        for (int ni = 0; ni < 4; ++ni) acc[mi][ni] = {0.f, 0.f, 0.f, 0.f};

    for (int k0 = 0; k0 < K; k0 += 64) {
        // stage: ROWS rows x 64 f32 -> bf16 LDS (swizzled)
        for (int i = tid; i < ROWS * 16; i += 256) {
            const int row = i >> 4, kq = i & 15;
            const float* src = (row < BM) ? (A + (size_t)(bm + row) * lda + k0)
                                          : (W + (size_t)(bn + row - BM) * ldw + k0);
            float4 v = *(const float4*)(src + kq * 4);
            ushort4 h = { f2bf(v.x), f2bf(v.y), f2bf(v.z), f2bf(v.w) };
            *(ushort4*)&lds[row * 64 + ((kq * 4) ^ ((row & 7) << 3))] = h;
        }
        __syncthreads();
#pragma unroll
        for (int ks = 0; ks < 64; ks += 32) {
            bf16x8 af[4], bfr[4];
#pragma unroll
            for (int mi = 0; mi < 4; ++mi) {
                const int r = wr*64 + mi*16 + l16;
                af[mi] = *(const bf16x8*)&lds[r*64 + ((ks + lq*8) ^ swz)];
            }
#pragma unroll
            for (int ni = 0; ni < 4; ++ni) {
                const int r = BM + wc*64 + ni*16 + l16;
                bfr[ni] = *(const bf16x8*)&lds[r*64 + ((ks + lq*8) ^ swz)];
            }
#pragma unroll
            for (int mi = 0; mi < 4; ++mi)
#pragma unroll
                for (int ni = 0; ni < 4; ++ni)
                    acc[mi][ni] = __builtin_amdgcn_mfma_f32_16x16x32_bf16(
                        af[mi], bfr[ni], acc[mi][ni], 0, 0, 0);
        }
        __syncthreads();
    }
    // epilogue: D layout col=lane&15, row=(lane>>4)*4+reg  [m89/m91]
#pragma unroll
    for (int ni = 0; ni < 4; ++ni) {
        const int col = bn + wc*64 + ni*16 + l16;
        const float bv = bias ? bias[col] : 0.f;
#pragma unroll
        for (int mi = 0; mi < 4; ++mi) {
            const int row = bm + wr*64 + mi*16 + lq*4;
#pragma unroll
            for (int r = 0; r < 4; ++r)
                C[(size_t)(row + r) * ldc + col] = acc[mi][ni][r] + bv;
        }
    }
}

// ---------------- small per-output-thread GEMM ----------------
// EPI: 0 none, 1 gelu, 2 sigmoid, 3 softplus
template<int EPI>
__global__ __launch_bounds__(256) void small_nt(
    const float* __restrict__ A, const float* __restrict__ W,
    const float* __restrict__ bias, float* __restrict__ C,
    int M, int N, int K, int lda)
{
    const int idx = blockIdx.x * 256 + threadIdx.x;
    if (idx >= M * N) return;
    const int r = idx / N, c = idx - r * N;
    const float* a = A + (size_t)r * lda;
    const float* w = W + (size_t)c * K;
    float acc = 0.f;
    for (int k = 0; k < K; k += 4) {
        float4 av = *(const float4*)(a + k);
        float4 wv = *(const float4*)(w + k);
        acc += av.x*wv.x + av.y*wv.y + av.z*wv.z + av.w*wv.w;
    }
    if (bias) acc += bias[c];
    if (EPI == 1)      acc = geluf(acc);
    else if (EPI == 2) acc = 1.f / (1.f + __expf(-acc));
    else if (EPI == 3) acc = (acc > 20.f) ? acc : log1pf(__expf(acc));
    C[(size_t)r * N + c] = acc;
}

// ---------------- causal depthwise conv (k=4) + SiLU ----------------
__global__ void dwconv_silu(const float* __restrict__ u, const float* __restrict__ cw,
                            const float* __restrict__ cb, float* __restrict__ out)
{
    const int idx = blockIdx.x * 256 + threadIdx.x;   // < BL*DI
    const int c = idx & (DI-1);
    const int row = idx >> 10;        // b*L + t
    const int t = row & (LL-1);
    const float* w = cw + c*4;
    float s = cb[c];
#pragma unroll
    for (int j = 0; j < 4; ++j) {
        const int tt = t - 3 + j;
        if (tt >= 0) s = fmaf(u[(size_t)(row - 3 + j) * DI + c], w[j], s);
    }
    out[idx] = s / (1.f + __expf(-s));   // silu
}

// ---------------- SSM chunked scan ----------------
__global__ __launch_bounds__(256) void ssm_pass1(
    const float* __restrict__ delta, const float* __restrict__ uact,
    const float* __restrict__ xdbl, const float* __restrict__ A_log,
    float* __restrict__ hseg, float* __restrict__ dsum)
{
    const int tid = threadIdx.x;
    const int ch = blockIdx.x * 256 + tid;
    const int seg = blockIdx.y, b = blockIdx.z;
    const size_t rb = (size_t)b * LL + seg * TSEG;
    __shared__ float sB[TSEG][16];
    for (int i = tid; i < TSEG*16; i += 256) {
        const int tt = i >> 4, s = i & 15;
        sB[tt][s] = xdbl[(rb + tt)*64 + 32 + s];
    }
    float Av[16];
#pragma unroll
    for (int s = 0; s < 16; ++s) Av[s] = -__expf(A_log[ch*16 + s]);
    __syncthreads();
    float h[16] = {};
    float ds = 0.f;
    float d  = delta[rb*DI + ch];
    float uu = uact [rb*DI + ch];
    for (int t = 0; t < TSEG; ++t) {
        const int tn = (t + 1 < TSEG) ? t + 1 : t;
        const float dn = delta[(rb + tn)*DI + ch];
        const float un = uact [(rb + tn)*DI + ch];
        ds += d;
        const float du = d * uu;
#pragma unroll
        for (int s = 0; s < 16; ++s) {
            const float a = __expf(d * Av[s]);
            h[s] = fmaf(a, h[s], du * sB[t][s]);
        }
        d = dn; uu = un;
    }
    float* hp = hseg + (((size_t)b*NSEG + seg)*DI + ch)*16;
    float4 o0 = {h[0],h[1],h[2],h[3]},   o1 = {h[4],h[5],h[6],h[7]};
    float4 o2 = {h[8],h[9],h[10],h[11]}, o3 = {h[12],h[13],h[14],h[15]};
    *(float4*)(hp)    = o0; *(float4*)(hp+4)  = o1;
    *(float4*)(hp+8)  = o2; *(float4*)(hp+12) = o3;
    dsum[((size_t)b*NSEG + seg)*DI + ch] = ds;
}

__global__ __launch_bounds__(256) void ssm_seg_scan(
    const float* __restrict__ A_log, const float* __restrict__ dsum,
    float* __restrict__ hseg)
{
    const int idx = blockIdx.x * 256 + threadIdx.x;
    const int s = idx & 15;
    const int bc = idx >> 4;
    const int ch = bc & (DI-1);
    const int b = bc >> 10;
    const float Av = -__expf(A_log[ch*16 + s]);
    float g = 0.f;
    for (int seg = 0; seg < NSEG; ++seg) {
        const size_t soff = ((size_t)b*NSEG + seg)*DI + ch;
        const float hloc = hseg[soff*16 + s];
        const float a = __expf(Av * dsum[soff]);
        hseg[soff*16 + s] = g;
        g = fmaf(a, g, hloc);
    }
}

__global__ __launch_bounds__(256) void ssm_pass2(
    const float* __restrict__ delta, const float* __restrict__ uact,
    const float* __restrict__ z, const float* __restrict__ xdbl,
    const float* __restrict__ A_log, const float* __restrict__ ssm_D,
    const float* __restrict__ hin, float* __restrict__ y)
{
    const int tid = threadIdx.x;
    const int ch = blockIdx.x * 256 + tid;
    const int seg = blockIdx.y, b = blockIdx.z;
    const size_t rb = (size_t)b * LL + seg * TSEG;
    __shared__ float sB[TSEG][16], sC[TSEG][16];
    for (int i = tid; i < TSEG*16; i += 256) {
        const int tt = i >> 4, s = i & 15;
        sB[tt][s] = xdbl[(rb + tt)*64 + 32 + s];
        sC[tt][s] = xdbl[(rb + tt)*64 + 48 + s];
    }
    float Av[16];
#pragma unroll
    for (int s = 0; s < 16; ++s) Av[s] = -__expf(A_log[ch*16 + s]);
    float h[16];
    const float* hp = hin + (((size_t)b*NSEG + seg)*DI + ch)*16;
#pragma unroll
    for (int s = 0; s < 16; ++s) h[s] = hp[s];
    const float Dc = ssm_D[ch];
    __syncthreads();
    float d  = delta[rb*DI + ch];
    float uu = uact [rb*DI + ch];
    float zz = z    [rb*DI + ch];
    for (int t = 0; t < TSEG; ++t) {
        const int tn = (t + 1 < TSEG) ? t + 1 : t;
        const float dn = delta[(rb + tn)*DI + ch];
        const float un = uact [(rb + tn)*DI + ch];
        const float zn = z    [(rb + tn)*DI + ch];
        const float du = d * uu;
        float p = 0.f;
#pragma unroll
        for (int s = 0; s < 16; ++s) {
            const float a = __expf(d * Av[s]);
            h[s] = fmaf(a, h[s], du * sB[t][s]);
            p = fmaf(h[s], sC[t][s], p);
        }
        const float sil = zz / (1.f + __expf(-zz));
        y[(rb + t)*DI + ch] = (p + uu*Dc) * sil;
        d = dn; uu = un; zz = zn;
    }
}

// ---------------- ln1 * (1+g) + residual -> ln2 ----------------
__global__ __launch_bounds__(256) void ln_gate_res_ln2(
    const float* __restrict__ x1raw, const float* __restrict__ xres,
    const float* __restrict__ g,
    const float* __restrict__ w1, const float* __restrict__ b1,
    const float* __restrict__ w2, const float* __restrict__ b2,
    float* __restrict__ x2)
{
    __shared__ float sred[8];
    const int row = blockIdx.x;
    const int b = row >> 11;
    const int c = threadIdx.x * 2;
    const size_t base = (size_t)row * DD;
    float2 v = *(const float2*)(x1raw + base + c);
    float s = v.x + v.y, ss = v.x*v.x + v.y*v.y;
    block_reduce_sum2(s, ss, sred);
    float mean = s * (1.f/DD);
    float rs = rsqrtf(fmaxf(ss * (1.f/DD) - mean*mean, 0.f) + 1e-5f);
    float2 xr = *(const float2*)(xres + base + c);
    float y0 = ((v.x - mean)*rs*w1[c]   + b1[c]  ) * (1.f + g[b*DD + c])   + xr.x;
    float y1 = ((v.y - mean)*rs*w1[c+1] + b1[c+1]) * (1.f + g[b*DD + c+1]) + xr.y;
    s = y0 + y1; ss = y0*y0 + y1*y1;
    block_reduce_sum2(s, ss, sred);
    mean = s * (1.f/DD);
    rs = rsqrtf(fmaxf(ss * (1.f/DD) - mean*mean, 0.f) + 1e-5f);
    float2 o;
    o.x = (y0 - mean)*rs*w2[c]   + b2[c];
    o.y = (y1 - mean)*rs*w2[c+1] + b2[c+1];
    *(float2*)(x2 + base + c) = o;
}

// ---------------- x + broadcast(add[b]) -> LN ----------------
__global__ __launch_bounds__(256) void add_bcast_ln(
    const float* __restrict__ xin, const float* __restrict__ addb,
    const float* __restrict__ w, const float* __restrict__ bb,
    float* __restrict__ out)
{
    __shared__ float sred[8];
    const int row = blockIdx.x, b = row >> 11, c = threadIdx.x * 2;
    const size_t base = (size_t)row * DD;
    float2 v = *(const float2*)(xin + base + c);
    v.x += addb[b*DD + c];
    v.y += addb[b*DD + c + 1];
    float s = v.x + v.y, ss = v.x*v.x + v.y*v.y;
    block_reduce_sum2(s, ss, sred);
    float mean = s * (1.f/DD);
    float rs = rsqrtf(fmaxf(ss * (1.f/DD) - mean*mean, 0.f) + 1e-5f);
    float2 o = { (v.x - mean)*rs*w[c] + bb[c], (v.y - mean)*rs*w[c+1] + bb[c+1] };
    *(float2*)(out + base + c) = o;
}

// ---------------- cross-attention (q_len = 1) ----------------
__global__ __launch_bounds__(256) void attn_kernel(
    const float* __restrict__ q, const float* __restrict__ kv, float* __restrict__ o)
{
    const int b = blockIdx.x >> 2, h = blockIdx.x & 3;
    const int tid = threadIdx.x;
    __shared__ float sc[LL];
    __shared__ float sq[128];
    __shared__ float sred[8];
    __shared__ float opart[2][128];
    if (tid < 128) sq[tid] = q[b*DD + h*128 + tid];
    __syncthreads();
    float lmax = -1e30f;
    for (int t = tid; t < LL; t += 256) {
        const float* kr = kv + ((size_t)(b*LL + t)) * 1024 + h*128;
        float dot = 0.f;
        for (int d = 0; d < 128; d += 4) {
            float4 k4 = *(const float4*)(kr + d);
            dot += sq[d]*k4.x + sq[d+1]*k4.y + sq[d+2]*k4.z + sq[d+3]*k4.w;
        }
        dot *= 0.088388347648318447f;  // 1/sqrt(128)
        sc[t] = dot;
        lmax = fmaxf(lmax, dot);
    }
    const float m = block_reduce_max(lmax, sred);
    float lsum = 0.f;
    for (int t = tid; t < LL; t += 256) {
        const float e = __expf(sc[t] - m);
        sc[t] = e;
        lsum += e;
    }
    const float inv = 1.f / block_reduce_sum1(lsum, sred);
    const int dh = tid & 127, td = tid >> 7;
    float acc = 0.f;
    for (int t = td; t < LL; t += 2)
        acc = fmaf(sc[t], kv[((size_t)(b*LL + t))*1024 + 512 + h*128 + dh], acc);
    opart[td][dh] = acc;
    __syncthreads();
    if (tid < 128) o[b*DD + h*128 + tid] = (opart[0][tid] + opart[1][tid]) * inv;
}

// ---------------- grouped temporal conv (k=3,pad=1,groups=4) + BN + GELU + residual ----------------
__global__ __launch_bounds__(256) void teconv_bn_gelu(
    const float* __restrict__ x3, const float* __restrict__ tw,
    const float* __restrict__ tb,
    const float* __restrict__ bng, const float* __restrict__ bnb,
    const float* __restrict__ bnm, const float* __restrict__ bnv,
    float* __restrict__ out)
{
    const int b = blockIdx.y >> 2, gg = blockIdx.y & 3;
    const int t0 = blockIdx.x * 32;
    const int tid = threadIdx.x;
    const int o = tid & 127, th = tid >> 7;
    __shared__ float xs[16][35];
    __shared__ float ws[128][49];
    float acc[16] = {};
    const int og = gg*128 + o;
    for (int i0 = 0; i0 < 128; i0 += 16) {
        __syncthreads();
        for (int i = tid; i < 16*34; i += 256) {
            const int ii = i / 34, tt = i - ii*34;
            const int t = t0 - 1 + tt;
            xs[ii][tt] = (t >= 0 && t < LL)
                       ? x3[((size_t)b*LL + t)*DD + gg*128 + i0 + ii] : 0.f;
        }
        for (int i = tid; i < 128*48; i += 256) {
            const int oo = i / 48, cc = i - oo*48;
            ws[oo][cc] = tw[(size_t)(gg*128 + oo)*384 + i0*3 + cc];
        }
        __syncthreads();
#pragma unroll
        for (int ii = 0; ii < 16; ++ii) {
            const float w0 = ws[o][ii*3+0], w1 = ws[o][ii*3+1], w2 = ws[o][ii*3+2];
            float xv[18];
#pragma unroll
            for (int j = 0; j < 18; ++j) xv[j] = xs[ii][th*16 + j];
#pragma unroll
            for (int j = 0; j < 16; ++j)
                acc[j] = fmaf(w0, xv[j], fmaf(w1, xv[j+1], fmaf(w2, xv[j+2], acc[j])));
        }
    }
    const float scale = bng[og] * rsqrtf(bnv[og] + 1e-5f);
    const float shift = bnb[og] - bnm[og]*scale;
    const float cbv = tb[og];
#pragma unroll
    for (int j = 0; j < 16; ++j) {
        const int t = t0 + th*16 + j;
        const float v = (acc[j] + cbv)*scale + shift;
        const size_t oi = ((size_t)b*LL + t)*DD + og;
        out[oi] = x3[oi] + geluf(v);
    }
}

// ---------------- launch ----------------
extern "C" void kernel_launch(void* const* d_in, const int* in_sizes, int n_in,
                              void* d_out, int out_size, void* d_ws, size_t ws_size,
                              hipStream_t stream)
{
    (void)in_sizes; (void)n_in; (void)out_size; (void)ws_size;
    const float* x         = (const float*)d_in[0];
    const float* freq      = (const float*)d_in[1];
    const float* in_proj_w = (const float*)d_in[2];
    const float* conv_w    = (const float*)d_in[3];
    const float* conv_b    = (const float*)d_in[4];
    const float* x_proj_w  = (const float*)d_in[5];
    const float* dt_proj_w = (const float*)d_in[6];
    const float* dt_proj_b = (const float*)d_in[7];
    const float* A_log     = (const float*)d_in[8];
    const float* ssm_D     = (const float*)d_in[9];
    const float* out_proj_w= (const float*)d_in[10];
    const float* fg_w1     = (const float*)d_in[11];
    const float* fg_b1     = (const float*)d_in[12];
    const float* fg_w2     = (const float*)d_in[13];
    const float* fg_b2     = (const float*)d_in[14];
    const float* attn_in_w = (const float*)d_in[15];
    const float* attn_in_b = (const float*)d_in[16];
    const float* attn_out_w= (const float*)d_in[17];
    const float* attn_out_b= (const float*)d_in[18];
    const float* te_w      = (const float*)d_in[19];
    const float* te_b      = (const float*)d_in[20];
    const float* bn_g      = (const float*)d_in[21];
    const float* bn_b      = (const float*)d_in[22];
    const float* bn_m      = (const float*)d_in[23];
    const float* bn_v      = (const float*)d_in[24];
    const float* ln1w = (const float*)d_in[25];
    const float* ln1b = (const float*)d_in[26];
    const float* ln2w = (const float*)d_in[27];
    const float* ln2b = (const float*)d_in[28];
    const float* ln3w = (const float*)d_in[29];
    const float* ln3b = (const float*)d_in[30];
    float* out = (float*)d_out;

    // ---- workspace layout (lifetime-overlapped), total ~145 MB ----
    float* ws = (float*)d_ws;
    const size_t SEG = 8388608;                 // 8192*1024
    float* S1 = ws;                             // u_raw -> delta
    float* S2 = ws + SEG;                       // z_raw -> x1 | x3
    float* S3 = ws + 2*SEG;                     // u_act -> x2
    float* S4 = ws + 3*SEG;                     // y -> kv
    float* xdbl = ws + 4*SEG;                   // 524288
    float* sm   = ws + 4*SEG + 524288;          // small scalars (16384)
    float* hseg = sm + 16384;                   // 2097152 floats
    float* dsum = hseg + 2097152;               // 131072 floats
    float* u_raw = S1;  float* deltab = S1;
    float* z_raw = S2;  float* x1 = S2;  float* x3 = S2 + 4194304;
    float* u_act = S3;  float* x2 = S3;
    float* ybuf  = S4;  float* kv = S4;
    float* hidden = sm;        // 4096
    float* g  = sm + 4096;     // 2048
    float* qb = sm + 6144;     // 2048
    float* ob = sm + 8192;     // 2048
    float* ao = sm + 10240;    // 2048

    dim3 blk(256);

    // 1) in_proj: u and z halves (bf16 MFMA, 128x128 tiles)
    gemm_bf16<2,2><<<dim3(8,64), blk, 0, stream>>>(x, in_proj_w,          u_raw, nullptr, DD, DD, DD, DI);
    gemm_bf16<2,2><<<dim3(8,64), blk, 0, stream>>>(x, in_proj_w + 524288, z_raw, nullptr, DD, DD, DD, DI);
    // 2) causal depthwise conv + silu
    dwconv_silu<<<(BL*DI)/256, blk, 0, stream>>>(u_raw, conv_w, conv_b, u_act);
    // 3) x_dbl = u @ x_proj^T  (N=64: 256x64 tiles)
    gemm_bf16<4,1><<<dim3(1,32), blk, 0, stream>>>(u_act, x_proj_w, xdbl, nullptr, DI, DI, DI, 64);
    // 4) delta = softplus(dt @ dt_proj^T + b)
    small_nt<3><<<(BL*DI)/256, blk, 0, stream>>>(xdbl, dt_proj_w, dt_proj_b, deltab, BL, DI, DTR, 64);
    // 5) selective scan, chunked
    ssm_pass1<<<dim3(4, NSEG, BB), blk, 0, stream>>>(deltab, u_act, xdbl, A_log, hseg, dsum);
    ssm_seg_scan<<<256, blk, 0, stream>>>(A_log, dsum, hseg);
    ssm_pass2<<<dim3(4, NSEG, BB), blk, 0, stream>>>(deltab, u_act, z_raw, xdbl, A_log, ssm_D, hseg, ybuf);
    // 6) out_proj (N=512, K=1024)
    gemm_bf16<2,2><<<dim3(4,64), blk, 0, stream>>>(ybuf, out_proj_w, x1, nullptr, DI, DI, DI, DD);
    // 7) freq gate MLP
    small_nt<1><<<16, blk, 0, stream>>>(freq,   fg_w1, fg_b1, hidden, BB, 2*DD, DD, DD);
    small_nt<2><<<8,  blk, 0, stream>>>(hidden, fg_w2, fg_b2, g,      BB, DD, 2*DD, 2*DD);
    // 8) ln1 * (1+g) + residual -> ln2
    ln_gate_res_ln2<<<BL, blk, 0, stream>>>(x1, x, g, ln1w, ln1b, ln2w, ln2b, x2);
    // 9) attention
    small_nt<0><<<8, blk, 0, stream>>>(freq, attn_in_w, attn_in_b, qb, BB, DD, DD, DD);
    gemm_bf16<2,2><<<dim3(8,64), blk, 0, stream>>>(x2, attn_in_w + 262144, kv, attn_in_b + 512, DD, DD, DD, 2*DD);
    attn_kernel<<<BB*4, blk, 0, stream>>>(qb, kv, ob);
    small_nt<0><<<8, blk, 0, stream>>>(ob, attn_out_w, attn_out_b, ao, BB, DD, DD, DD);
    // 10) ln3(x2 + attn_broadcast)
    add_bcast_ln<<<BL, blk, 0, stream>>>(x2, ao, ln3w, ln3b, x3);
    // 11) temporal conv + BN + gelu + residual
    teconv_bn_gelu<<<dim3(LL/32, BB*4), blk, 0, stream>>>(x3, te_w, te_b, bn_g, bn_b, bn_m, bn_v, out);
}

// Round 4
// 623.501 us; speedup vs baseline: 3.2203x; 1.8651x over previous
//
#include <hip/hip_runtime.h>
#include <hip/hip_bf16.h>

// ---------------- constants ----------------
// B=4, L=2048, D=512, DI=1024, DS=16, DC=4, DTR=32, H=4, DH=128
#define BB 4
#define LL 2048
#define DD 512
#define DI 1024
#define DS 16
#define DTR 32
#define BL (BB*LL)   // 8192
#define NSEG 32
#define TSEG 64      // NSEG*TSEG == LL
#define ACH 32       // attention chunks per (b,h)

using bf16x8 = __attribute__((ext_vector_type(8))) short;
using f32x4  = __attribute__((ext_vector_type(4))) float;

// ---------------- helpers ----------------
__device__ __forceinline__ float geluf(float x) {
    return 0.5f * x * (1.f + erff(x * 0.7071067811865476f));
}

__device__ __forceinline__ unsigned short f2bf(float f) {
    unsigned u = __float_as_uint(f);
    u += 0x7FFFu + ((u >> 16) & 1u);   // round-to-nearest-even
    return (unsigned short)(u >> 16);
}

__device__ __forceinline__ void gload_lds16(const void* g, void* l) {
    __builtin_amdgcn_global_load_lds(
        (__attribute__((address_space(1))) void*)g,
        (__attribute__((address_space(3))) void*)l, 16, 0, 0);
}

__device__ __forceinline__ void block_reduce_sum2(float& a, float& b, float* sred) {
    for (int off = 32; off > 0; off >>= 1) {
        a += __shfl_down(a, off);
        b += __shfl_down(b, off);
    }
    const int lane = threadIdx.x & 63, wid = threadIdx.x >> 6;
    if (lane == 0) { sred[wid*2] = a; sred[wid*2+1] = b; }
    __syncthreads();
    a = sred[0] + sred[2] + sred[4] + sred[6];
    b = sred[1] + sred[3] + sred[5] + sred[7];
    __syncthreads();
}

__device__ __forceinline__ float block_reduce_max(float v, float* sred) {
    for (int off = 32; off > 0; off >>= 1) v = fmaxf(v, __shfl_down(v, off));
    const int lane = threadIdx.x & 63, wid = threadIdx.x >> 6;
    if (lane == 0) sred[wid] = v;
    __syncthreads();
    v = fmaxf(fmaxf(sred[0], sred[1]), fmaxf(sred[2], sred[3]));
    __syncthreads();
    return v;
}

__device__ __forceinline__ float block_reduce_sum1(float v, float* sred) {
    for (int off = 32; off > 0; off >>= 1) v += __shfl_down(v, off);
    const int lane = threadIdx.x & 63, wid = threadIdx.x >> 6;
    if (lane == 0) sred[wid] = v;
    __syncthreads();
    v = sred[0] + sred[1] + sred[2] + sred[3];
    __syncthreads();
    return v;
}

// ---------------- f32 -> bf16 convert ----------------
__global__ __launch_bounds__(256) void cvt_bf16(
    const float* __restrict__ in, unsigned short* __restrict__ out, int n)
{
    const int i = (blockIdx.x * 256 + threadIdx.x) * 8;
    if (i >= n) return;
    float4 a = *(const float4*)(in + i);
    float4 b = *(const float4*)(in + i + 4);
    ushort4 h0 = { f2bf(a.x), f2bf(a.y), f2bf(a.z), f2bf(a.w) };
    ushort4 h1 = { f2bf(b.x), f2bf(b.y), f2bf(b.z), f2bf(b.w) };
    *(ushort4*)(out + i)     = h0;
    *(ushort4*)(out + i + 4) = h1;
}

// ---------------- bf16 MFMA GEMM, global_load_lds staging ----------------
// C[M,N] = A[M,K] * W[N,K]^T (+bias). A,W bf16 (ushort), C f32.
// LDS linear [ROWS][64] ushort; global source pre-swizzled so that
// LDS chunk c of row r holds global 16B-chunk (c ^ (r&7)); frag reads XOR back.
template<int WGM, int WGN>
__global__ __launch_bounds__(256) void gemm_bf16g(
    const unsigned short* __restrict__ A, const unsigned short* __restrict__ W,
    float* __restrict__ C, const float* __restrict__ bias,
    int K, int lda, int ldw, int ldc)
{
    constexpr int BM = WGM*64, BN = WGN*64, ROWS = BM + BN;
    constexpr int ITERS = ROWS * 8 / 256;      // 16B chunks per thread per K-step
    __shared__ unsigned short lds[ROWS * 64];
    const int tid = threadIdx.x;
    const int bm = blockIdx.y * BM, bn = blockIdx.x * BN;
    const int lane = tid & 63, wid = tid >> 6;
    const int wr = wid / WGN, wc = wid % WGN;
    const int l16 = lane & 15, lq = lane >> 4;
    const int swz = (l16 & 7) << 3;

    f32x4 acc[4][4];
#pragma unroll
    for (int mi = 0; mi < 4; ++mi)
#pragma unroll
        for (int ni = 0; ni < 4; ++ni) acc[mi][ni] = {0.f, 0.f, 0.f, 0.f};

    for (int k0 = 0; k0 < K; k0 += 64) {
#pragma unroll
        for (int it = 0; it < ITERS; ++it) {
            const int cid = it * 256 + tid;            // 16B-chunk id
            const int r = cid >> 3, c = cid & 7;
            const int j = c ^ (r & 7);                 // pre-swizzled source chunk
            const unsigned short* gsrc =
                (r < BM ? A + (size_t)(bm + r) * lda : W + (size_t)(bn + r - BM) * ldw)
                + k0 + j * 8;
            gload_lds16(gsrc, &lds[(size_t)(cid & ~63) * 8]);
        }
        __syncthreads();   // compiler drains vmcnt before s_barrier
#pragma unroll
        for (int ks = 0; ks < 64; ks += 32) {
            bf16x8 af[4], bfr[4];
#pragma unroll
            for (int mi = 0; mi < 4; ++mi) {
                const int r = wr*64 + mi*16 + l16;
                af[mi] = *(const bf16x8*)&lds[r*64 + ((ks + lq*8) ^ swz)];
            }
#pragma unroll
            for (int ni = 0; ni < 4; ++ni) {
                const int r = BM + wc*64 + ni*16 + l16;
                bfr[ni] = *(const bf16x8*)&lds[r*64 + ((ks + lq*8) ^ swz)];
            }
#pragma unroll
            for (int mi = 0; mi < 4; ++mi)
#pragma unroll
                for (int ni = 0; ni < 4; ++ni)
                    acc[mi][ni] = __builtin_amdgcn_mfma_f32_16x16x32_bf16(
                        af[mi], bfr[ni], acc[mi][ni], 0, 0, 0);
        }
        __syncthreads();
    }
    // epilogue: D layout col=lane&15, row=(lane>>4)*4+reg  [m89/m91]
#pragma unroll
    for (int ni = 0; ni < 4; ++ni) {
        const int col = bn + wc*64 + ni*16 + l16;
        const float bv = bias ? bias[col] : 0.f;
#pragma unroll
        for (int mi = 0; mi < 4; ++mi) {
            const int row = bm + wr*64 + mi*16 + lq*4;
#pragma unroll
            for (int r = 0; r < 4; ++r)
                C[(size_t)(row + r) * ldc + col] = acc[mi][ni][r] + bv;
        }
    }
}

// ---------------- small per-output-thread GEMM ----------------
// EPI: 0 none, 1 gelu, 2 sigmoid, 3 softplus
template<int EPI>
__global__ __launch_bounds__(256) void small_nt(
    const float* __restrict__ A, const float* __restrict__ W,
    const float* __restrict__ bias, float* __restrict__ C,
    int M, int N, int K, int lda)
{
    const int idx = blockIdx.x * 256 + threadIdx.x;
    if (idx >= M * N) return;
    const int r = idx / N, c = idx - r * N;
    const float* a = A + (size_t)r * lda;
    const float* w = W + (size_t)c * K;
    float acc = 0.f;
    for (int k = 0; k < K; k += 4) {
        float4 av = *(const float4*)(a + k);
        float4 wv = *(const float4*)(w + k);
        acc += av.x*wv.x + av.y*wv.y + av.z*wv.z + av.w*wv.w;
    }
    if (bias) acc += bias[c];
    if (EPI == 1)      acc = geluf(acc);
    else if (EPI == 2) acc = 1.f / (1.f + __expf(-acc));
    else if (EPI == 3) acc = (acc > 20.f) ? acc : log1pf(__expf(acc));
    C[(size_t)r * N + c] = acc;
}

// ---------------- causal depthwise conv (k=4) + SiLU (f32 + bf16 out) ----------------
__global__ void dwconv_silu(const float* __restrict__ u, const float* __restrict__ cw,
                            const float* __restrict__ cb, float* __restrict__ out,
                            unsigned short* __restrict__ out_bf)
{
    const int idx = blockIdx.x * 256 + threadIdx.x;   // < BL*DI
    const int c = idx & (DI-1);
    const int row = idx >> 10;        // b*L + t
    const int t = row & (LL-1);
    const float* w = cw + c*4;
    float s = cb[c];
#pragma unroll
    for (int j = 0; j < 4; ++j) {
        const int tt = t - 3 + j;
        if (tt >= 0) s = fmaf(u[(size_t)(row - 3 + j) * DI + c], w[j], s);
    }
    const float v = s / (1.f + __expf(-s));   // silu
    out[idx] = v;
    out_bf[idx] = f2bf(v);
}

// ---------------- SSM chunked scan ----------------
__global__ __launch_bounds__(256) void ssm_pass1(
    const float* __restrict__ delta, const float* __restrict__ uact,
    const float* __restrict__ xdbl, const float* __restrict__ A_log,
    float* __restrict__ hseg, float* __restrict__ dsum)
{
    const int tid = threadIdx.x;
    const int ch = blockIdx.x * 256 + tid;
    const int seg = blockIdx.y, b = blockIdx.z;
    const size_t rb = (size_t)b * LL + seg * TSEG;
    __shared__ float sB[TSEG][16];
    for (int i = tid; i < TSEG*16; i += 256) {
        const int tt = i >> 4, s = i & 15;
        sB[tt][s] = xdbl[(rb + tt)*64 + 32 + s];
    }
    float Av[16];
#pragma unroll
    for (int s = 0; s < 16; ++s) Av[s] = -__expf(A_log[ch*16 + s]);
    __syncthreads();
    float h[16] = {};
    float ds = 0.f;
    float d  = delta[rb*DI + ch];
    float uu = uact [rb*DI + ch];
    for (int t = 0; t < TSEG; ++t) {
        const int tn = (t + 1 < TSEG) ? t + 1 : t;
        const float dn = delta[(rb + tn)*DI + ch];
        const float un = uact [(rb + tn)*DI + ch];
        ds += d;
        const float du = d * uu;
#pragma unroll
        for (int s = 0; s < 16; ++s) {
            const float a = __expf(d * Av[s]);
            h[s] = fmaf(a, h[s], du * sB[t][s]);
        }
        d = dn; uu = un;
    }
    float* hp = hseg + (((size_t)b*NSEG + seg)*DI + ch)*16;
    float4 o0 = {h[0],h[1],h[2],h[3]},   o1 = {h[4],h[5],h[6],h[7]};
    float4 o2 = {h[8],h[9],h[10],h[11]}, o3 = {h[12],h[13],h[14],h[15]};
    *(float4*)(hp)    = o0; *(float4*)(hp+4)  = o1;
    *(float4*)(hp+8)  = o2; *(float4*)(hp+12) = o3;
    dsum[((size_t)b*NSEG + seg)*DI + ch] = ds;
}

__global__ __launch_bounds__(256) void ssm_seg_scan(
    const float* __restrict__ A_log, const float* __restrict__ dsum,
    float* __restrict__ hseg)
{
    const int idx = blockIdx.x * 256 + threadIdx.x;
    const int s = idx & 15;
    const int bc = idx >> 4;
    const int ch = bc & (DI-1);
    const int b = bc >> 10;
    const float Av = -__expf(A_log[ch*16 + s]);
    float g = 0.f;
    for (int seg = 0; seg < NSEG; ++seg) {
        const size_t soff = ((size_t)b*NSEG + seg)*DI + ch;
        const float hloc = hseg[soff*16 + s];
        const float a = __expf(Av * dsum[soff]);
        hseg[soff*16 + s] = g;
        g = fmaf(a, g, hloc);
    }
}

// pass2: seeded local scan + C-dot + u*D + silu(z) gate -> y (bf16)
__global__ __launch_bounds__(256) void ssm_pass2(
    const float* __restrict__ delta, const float* __restrict__ uact,
    const float* __restrict__ z, const float* __restrict__ xdbl,
    const float* __restrict__ A_log, const float* __restrict__ ssm_D,
    const float* __restrict__ hin, unsigned short* __restrict__ y)
{
    const int tid = threadIdx.x;
    const int ch = blockIdx.x * 256 + tid;
    const int seg = blockIdx.y, b = blockIdx.z;
    const size_t rb = (size_t)b * LL + seg * TSEG;
    __shared__ float sB[TSEG][16], sC[TSEG][16];
    for (int i = tid; i < TSEG*16; i += 256) {
        const int tt = i >> 4, s = i & 15;
        sB[tt][s] = xdbl[(rb + tt)*64 + 32 + s];
        sC[tt][s] = xdbl[(rb + tt)*64 + 48 + s];
    }
    float Av[16];
#pragma unroll
    for (int s = 0; s < 16; ++s) Av[s] = -__expf(A_log[ch*16 + s]);
    float h[16];
    const float* hp = hin + (((size_t)b*NSEG + seg)*DI + ch)*16;
#pragma unroll
    for (int s = 0; s < 16; ++s) h[s] = hp[s];
    const float Dc = ssm_D[ch];
    __syncthreads();
    float d  = delta[rb*DI + ch];
    float uu = uact [rb*DI + ch];
    float zz = z    [rb*DI + ch];
    for (int t = 0; t < TSEG; ++t) {
        const int tn = (t + 1 < TSEG) ? t + 1 : t;
        const float dn = delta[(rb + tn)*DI + ch];
        const float un = uact [(rb + tn)*DI + ch];
        const float zn = z    [(rb + tn)*DI + ch];
        const float du = d * uu;
        float p = 0.f;
#pragma unroll
        for (int s = 0; s < 16; ++s) {
            const float a = __expf(d * Av[s]);
            h[s] = fmaf(a, h[s], du * sB[t][s]);
            p = fmaf(h[s], sC[t][s], p);
        }
        const float sil = zz / (1.f + __expf(-zz));
        y[(rb + t)*DI + ch] = f2bf((p + uu*Dc) * sil);
        d = dn; uu = un; zz = zn;
    }
}

// ---------------- ln1 * (1+g) + residual -> ln2 (f32 + bf16 out) ----------------
__global__ __launch_bounds__(256) void ln_gate_res_ln2(
    const float* __restrict__ x1raw, const float* __restrict__ xres,
    const float* __restrict__ g,
    const float* __restrict__ w1, const float* __restrict__ b1,
    const float* __restrict__ w2, const float* __restrict__ b2,
    float* __restrict__ x2, unsigned short* __restrict__ x2b)
{
    __shared__ float sred[8];
    const int row = blockIdx.x;
    const int b = row >> 11;
    const int c = threadIdx.x * 2;
    const size_t base = (size_t)row * DD;
    float2 v = *(const float2*)(x1raw + base + c);
    float s = v.x + v.y, ss = v.x*v.x + v.y*v.y;
    block_reduce_sum2(s, ss, sred);
    float mean = s * (1.f/DD);
    float rs = rsqrtf(fmaxf(ss * (1.f/DD) - mean*mean, 0.f) + 1e-5f);
    float2 xr = *(const float2*)(xres + base + c);
    float y0 = ((v.x - mean)*rs*w1[c]   + b1[c]  ) * (1.f + g[b*DD + c])   + xr.x;
    float y1 = ((v.y - mean)*rs*w1[c+1] + b1[c+1]) * (1.f + g[b*DD + c+1]) + xr.y;
    s = y0 + y1; ss = y0*y0 + y1*y1;
    block_reduce_sum2(s, ss, sred);
    mean = s * (1.f/DD);
    rs = rsqrtf(fmaxf(ss * (1.f/DD) - mean*mean, 0.f) + 1e-5f);
    float2 o;
    o.x = (y0 - mean)*rs*w2[c]   + b2[c];
    o.y = (y1 - mean)*rs*w2[c+1] + b2[c+1];
    *(float2*)(x2 + base + c) = o;
    ushort2 ob = { f2bf(o.x), f2bf(o.y) };
    *(ushort2*)(x2b + base + c) = ob;
}

// ---------------- x + broadcast(add[b]) -> LN ----------------
__global__ __launch_bounds__(256) void add_bcast_ln(
    const float* __restrict__ xin, const float* __restrict__ addb,
    const float* __restrict__ w, const float* __restrict__ bb,
    float* __restrict__ out)
{
    __shared__ float sred[8];
    const int row = blockIdx.x, b = row >> 11, c = threadIdx.x * 2;
    const size_t base = (size_t)row * DD;
    float2 v = *(const float2*)(xin + base + c);
    v.x += addb[b*DD + c];
    v.y += addb[b*DD + c + 1];
    float s = v.x + v.y, ss = v.x*v.x + v.y*v.y;
    block_reduce_sum2(s, ss, sred);
    float mean = s * (1.f/DD);
    float rs = rsqrtf(fmaxf(ss * (1.f/DD) - mean*mean, 0.f) + 1e-5f);
    float2 o = { (v.x - mean)*rs*w[c] + bb[c], (v.y - mean)*rs*w[c+1] + bb[c+1] };
    *(float2*)(out + base + c) = o;
}

// ---------------- cross-attention, flash-split ----------------
// part: grid (ACH, B*H); each block does 64 rows of one (b,h): partial m,s,o
__global__ __launch_bounds__(256) void attn_part(
    const float* __restrict__ q, const float* __restrict__ kv,
    float* __restrict__ po, float* __restrict__ pms)
{
    const int chunk = blockIdx.x, bh = blockIdx.y;
    const int b = bh >> 2, h = bh & 3;
    const int tid = threadIdx.x;
    __shared__ float sq[128];
    __shared__ float se[64];
    __shared__ float sred[8];
    __shared__ float opart[2][128];
    if (tid < 128) sq[tid] = q[b*DD + h*128 + tid];
    __syncthreads();
    const int r = tid >> 2, p = tid & 3;   // row 0..63, quarter 0..3
    const int trow = chunk*64 + r;
    const float* kr = kv + ((size_t)(b*LL + trow))*1024 + h*128 + p*32;
    float dot = 0.f;
#pragma unroll
    for (int d = 0; d < 32; d += 4) {
        float4 k4 = *(const float4*)(kr + d);
        dot += sq[p*32+d]*k4.x + sq[p*32+d+1]*k4.y + sq[p*32+d+2]*k4.z + sq[p*32+d+3]*k4.w;
    }
    dot += __shfl_xor(dot, 1);
    dot += __shfl_xor(dot, 2);
    if (p == 0) se[r] = dot * 0.088388347648318447f;   // 1/sqrt(128)
    __syncthreads();
    const float lm = (tid < 64) ? se[tid] : -1e30f;
    const float m = block_reduce_max(lm, sred);
    float le = 0.f;
    if (tid < 64) { le = __expf(se[tid] - m); se[tid] = le; }
    const float ssum = block_reduce_sum1(le, sred);
    const int d = tid & 127, half = tid >> 7;
    float acc = 0.f;
    for (int rr = half; rr < 64; rr += 2)
        acc = fmaf(se[rr], kv[((size_t)(b*LL + chunk*64 + rr))*1024 + 512 + h*128 + d], acc);
    opart[half][d] = acc;
    __syncthreads();
    if (tid < 128) po[((size_t)bh*ACH + chunk)*128 + tid] = opart[0][tid] + opart[1][tid];
    if (tid == 0) {
        pms[(bh*ACH + chunk)*2]     = m;
        pms[(bh*ACH + chunk)*2 + 1] = ssum;
    }
}

// combine: grid B*H blocks x 128 threads
__global__ __launch_bounds__(128) void attn_combine(
    const float* __restrict__ po, const float* __restrict__ pms,
    float* __restrict__ ob)
{
    const int bh = blockIdx.x, tid = threadIdx.x;
    __shared__ float sm_[ACH], ss_[ACH];
    if (tid < ACH) {
        sm_[tid] = pms[(bh*ACH + tid)*2];
        ss_[tid] = pms[(bh*ACH + tid)*2 + 1];
    }
    __syncthreads();
    float M = -1e30f;
#pragma unroll
    for (int i = 0; i < ACH; ++i) M = fmaxf(M, sm_[i]);
    float S = 0.f, acc = 0.f;
    for (int i = 0; i < ACH; ++i) {
        const float e = __expf(sm_[i] - M);
        S += e * ss_[i];
        acc = fmaf(e, po[((size_t)bh*ACH + i)*128 + tid], acc);
    }
    const int b = bh >> 2, h = bh & 3;
    ob[b*DD + h*128 + tid] = acc / S;
}

// ---------------- grouped temporal conv (k=3,pad=1,groups=4) + BN + GELU + residual ----------------
__global__ __launch_bounds__(256) void teconv_bn_gelu(
    const float* __restrict__ x3, const float* __restrict__ tw,
    const float* __restrict__ tb,
    const float* __restrict__ bng, const float* __restrict__ bnb,
    const float* __restrict__ bnm, const float* __restrict__ bnv,
    float* __restrict__ out)
{
    const int b = blockIdx.y >> 2, gg = blockIdx.y & 3;
    const int t0 = blockIdx.x * 32;
    const int tid = threadIdx.x;
    const int o = tid & 127, th = tid >> 7;
    __shared__ float xs[16][35];
    __shared__ float ws[128][49];
    float acc[16] = {};
    const int og = gg*128 + o;
    for (int i0 = 0; i0 < 128; i0 += 16) {
        __syncthreads();
        for (int i = tid; i < 16*34; i += 256) {
            const int ii = i / 34, tt = i - ii*34;
            const int t = t0 - 1 + tt;
            xs[ii][tt] = (t >= 0 && t < LL)
                       ? x3[((size_t)b*LL + t)*DD + gg*128 + i0 + ii] : 0.f;
        }
        for (int i = tid; i < 128*48; i += 256) {
            const int oo = i / 48, cc = i - oo*48;
            ws[oo][cc] = tw[(size_t)(gg*128 + oo)*384 + i0*3 + cc];
        }
        __syncthreads();
#pragma unroll
        for (int ii = 0; ii < 16; ++ii) {
            const float w0 = ws[o][ii*3+0], w1 = ws[o][ii*3+1], w2 = ws[o][ii*3+2];
            float xv[18];
#pragma unroll
            for (int j = 0; j < 18; ++j) xv[j] = xs[ii][th*16 + j];
#pragma unroll
            for (int j = 0; j < 16; ++j)
                acc[j] = fmaf(w0, xv[j], fmaf(w1, xv[j+1], fmaf(w2, xv[j+2], acc[j])));
        }
    }
    const float scale = bng[og] * rsqrtf(bnv[og] + 1e-5f);
    const float shift = bnb[og] - bnm[og]*scale;
    const float cbv = tb[og];
#pragma unroll
    for (int j = 0; j < 16; ++j) {
        const int t = t0 + th*16 + j;
        const float v = (acc[j] + cbv)*scale + shift;
        const size_t oi = ((size_t)b*LL + t)*DD + og;
        out[oi] = x3[oi] + geluf(v);
    }
}

// ---------------- launch ----------------
extern "C" void kernel_launch(void* const* d_in, const int* in_sizes, int n_in,
                              void* d_out, int out_size, void* d_ws, size_t ws_size,
                              hipStream_t stream)
{
    (void)in_sizes; (void)n_in; (void)out_size; (void)ws_size;
    const float* x         = (const float*)d_in[0];
    const float* freq      = (const float*)d_in[1];
    const float* in_proj_w = (const float*)d_in[2];
    const float* conv_w    = (const float*)d_in[3];
    const float* conv_b    = (const float*)d_in[4];
    const float* x_proj_w  = (const float*)d_in[5];
    const float* dt_proj_w = (const float*)d_in[6];
    const float* dt_proj_b = (const float*)d_in[7];
    const float* A_log     = (const float*)d_in[8];
    const float* ssm_D     = (const float*)d_in[9];
    const float* out_proj_w= (const float*)d_in[10];
    const float* fg_w1     = (const float*)d_in[11];
    const float* fg_b1     = (const float*)d_in[12];
    const float* fg_w2     = (const float*)d_in[13];
    const float* fg_b2     = (const float*)d_in[14];
    const float* attn_in_w = (const float*)d_in[15];
    const float* attn_in_b = (const float*)d_in[16];
    const float* attn_out_w= (const float*)d_in[17];
    const float* attn_out_b= (const float*)d_in[18];
    const float* te_w      = (const float*)d_in[19];
    const float* te_b      = (const float*)d_in[20];
    const float* bn_g      = (const float*)d_in[21];
    const float* bn_b      = (const float*)d_in[22];
    const float* bn_m      = (const float*)d_in[23];
    const float* bn_v      = (const float*)d_in[24];
    const float* ln1w = (const float*)d_in[25];
    const float* ln1b = (const float*)d_in[26];
    const float* ln2w = (const float*)d_in[27];
    const float* ln2b = (const float*)d_in[28];
    const float* ln3w = (const float*)d_in[29];
    const float* ln3b = (const float*)d_in[30];
    float* out = (float*)d_out;

    // ---- workspace layout (lifetime-overlapped), ~150 MB ----
    float* ws = (float*)d_ws;
    const size_t SEG = 8388608;                 // 8192*1024 floats = 32 MiB
    float* S1 = ws;                             // u_raw -> delta -> x2b(bf16)
    float* S2 = ws + SEG;                       // z_raw -> x1 | x3
    float* S3 = ws + 2*SEG;                     // u_act -> x2
    float* S4 = ws + 3*SEG;                     // xb(bf16) -> u_act_bf -> ybuf_bf -> kv
    float* xdbl = ws + 4*SEG;                   // 524288 f; later attn partials
    float* sm   = ws + 4*SEG + 524288;          // small scalars (16384 f)
    float* hseg = sm + 16384;                   // 2097152 f
    float* dsum = hseg + 2097152;               // 131072 f
    unsigned short* wb = (unsigned short*)(dsum + 131072);   // bf16 weights
    unsigned short* ipw_b = wb;                 // 1048576 us (both in_proj halves)
    unsigned short* xpw_b = wb + 1048576;       // 65536 us
    unsigned short* opw_b = wb + 1114112;       // 524288 us
    unsigned short* kvw_b = wb + 1638400;       // 524288 us

    float* u_raw = S1;  float* deltab = S1;
    unsigned short* x2b = (unsigned short*)S1;
    float* z_raw = S2;  float* x1 = S2;  float* x3 = S2 + 4194304;
    float* u_act = S3;  float* x2 = S3;
    unsigned short* xb      = (unsigned short*)S4;
    unsigned short* uact_b  = (unsigned short*)S4;
    unsigned short* ybuf_b  = (unsigned short*)S4;
    float* kv = S4;
    float* hidden = sm;        // 4096
    float* g  = sm + 4096;     // 2048
    float* qb = sm + 6144;     // 2048
    float* ob = sm + 8192;     // 2048
    float* ao = sm + 10240;    // 2048
    float* po  = xdbl;         // 65536 f (attn partial o) - xdbl dead by then
    float* pms = xdbl + 65536; // 1024 f

    dim3 blk(256);

    // 0) bf16 conversions: inputs + weights
    cvt_bf16<<<2048, blk, 0, stream>>>(x, xb, 4194304);
    cvt_bf16<<<512,  blk, 0, stream>>>(in_proj_w, ipw_b, 1048576);
    cvt_bf16<<<32,   blk, 0, stream>>>(x_proj_w, xpw_b, 65536);
    cvt_bf16<<<256,  blk, 0, stream>>>(out_proj_w, opw_b, 524288);
    cvt_bf16<<<256,  blk, 0, stream>>>(attn_in_w + 262144, kvw_b, 524288);

    // 1) in_proj: u and z halves
    gemm_bf16g<2,2><<<dim3(8,64), blk, 0, stream>>>(xb, ipw_b,          u_raw, nullptr, DD, DD, DD, DI);
    gemm_bf16g<2,2><<<dim3(8,64), blk, 0, stream>>>(xb, ipw_b + 524288, z_raw, nullptr, DD, DD, DD, DI);
    // 2) causal depthwise conv + silu (writes f32 + bf16)
    dwconv_silu<<<(BL*DI)/256, blk, 0, stream>>>(u_raw, conv_w, conv_b, u_act, uact_b);
    // 3) x_dbl = u @ x_proj^T  (N=64)
    gemm_bf16g<4,1><<<dim3(1,32), blk, 0, stream>>>(uact_b, xpw_b, xdbl, nullptr, DI, DI, DI, 64);
    // 4) delta = softplus(dt @ dt_proj^T + b)
    small_nt<3><<<(BL*DI)/256, blk, 0, stream>>>(xdbl, dt_proj_w, dt_proj_b, deltab, BL, DI, DTR, 64);
    // 5) selective scan, chunked (pass2 writes bf16 y)
    ssm_pass1<<<dim3(4, NSEG, BB), blk, 0, stream>>>(deltab, u_act, xdbl, A_log, hseg, dsum);
    ssm_seg_scan<<<256, blk, 0, stream>>>(A_log, dsum, hseg);
    ssm_pass2<<<dim3(4, NSEG, BB), blk, 0, stream>>>(deltab, u_act, z_raw, xdbl, A_log, ssm_D, hseg, ybuf_b);
    // 6) out_proj
    gemm_bf16g<2,2><<<dim3(4,64), blk, 0, stream>>>(ybuf_b, opw_b, x1, nullptr, DI, DI, DI, DD);
    // 7) freq gate MLP
    small_nt<1><<<16, blk, 0, stream>>>(freq,   fg_w1, fg_b1, hidden, BB, 2*DD, DD, DD);
    small_nt<2><<<8,  blk, 0, stream>>>(hidden, fg_w2, fg_b2, g,      BB, DD, 2*DD, 2*DD);
    // 8) ln1 * (1+g) + residual -> ln2 (writes f32 + bf16)
    ln_gate_res_ln2<<<BL, blk, 0, stream>>>(x1, x, g, ln1w, ln1b, ln2w, ln2b, x2, x2b);
    // 9) attention
    small_nt<0><<<8, blk, 0, stream>>>(freq, attn_in_w, attn_in_b, qb, BB, DD, DD, DD);
    gemm_bf16g<2,2><<<dim3(8,64), blk, 0, stream>>>(x2b, kvw_b, kv, attn_in_b + 512, DD, DD, DD, 2*DD);
    attn_part<<<dim3(ACH, BB*4), blk, 0, stream>>>(qb, kv, po, pms);
    attn_combine<<<BB*4, dim3(128), 0, stream>>>(po, pms, ob);
    small_nt<0><<<8, blk, 0, stream>>>(ob, attn_out_w, attn_out_b, ao, BB, DD, DD, DD);
    // 10) ln3(x2 + attn_broadcast)
    add_bcast_ln<<<BL, blk, 0, stream>>>(x2, ao, ln3w, ln3b, x3);
    // 11) temporal conv + BN + gelu + residual
    teconv_bn_gelu<<<dim3(LL/32, BB*4), blk, 0, stream>>>(x3, te_w, te_b, bn_g, bn_b, bn_m, bn_v, out);
}

// Round 5
// 580.577 us; speedup vs baseline: 3.4584x; 1.0739x over previous
//
#include <hip/hip_runtime.h>
#include <hip/hip_bf16.h>

// ---------------- constants ----------------
// B=4, L=2048, D=512, DI=1024, DS=16, DC=4, DTR=32, H=4, DH=128
#define BB 4
#define LL 2048
#define DD 512
#define DI 1024
#define DS 16
#define DTR 32
#define BL (BB*LL)   // 8192
#define NSEG 32
#define TSEG 64      // NSEG*TSEG == LL
#define ACH 32       // attention chunks per (b,h)

using bf16x8 = __attribute__((ext_vector_type(8))) short;
using f32x4  = __attribute__((ext_vector_type(4))) float;

// ---------------- helpers ----------------
__device__ __forceinline__ float geluf(float x) {
    return 0.5f * x * (1.f + erff(x * 0.7071067811865476f));
}

__device__ __forceinline__ unsigned short f2bf(float f) {
    unsigned u = __float_as_uint(f);
    u += 0x7FFFu + ((u >> 16) & 1u);   // round-to-nearest-even
    return (unsigned short)(u >> 16);
}

__device__ __forceinline__ void gload_lds16(const void* g, void* l) {
    __builtin_amdgcn_global_load_lds(
        (__attribute__((address_space(1))) void*)g,
        (__attribute__((address_space(3))) void*)l, 16, 0, 0);
}

__device__ __forceinline__ void block_reduce_sum2(float& a, float& b, float* sred) {
    for (int off = 32; off > 0; off >>= 1) {
        a += __shfl_down(a, off);
        b += __shfl_down(b, off);
    }
    const int lane = threadIdx.x & 63, wid = threadIdx.x >> 6;
    if (lane == 0) { sred[wid*2] = a; sred[wid*2+1] = b; }
    __syncthreads();
    a = sred[0] + sred[2] + sred[4] + sred[6];
    b = sred[1] + sred[3] + sred[5] + sred[7];
    __syncthreads();
}

__device__ __forceinline__ float block_reduce_max(float v, float* sred) {
    for (int off = 32; off > 0; off >>= 1) v = fmaxf(v, __shfl_down(v, off));
    const int lane = threadIdx.x & 63, wid = threadIdx.x >> 6;
    if (lane == 0) sred[wid] = v;
    __syncthreads();
    v = fmaxf(fmaxf(sred[0], sred[1]), fmaxf(sred[2], sred[3]));
    __syncthreads();
    return v;
}

__device__ __forceinline__ float block_reduce_sum1(float v, float* sred) {
    for (int off = 32; off > 0; off >>= 1) v += __shfl_down(v, off);
    const int lane = threadIdx.x & 63, wid = threadIdx.x >> 6;
    if (lane == 0) sred[wid] = v;
    __syncthreads();
    v = sred[0] + sred[1] + sred[2] + sred[3];
    __syncthreads();
    return v;
}

// ---------------- utility kernels ----------------
__global__ __launch_bounds__(256) void zero_f32(float* __restrict__ p, int n) {
    const int i = (blockIdx.x * 256 + threadIdx.x) * 4;
    if (i < n) { float4 z = {0.f,0.f,0.f,0.f}; *(float4*)(p + i) = z; }
}

__global__ __launch_bounds__(256) void cvt_bf16(
    const float* __restrict__ in, unsigned short* __restrict__ out, int n)
{
    const int i = (blockIdx.x * 256 + threadIdx.x) * 8;
    if (i >= n) return;
    float4 a = *(const float4*)(in + i);
    float4 b = *(const float4*)(in + i + 4);
    ushort4 h0 = { f2bf(a.x), f2bf(a.y), f2bf(a.z), f2bf(a.w) };
    ushort4 h1 = { f2bf(b.x), f2bf(b.y), f2bf(b.z), f2bf(b.w) };
    *(ushort4*)(out + i)     = h0;
    *(ushort4*)(out + i + 4) = h1;
}

// ---------------- bf16 MFMA GEMM, global_load_lds staging ----------------
// C[M,N] = A[M,K] * W[N,K]^T (+bias). A,W bf16 (ushort), C f32.
// LDS linear [ROWS][64] ushort; global source pre-swizzled so that
// LDS chunk c of row r holds global 16B-chunk (c ^ (r&7)); frag reads XOR back.
template<int WGM, int WGN>
__global__ __launch_bounds__(256) void gemm_bf16g(
    const unsigned short* __restrict__ A, const unsigned short* __restrict__ W,
    float* __restrict__ C, const float* __restrict__ bias,
    int K, int lda, int ldw, int ldc)
{
    constexpr int BM = WGM*64, BN = WGN*64, ROWS = BM + BN;
    constexpr int ITERS = ROWS * 8 / 256;      // 16B chunks per thread per K-step
    __shared__ unsigned short lds[ROWS * 64];
    const int tid = threadIdx.x;
    const int bm = blockIdx.y * BM, bn = blockIdx.x * BN;
    const int lane = tid & 63, wid = tid >> 6;
    const int wr = wid / WGN, wc = wid % WGN;
    const int l16 = lane & 15, lq = lane >> 4;
    const int swz = (l16 & 7) << 3;

    f32x4 acc[4][4];
#pragma unroll
    for (int mi = 0; mi < 4; ++mi)
#pragma unroll
        for (int ni = 0; ni < 4; ++ni) acc[mi][ni] = {0.f, 0.f, 0.f, 0.f};

    for (int k0 = 0; k0 < K; k0 += 64) {
#pragma unroll
        for (int it = 0; it < ITERS; ++it) {
            const int cid = it * 256 + tid;            // 16B-chunk id
            const int r = cid >> 3, c = cid & 7;
            const int j = c ^ (r & 7);                 // pre-swizzled source chunk
            const unsigned short* gsrc =
                (r < BM ? A + (size_t)(bm + r) * lda : W + (size_t)(bn + r - BM) * ldw)
                + k0 + j * 8;
            gload_lds16(gsrc, &lds[(size_t)(cid & ~63) * 8]);
        }
        __syncthreads();
#pragma unroll
        for (int ks = 0; ks < 64; ks += 32) {
            bf16x8 af[4], bfr[4];
#pragma unroll
            for (int mi = 0; mi < 4; ++mi) {
                const int r = wr*64 + mi*16 + l16;
                af[mi] = *(const bf16x8*)&lds[r*64 + ((ks + lq*8) ^ swz)];
            }
#pragma unroll
            for (int ni = 0; ni < 4; ++ni) {
                const int r = BM + wc*64 + ni*16 + l16;
                bfr[ni] = *(const bf16x8*)&lds[r*64 + ((ks + lq*8) ^ swz)];
            }
#pragma unroll
            for (int mi = 0; mi < 4; ++mi)
#pragma unroll
                for (int ni = 0; ni < 4; ++ni)
                    acc[mi][ni] = __builtin_amdgcn_mfma_f32_16x16x32_bf16(
                        af[mi], bfr[ni], acc[mi][ni], 0, 0, 0);
        }
        __syncthreads();
    }
    // epilogue: D layout col=lane&15, row=(lane>>4)*4+reg  [m89/m91]
#pragma unroll
    for (int ni = 0; ni < 4; ++ni) {
        const int col = bn + wc*64 + ni*16 + l16;
        const float bv = bias ? bias[col] : 0.f;
#pragma unroll
        for (int mi = 0; mi < 4; ++mi) {
            const int row = bm + wr*64 + mi*16 + lq*4;
#pragma unroll
            for (int r = 0; r < 4; ++r)
                C[(size_t)(row + r) * ldc + col] = acc[mi][ni][r] + bv;
        }
    }
}

// ---------------- xdbl split-K GEMM: C[M,64] += A-slice @ W-slice^T ----------------
// grid (16, M/256); each block one K-step of 64. BM=256, BN=64. atomicAdd epilogue.
__global__ __launch_bounds__(256) void gemm_xdbl_sk(
    const unsigned short* __restrict__ A, const unsigned short* __restrict__ W,
    float* __restrict__ C)
{
    __shared__ unsigned short lds[320 * 64];
    const int tid = threadIdx.x;
    const int k0 = blockIdx.x * 64;
    const int bm = blockIdx.y * 256;
    const int lane = tid & 63, wid = tid >> 6;     // wr = wid, wc = 0
    const int l16 = lane & 15, lq = lane >> 4;
    const int swz = (l16 & 7) << 3;
#pragma unroll
    for (int it = 0; it < 10; ++it) {
        const int cid = it * 256 + tid;
        const int r = cid >> 3, c = cid & 7;
        const int j = c ^ (r & 7);
        const unsigned short* gsrc =
            (r < 256 ? A + (size_t)(bm + r) * DI : W + (size_t)(r - 256) * DI) + k0 + j * 8;
        gload_lds16(gsrc, &lds[(size_t)(cid & ~63) * 8]);
    }
    __syncthreads();
    f32x4 acc[4][4];
#pragma unroll
    for (int mi = 0; mi < 4; ++mi)
#pragma unroll
        for (int ni = 0; ni < 4; ++ni) acc[mi][ni] = {0.f, 0.f, 0.f, 0.f};
#pragma unroll
    for (int ks = 0; ks < 64; ks += 32) {
        bf16x8 af[4], bfr[4];
#pragma unroll
        for (int mi = 0; mi < 4; ++mi) {
            const int r = wid*64 + mi*16 + l16;
            af[mi] = *(const bf16x8*)&lds[r*64 + ((ks + lq*8) ^ swz)];
        }
#pragma unroll
        for (int ni = 0; ni < 4; ++ni) {
            const int r = 256 + ni*16 + l16;
            bfr[ni] = *(const bf16x8*)&lds[r*64 + ((ks + lq*8) ^ swz)];
        }
#pragma unroll
        for (int mi = 0; mi < 4; ++mi)
#pragma unroll
            for (int ni = 0; ni < 4; ++ni)
                acc[mi][ni] = __builtin_amdgcn_mfma_f32_16x16x32_bf16(
                    af[mi], bfr[ni], acc[mi][ni], 0, 0, 0);
    }
#pragma unroll
    for (int ni = 0; ni < 4; ++ni) {
        const int col = ni*16 + l16;
#pragma unroll
        for (int mi = 0; mi < 4; ++mi) {
            const int row = bm + wid*64 + mi*16 + lq*4;
#pragma unroll
            for (int r = 0; r < 4; ++r)
                atomicAdd(&C[(size_t)(row + r) * 64 + col], acc[mi][ni][r]);
        }
    }
}

// ---------------- delta GEMM: softplus(xdbl[:,0:32] @ dt_proj_w^T + b) ----------------
// M=8192, N=1024, K=32 -> ONE mfma per 16x16 frag. 128x128 tile, grid (8, 64).
// LDS rows padded to 34 shorts (17-bank stride -> exactly 2 lanes/bank, free).
__global__ __launch_bounds__(256) void delta_gemm(
    const float* __restrict__ xdbl, const float* __restrict__ dtw,
    const float* __restrict__ dtb, float* __restrict__ delta)
{
    __shared__ unsigned short As[128 * 34];
    __shared__ unsigned short Ws[128 * 34];
    const int tid = threadIdx.x;
    const int bn = blockIdx.x * 128, bm = blockIdx.y * 128;
    for (int i = tid; i < 128 * 8; i += 256) {
        const int r = i >> 3, c4 = (i & 7) * 4;
        float4 va = *(const float4*)(xdbl + (size_t)(bm + r) * 64 + c4);
        ushort4 ha = { f2bf(va.x), f2bf(va.y), f2bf(va.z), f2bf(va.w) };
        *(ushort4*)&As[r * 34 + c4] = ha;
        float4 vw = *(const float4*)(dtw + (size_t)(bn + r) * 32 + c4);
        ushort4 hw = { f2bf(vw.x), f2bf(vw.y), f2bf(vw.z), f2bf(vw.w) };
        *(ushort4*)&Ws[r * 34 + c4] = hw;
    }
    __syncthreads();
    const int lane = tid & 63, wid = tid >> 6;
    const int wr = wid >> 1, wc = wid & 1;
    const int l16 = lane & 15, lq = lane >> 4;
    bf16x8 af[4], wf[4];
#pragma unroll
    for (int mi = 0; mi < 4; ++mi)
        af[mi] = *(const bf16x8*)&As[(wr*64 + mi*16 + l16) * 34 + lq*8];
#pragma unroll
    for (int ni = 0; ni < 4; ++ni)
        wf[ni] = *(const bf16x8*)&Ws[(wc*64 + ni*16 + l16) * 34 + lq*8];
    f32x4 acc[4][4];
#pragma unroll
    for (int mi = 0; mi < 4; ++mi)
#pragma unroll
        for (int ni = 0; ni < 4; ++ni) {
            f32x4 z = {0.f, 0.f, 0.f, 0.f};
            acc[mi][ni] = __builtin_amdgcn_mfma_f32_16x16x32_bf16(af[mi], wf[ni], z, 0, 0, 0);
        }
#pragma unroll
    for (int ni = 0; ni < 4; ++ni) {
        const int col = bn + wc*64 + ni*16 + l16;
        const float bv = dtb[col];
#pragma unroll
        for (int mi = 0; mi < 4; ++mi) {
            const int row = bm + wr*64 + mi*16 + lq*4;
#pragma unroll
            for (int r = 0; r < 4; ++r) {
                float v = acc[mi][ni][r] + bv;
                v = (v > 20.f) ? v : log1pf(__expf(v));
                delta[(size_t)(row + r) * DI + col] = v;
            }
        }
    }
}

// ---------------- small per-output-thread GEMM ----------------
// EPI: 0 none, 1 gelu, 2 sigmoid
template<int EPI>
__global__ __launch_bounds__(256) void small_nt(
    const float* __restrict__ A, const float* __restrict__ W,
    const float* __restrict__ bias, float* __restrict__ C,
    int M, int N, int K, int lda)
{
    const int idx = blockIdx.x * 256 + threadIdx.x;
    if (idx >= M * N) return;
    const int r = idx / N, c = idx - r * N;
    const float* a = A + (size_t)r * lda;
    const float* w = W + (size_t)c * K;
    float acc = 0.f;
    for (int k = 0; k < K; k += 4) {
        float4 av = *(const float4*)(a + k);
        float4 wv = *(const float4*)(w + k);
        acc += av.x*wv.x + av.y*wv.y + av.z*wv.z + av.w*wv.w;
    }
    if (bias) acc += bias[c];
    if (EPI == 1)      acc = geluf(acc);
    else if (EPI == 2) acc = 1.f / (1.f + __expf(-acc));
    C[(size_t)r * N + c] = acc;
}

// ---------------- causal depthwise conv (k=4) + SiLU (f32 + bf16 out) ----------------
__global__ void dwconv_silu(const float* __restrict__ u, const float* __restrict__ cw,
                            const float* __restrict__ cb, float* __restrict__ out,
                            unsigned short* __restrict__ out_bf)
{
    const int idx = blockIdx.x * 256 + threadIdx.x;   // < BL*DI
    const int c = idx & (DI-1);
    const int row = idx >> 10;        // b*L + t
    const int t = row & (LL-1);
    const float* w = cw + c*4;
    float s = cb[c];
#pragma unroll
    for (int j = 0; j < 4; ++j) {
        const int tt = t - 3 + j;
        if (tt >= 0) s = fmaf(u[(size_t)(row - 3 + j) * DI + c], w[j], s);
    }
    const float v = s / (1.f + __expf(-s));   // silu
    out[idx] = v;
    out_bf[idx] = f2bf(v);
}

// ---------------- SSM chunked scan ----------------
__global__ __launch_bounds__(256) void ssm_pass1(
    const float* __restrict__ delta, const float* __restrict__ uact,
    const float* __restrict__ xdbl, const float* __restrict__ A_log,
    float* __restrict__ hseg, float* __restrict__ dsum)
{
    const int tid = threadIdx.x;
    const int ch = blockIdx.x * 256 + tid;
    const int seg = blockIdx.y, b = blockIdx.z;
    const size_t rb = (size_t)b * LL + seg * TSEG;
    __shared__ float sB[TSEG][16];
    for (int i = tid; i < TSEG*16; i += 256) {
        const int tt = i >> 4, s = i & 15;
        sB[tt][s] = xdbl[(rb + tt)*64 + 32 + s];
    }
    float Av[16];
#pragma unroll
    for (int s = 0; s < 16; ++s) Av[s] = -__expf(A_log[ch*16 + s]);
    __syncthreads();
    float h[16] = {};
    float ds = 0.f;
    float d  = delta[rb*DI + ch];
    float uu = uact [rb*DI + ch];
    for (int t = 0; t < TSEG; ++t) {
        const int tn = (t + 1 < TSEG) ? t + 1 : t;
        const float dn = delta[(rb + tn)*DI + ch];
        const float un = uact [(rb + tn)*DI + ch];
        ds += d;
        const float du = d * uu;
#pragma unroll
        for (int s = 0; s < 16; ++s) {
            const float a = __expf(d * Av[s]);
            h[s] = fmaf(a, h[s], du * sB[t][s]);
        }
        d = dn; uu = un;
    }
    float* hp = hseg + (((size_t)b*NSEG + seg)*DI + ch)*16;
    float4 o0 = {h[0],h[1],h[2],h[3]},   o1 = {h[4],h[5],h[6],h[7]};
    float4 o2 = {h[8],h[9],h[10],h[11]}, o3 = {h[12],h[13],h[14],h[15]};
    *(float4*)(hp)    = o0; *(float4*)(hp+4)  = o1;
    *(float4*)(hp+8)  = o2; *(float4*)(hp+12) = o3;
    dsum[((size_t)b*NSEG + seg)*DI + ch] = ds;
}

__global__ __launch_bounds__(256) void ssm_seg_scan(
    const float* __restrict__ A_log, const float* __restrict__ dsum,
    float* __restrict__ hseg)
{
    const int idx = blockIdx.x * 256 + threadIdx.x;
    const int s = idx & 15;
    const int bc = idx >> 4;
    const int ch = bc & (DI-1);
    const int b = bc >> 10;
    const float Av = -__expf(A_log[ch*16 + s]);
    float g = 0.f;
    for (int seg = 0; seg < NSEG; ++seg) {
        const size_t soff = ((size_t)b*NSEG + seg)*DI + ch;
        const float hloc = hseg[soff*16 + s];
        const float a = __expf(Av * dsum[soff]);
        hseg[soff*16 + s] = g;
        g = fmaf(a, g, hloc);
    }
}

// pass2: seeded local scan + C-dot + u*D + silu(z) gate -> y (bf16)
__global__ __launch_bounds__(256) void ssm_pass2(
    const float* __restrict__ delta, const float* __restrict__ uact,
    const float* __restrict__ z, const float* __restrict__ xdbl,
    const float* __restrict__ A_log, const float* __restrict__ ssm_D,
    const float* __restrict__ hin, unsigned short* __restrict__ y)
{
    const int tid = threadIdx.x;
    const int ch = blockIdx.x * 256 + tid;
    const int seg = blockIdx.y, b = blockIdx.z;
    const size_t rb = (size_t)b * LL + seg * TSEG;
    __shared__ float sB[TSEG][16], sC[TSEG][16];
    for (int i = tid; i < TSEG*16; i += 256) {
        const int tt = i >> 4, s = i & 15;
        sB[tt][s] = xdbl[(rb + tt)*64 + 32 + s];
        sC[tt][s] = xdbl[(rb + tt)*64 + 48 + s];
    }
    float Av[16];
#pragma unroll
    for (int s = 0; s < 16; ++s) Av[s] = -__expf(A_log[ch*16 + s]);
    float h[16];
    const float* hp = hin + (((size_t)b*NSEG + seg)*DI + ch)*16;
#pragma unroll
    for (int s = 0; s < 16; ++s) h[s] = hp[s];
    const float Dc = ssm_D[ch];
    __syncthreads();
    float d  = delta[rb*DI + ch];
    float uu = uact [rb*DI + ch];
    float zz = z    [rb*DI + ch];
    for (int t = 0; t < TSEG; ++t) {
        const int tn = (t + 1 < TSEG) ? t + 1 : t;
        const float dn = delta[(rb + tn)*DI + ch];
        const float un = uact [(rb + tn)*DI + ch];
        const float zn = z    [(rb + tn)*DI + ch];
        const float du = d * uu;
        float p = 0.f;
#pragma unroll
        for (int s = 0; s < 16; ++s) {
            const float a = __expf(d * Av[s]);
            h[s] = fmaf(a, h[s], du * sB[t][s]);
            p = fmaf(h[s], sC[t][s], p);
        }
        const float sil = zz / (1.f + __expf(-zz));
        y[(rb + t)*DI + ch] = f2bf((p + uu*Dc) * sil);
        d = dn; uu = un; zz = zn;
    }
}

// ---------------- ln1 * (1+g) + residual -> ln2 (f32 + bf16 out) ----------------
__global__ __launch_bounds__(256) void ln_gate_res_ln2(
    const float* __restrict__ x1raw, const float* __restrict__ xres,
    const float* __restrict__ g,
    const float* __restrict__ w1, const float* __restrict__ b1,
    const float* __restrict__ w2, const float* __restrict__ b2,
    float* __restrict__ x2, unsigned short* __restrict__ x2b)
{
    __shared__ float sred[8];
    const int row = blockIdx.x;
    const int b = row >> 11;
    const int c = threadIdx.x * 2;
    const size_t base = (size_t)row * DD;
    float2 v = *(const float2*)(x1raw + base + c);
    float s = v.x + v.y, ss = v.x*v.x + v.y*v.y;
    block_reduce_sum2(s, ss, sred);
    float mean = s * (1.f/DD);
    float rs = rsqrtf(fmaxf(ss * (1.f/DD) - mean*mean, 0.f) + 1e-5f);
    float2 xr = *(const float2*)(xres + base + c);
    float y0 = ((v.x - mean)*rs*w1[c]   + b1[c]  ) * (1.f + g[b*DD + c])   + xr.x;
    float y1 = ((v.y - mean)*rs*w1[c+1] + b1[c+1]) * (1.f + g[b*DD + c+1]) + xr.y;
    s = y0 + y1; ss = y0*y0 + y1*y1;
    block_reduce_sum2(s, ss, sred);
    mean = s * (1.f/DD);
    rs = rsqrtf(fmaxf(ss * (1.f/DD) - mean*mean, 0.f) + 1e-5f);
    float2 o;
    o.x = (y0 - mean)*rs*w2[c]   + b2[c];
    o.y = (y1 - mean)*rs*w2[c+1] + b2[c+1];
    *(float2*)(x2 + base + c) = o;
    ushort2 ob = { f2bf(o.x), f2bf(o.y) };
    *(ushort2*)(x2b + base + c) = ob;
}

// ---------------- x + broadcast(add[b]) -> LN ----------------
__global__ __launch_bounds__(256) void add_bcast_ln(
    const float* __restrict__ xin, const float* __restrict__ addb,
    const float* __restrict__ w, const float* __restrict__ bb,
    float* __restrict__ out)
{
    __shared__ float sred[8];
    const int row = blockIdx.x, b = row >> 11, c = threadIdx.x * 2;
    const size_t base = (size_t)row * DD;
    float2 v = *(const float2*)(xin + base + c);
    v.x += addb[b*DD + c];
    v.y += addb[b*DD + c + 1];
    float s = v.x + v.y, ss = v.x*v.x + v.y*v.y;
    block_reduce_sum2(s, ss, sred);
    float mean = s * (1.f/DD);
    float rs = rsqrtf(fmaxf(ss * (1.f/DD) - mean*mean, 0.f) + 1e-5f);
    float2 o = { (v.x - mean)*rs*w[c] + bb[c], (v.y - mean)*rs*w[c+1] + bb[c+1] };
    *(float2*)(out + base + c) = o;
}

// ---------------- cross-attention, flash-split ----------------
__global__ __launch_bounds__(256) void attn_part(
    const float* __restrict__ q, const float* __restrict__ kv,
    float* __restrict__ po, float* __restrict__ pms)
{
    const int chunk = blockIdx.x, bh = blockIdx.y;
    const int b = bh >> 2, h = bh & 3;
    const int tid = threadIdx.x;
    __shared__ float sq[128];
    __shared__ float se[64];
    __shared__ float sred[8];
    __shared__ float opart[2][128];
    if (tid < 128) sq[tid] = q[b*DD + h*128 + tid];
    __syncthreads();
    const int r = tid >> 2, p = tid & 3;   // row 0..63, quarter 0..3
    const int trow = chunk*64 + r;
    const float* kr = kv + ((size_t)(b*LL + trow))*1024 + h*128 + p*32;
    float dot = 0.f;
#pragma unroll
    for (int d = 0; d < 32; d += 4) {
        float4 k4 = *(const float4*)(kr + d);
        dot += sq[p*32+d]*k4.x + sq[p*32+d+1]*k4.y + sq[p*32+d+2]*k4.z + sq[p*32+d+3]*k4.w;
    }
    dot += __shfl_xor(dot, 1);
    dot += __shfl_xor(dot, 2);
    if (p == 0) se[r] = dot * 0.088388347648318447f;   // 1/sqrt(128)
    __syncthreads();
    const float lm = (tid < 64) ? se[tid] : -1e30f;
    const float m = block_reduce_max(lm, sred);
    float le = 0.f;
    if (tid < 64) { le = __expf(se[tid] - m); se[tid] = le; }
    const float ssum = block_reduce_sum1(le, sred);
    const int d = tid & 127, half = tid >> 7;
    float acc = 0.f;
    for (int rr = half; rr < 64; rr += 2)
        acc = fmaf(se[rr], kv[((size_t)(b*LL + chunk*64 + rr))*1024 + 512 + h*128 + d], acc);
    opart[half][d] = acc;
    __syncthreads();
    if (tid < 128) po[((size_t)bh*ACH + chunk)*128 + tid] = opart[0][tid] + opart[1][tid];
    if (tid == 0) {
        pms[(bh*ACH + chunk)*2]     = m;
        pms[(bh*ACH + chunk)*2 + 1] = ssum;
    }
}

__global__ __launch_bounds__(128) void attn_combine(
    const float* __restrict__ po, const float* __restrict__ pms,
    float* __restrict__ ob)
{
    const int bh = blockIdx.x, tid = threadIdx.x;
    __shared__ float sm_[ACH], ss_[ACH];
    if (tid < ACH) {
        sm_[tid] = pms[(bh*ACH + tid)*2];
        ss_[tid] = pms[(bh*ACH + tid)*2 + 1];
    }
    __syncthreads();
    float M = -1e30f;
#pragma unroll
    for (int i = 0; i < ACH; ++i) M = fmaxf(M, sm_[i]);
    float S = 0.f, acc = 0.f;
    for (int i = 0; i < ACH; ++i) {
        const float e = __expf(sm_[i] - M);
        S += e * ss_[i];
        acc = fmaf(e, po[((size_t)bh*ACH + i)*128 + tid], acc);
    }
    const int b = bh >> 2, h = bh & 3;
    ob[b*DD + h*128 + tid] = acc / S;
}

// ---------------- grouped temporal conv (k=3,pad=1,groups=4) + BN + GELU + residual ----------------
__global__ __launch_bounds__(256) void teconv_bn_gelu(
    const float* __restrict__ x3, const float* __restrict__ tw,
    const float* __restrict__ tb,
    const float* __restrict__ bng, const float* __restrict__ bnb,
    const float* __restrict__ bnm, const float* __restrict__ bnv,
    float* __restrict__ out)
{
    const int b = blockIdx.y >> 2, gg = blockIdx.y & 3;
    const int t0 = blockIdx.x * 32;
    const int tid = threadIdx.x;
    const int o = tid & 127, th = tid >> 7;
    __shared__ float xs[16][35];
    __shared__ float ws[128][49];
    float acc[16] = {};
    const int og = gg*128 + o;
    for (int i0 = 0; i0 < 128; i0 += 16) {
        __syncthreads();
        for (int i = tid; i < 16*34; i += 256) {
            const int ii = i / 34, tt = i - ii*34;
            const int t = t0 - 1 + tt;
            xs[ii][tt] = (t >= 0 && t < LL)
                       ? x3[((size_t)b*LL + t)*DD + gg*128 + i0 + ii] : 0.f;
        }
        for (int i = tid; i < 128*48; i += 256) {
            const int oo = i / 48, cc = i - oo*48;
            ws[oo][cc] = tw[(size_t)(gg*128 + oo)*384 + i0*3 + cc];
        }
        __syncthreads();
#pragma unroll
        for (int ii = 0; ii < 16; ++ii) {
            const float w0 = ws[o][ii*3+0], w1 = ws[o][ii*3+1], w2 = ws[o][ii*3+2];
            float xv[18];
#pragma unroll
            for (int j = 0; j < 18; ++j) xv[j] = xs[ii][th*16 + j];
#pragma unroll
            for (int j = 0; j < 16; ++j)
                acc[j] = fmaf(w0, xv[j], fmaf(w1, xv[j+1], fmaf(w2, xv[j+2], acc[j])));
        }
    }
    const float scale = bng[og] * rsqrtf(bnv[og] + 1e-5f);
    const float shift = bnb[og] - bnm[og]*scale;
    const float cbv = tb[og];
#pragma unroll
    for (int j = 0; j < 16; ++j) {
        const int t = t0 + th*16 + j;
        const float v = (acc[j] + cbv)*scale + shift;
        const size_t oi = ((size_t)b*LL + t)*DD + og;
        out[oi] = x3[oi] + geluf(v);
    }
}

// ---------------- launch ----------------
extern "C" void kernel_launch(void* const* d_in, const int* in_sizes, int n_in,
                              void* d_out, int out_size, void* d_ws, size_t ws_size,
                              hipStream_t stream)
{
    (void)in_sizes; (void)n_in; (void)out_size; (void)ws_size;
    const float* x         = (const float*)d_in[0];
    const float* freq      = (const float*)d_in[1];
    const float* in_proj_w = (const float*)d_in[2];
    const float* conv_w    = (const float*)d_in[3];
    const float* conv_b    = (const float*)d_in[4];
    const float* x_proj_w  = (const float*)d_in[5];
    const float* dt_proj_w = (const float*)d_in[6];
    const float* dt_proj_b = (const float*)d_in[7];
    const float* A_log     = (const float*)d_in[8];
    const float* ssm_D     = (const float*)d_in[9];
    const float* out_proj_w= (const float*)d_in[10];
    const float* fg_w1     = (const float*)d_in[11];
    const float* fg_b1     = (const float*)d_in[12];
    const float* fg_w2     = (const float*)d_in[13];
    const float* fg_b2     = (const float*)d_in[14];
    const float* attn_in_w = (const float*)d_in[15];
    const float* attn_in_b = (const float*)d_in[16];
    const float* attn_out_w= (const float*)d_in[17];
    const float* attn_out_b= (const float*)d_in[18];
    const float* te_w      = (const float*)d_in[19];
    const float* te_b      = (const float*)d_in[20];
    const float* bn_g      = (const float*)d_in[21];
    const float* bn_b      = (const float*)d_in[22];
    const float* bn_m      = (const float*)d_in[23];
    const float* bn_v      = (const float*)d_in[24];
    const float* ln1w = (const float*)d_in[25];
    const float* ln1b = (const float*)d_in[26];
    const float* ln2w = (const float*)d_in[27];
    const float* ln2b = (const float*)d_in[28];
    const float* ln3w = (const float*)d_in[29];
    const float* ln3b = (const float*)d_in[30];
    float* out = (float*)d_out;

    // ---- workspace layout (lifetime-overlapped), ~150 MB ----
    float* ws = (float*)d_ws;
    const size_t SEG = 8388608;                 // 8192*1024 floats = 32 MiB
    float* S1 = ws;                             // u_raw -> delta -> x2b(bf16)
    float* S2 = ws + SEG;                       // z_raw -> x1 | x3
    float* S3 = ws + 2*SEG;                     // u_act -> x2
    float* S4 = ws + 3*SEG;                     // xb(bf16) -> u_act_bf -> ybuf_bf -> kv
    float* xdbl = ws + 4*SEG;                   // 524288 f; later attn partials
    float* sm   = ws + 4*SEG + 524288;          // small scalars (16384 f)
    float* hseg = sm + 16384;                   // 2097152 f
    float* dsum = hseg + 2097152;               // 131072 f
    unsigned short* wb = (unsigned short*)(dsum + 131072);   // bf16 weights
    unsigned short* ipw_b = wb;                 // 1048576 us (both in_proj halves)
    unsigned short* xpw_b = wb + 1048576;       // 65536 us
    unsigned short* opw_b = wb + 1114112;       // 524288 us
    unsigned short* kvw_b = wb + 1638400;       // 524288 us

    float* u_raw = S1;  float* deltab = S1;
    unsigned short* x2b = (unsigned short*)S1;
    float* z_raw = S2;  float* x1 = S2;  float* x3 = S2 + 4194304;
    float* u_act = S3;  float* x2 = S3;
    unsigned short* xb      = (unsigned short*)S4;
    unsigned short* uact_b  = (unsigned short*)S4;
    unsigned short* ybuf_b  = (unsigned short*)S4;
    float* kv = S4;
    float* hidden = sm;        // 4096
    float* g  = sm + 4096;     // 2048
    float* qb = sm + 6144;     // 2048
    float* ob = sm + 8192;     // 2048
    float* ao = sm + 10240;    // 2048
    float* po  = xdbl;         // attn partial o (xdbl dead by then)
    float* pms = xdbl + 65536; // 1024 f

    dim3 blk(256);

    // 0) bf16 conversions: inputs + weights
    cvt_bf16<<<2048, blk, 0, stream>>>(x, xb, 4194304);
    cvt_bf16<<<512,  blk, 0, stream>>>(in_proj_w, ipw_b, 1048576);
    cvt_bf16<<<32,   blk, 0, stream>>>(x_proj_w, xpw_b, 65536);
    cvt_bf16<<<256,  blk, 0, stream>>>(out_proj_w, opw_b, 524288);
    cvt_bf16<<<256,  blk, 0, stream>>>(attn_in_w + 262144, kvw_b, 524288);

    // 1) in_proj: u and z halves
    gemm_bf16g<2,2><<<dim3(8,64), blk, 0, stream>>>(xb, ipw_b,          u_raw, nullptr, DD, DD, DD, DI);
    gemm_bf16g<2,2><<<dim3(8,64), blk, 0, stream>>>(xb, ipw_b + 524288, z_raw, nullptr, DD, DD, DD, DI);
    // 2) causal depthwise conv + silu (writes f32 + bf16)
    dwconv_silu<<<(BL*DI)/256, blk, 0, stream>>>(u_raw, conv_w, conv_b, u_act, uact_b);
    // 3) x_dbl = u @ x_proj^T  (split-K 16, atomic accumulate)
    zero_f32<<<512, blk, 0, stream>>>(xdbl, BL*64);
    gemm_xdbl_sk<<<dim3(16, 32), blk, 0, stream>>>(uact_b, xpw_b, xdbl);
    // 4) delta = softplus(dt @ dt_proj^T + b)  (MFMA K=32)
    delta_gemm<<<dim3(8, 64), blk, 0, stream>>>(xdbl, dt_proj_w, dt_proj_b, deltab);
    // 5) selective scan, chunked (pass2 writes bf16 y)
    ssm_pass1<<<dim3(4, NSEG, BB), blk, 0, stream>>>(deltab, u_act, xdbl, A_log, hseg, dsum);
    ssm_seg_scan<<<256, blk, 0, stream>>>(A_log, dsum, hseg);
    ssm_pass2<<<dim3(4, NSEG, BB), blk, 0, stream>>>(deltab, u_act, z_raw, xdbl, A_log, ssm_D, hseg, ybuf_b);
    // 6) out_proj
    gemm_bf16g<2,2><<<dim3(4,64), blk, 0, stream>>>(ybuf_b, opw_b, x1, nullptr, DI, DI, DI, DD);
    // 7) freq gate MLP
    small_nt<1><<<16, blk, 0, stream>>>(freq,   fg_w1, fg_b1, hidden, BB, 2*DD, DD, DD);
    small_nt<2><<<8,  blk, 0, stream>>>(hidden, fg_w2, fg_b2, g,      BB, DD, 2*DD, 2*DD);
    // 8) ln1 * (1+g) + residual -> ln2 (writes f32 + bf16)
    ln_gate_res_ln2<<<BL, blk, 0, stream>>>(x1, x, g, ln1w, ln1b, ln2w, ln2b, x2, x2b);
    // 9) attention
    small_nt<0><<<8, blk, 0, stream>>>(freq, attn_in_w, attn_in_b, qb, BB, DD, DD, DD);
    gemm_bf16g<2,2><<<dim3(8,64), blk, 0, stream>>>(x2b, kvw_b, kv, attn_in_b + 512, DD, DD, DD, 2*DD);
    attn_part<<<dim3(ACH, BB*4), blk, 0, stream>>>(qb, kv, po, pms);
    attn_combine<<<BB*4, dim3(128), 0, stream>>>(po, pms, ob);
    small_nt<0><<<8, blk, 0, stream>>>(ob, attn_out_w, attn_out_b, ao, BB, DD, DD, DD);
    // 10) ln3(x2 + attn_broadcast)
    add_bcast_ln<<<BL, blk, 0, stream>>>(x2, ao, ln3w, ln3b, x3);
    // 11) temporal conv + BN + gelu + residual
    teconv_bn_gelu<<<dim3(LL/32, BB*4), blk, 0, stream>>>(x3, te_w, te_b, bn_g, bn_b, bn_m, bn_v, out);
}

// Round 6
// 503.000 us; speedup vs baseline: 3.9917x; 1.1542x over previous
//
#include <hip/hip_runtime.h>
#include <hip/hip_bf16.h>

// ---------------- constants ----------------
// B=4, L=2048, D=512, DI=1024, DS=16, DC=4, DTR=32, H=4, DH=128
#define BB 4
#define LL 2048
#define DD 512
#define DI 1024
#define DS 16
#define DTR 32
#define BL (BB*LL)   // 8192
#define NSEG 32
#define TSEG 64      // NSEG*TSEG == LL
#define ACH 32       // attention chunks per (b,h)

using bf16x8 = __attribute__((ext_vector_type(8))) short;
using f32x4  = __attribute__((ext_vector_type(4))) float;

// ---------------- helpers ----------------
__device__ __forceinline__ float geluf(float x) {
    return 0.5f * x * (1.f + erff(x * 0.7071067811865476f));
}

__device__ __forceinline__ unsigned short f2bf(float f) {
    unsigned u = __float_as_uint(f);
    u += 0x7FFFu + ((u >> 16) & 1u);   // round-to-nearest-even
    return (unsigned short)(u >> 16);
}

__device__ __forceinline__ void gload_lds16(const void* g, void* l) {
    __builtin_amdgcn_global_load_lds(
        (__attribute__((address_space(1))) void*)g,
        (__attribute__((address_space(3))) void*)l, 16, 0, 0);
}

__device__ __forceinline__ void block_reduce_sum2(float& a, float& b, float* sred) {
    for (int off = 32; off > 0; off >>= 1) {
        a += __shfl_down(a, off);
        b += __shfl_down(b, off);
    }
    const int lane = threadIdx.x & 63, wid = threadIdx.x >> 6;
    if (lane == 0) { sred[wid*2] = a; sred[wid*2+1] = b; }
    __syncthreads();
    a = sred[0] + sred[2] + sred[4] + sred[6];
    b = sred[1] + sred[3] + sred[5] + sred[7];
    __syncthreads();
}

__device__ __forceinline__ float block_reduce_max(float v, float* sred) {
    for (int off = 32; off > 0; off >>= 1) v = fmaxf(v, __shfl_down(v, off));
    const int lane = threadIdx.x & 63, wid = threadIdx.x >> 6;
    if (lane == 0) sred[wid] = v;
    __syncthreads();
    v = fmaxf(fmaxf(sred[0], sred[1]), fmaxf(sred[2], sred[3]));
    __syncthreads();
    return v;
}

__device__ __forceinline__ float block_reduce_sum1(float v, float* sred) {
    for (int off = 32; off > 0; off >>= 1) v += __shfl_down(v, off);
    const int lane = threadIdx.x & 63, wid = threadIdx.x >> 6;
    if (lane == 0) sred[wid] = v;
    __syncthreads();
    v = sred[0] + sred[1] + sred[2] + sred[3];
    __syncthreads();
    return v;
}

// ---------------- utility kernels ----------------
__global__ __launch_bounds__(256) void zero_f32(float* __restrict__ p, int n) {
    const int i = (blockIdx.x * 256 + threadIdx.x) * 4;
    if (i < n) { float4 z = {0.f,0.f,0.f,0.f}; *(float4*)(p + i) = z; }
}

__global__ __launch_bounds__(256) void cvt_bf16(
    const float* __restrict__ in, unsigned short* __restrict__ out, int n)
{
    const int i = (blockIdx.x * 256 + threadIdx.x) * 8;
    if (i >= n) return;
    float4 a = *(const float4*)(in + i);
    float4 b = *(const float4*)(in + i + 4);
    ushort4 h0 = { f2bf(a.x), f2bf(a.y), f2bf(a.z), f2bf(a.w) };
    ushort4 h1 = { f2bf(b.x), f2bf(b.y), f2bf(b.z), f2bf(b.w) };
    *(ushort4*)(out + i)     = h0;
    *(ushort4*)(out + i + 4) = h1;
}

// ---------------- bf16 MFMA GEMM 128x128 tile, global_load_lds staging ----------------
// C[M,N] = A[M,K] * W[N,K]^T (+bias). A,W bf16 (ushort), C f32.
// Staging LDS: linear [256][64] ushort, source pre-swizzled (chunk c^(r&7)),
// frag reads XOR back. Epilogue: alias LDS as f32 cs[64][128], transpose per
// 64-row half -> fully coalesced float4 row-segment stores (512B / half-wave).
__global__ __launch_bounds__(256) void gemm_bf16g(
    const unsigned short* __restrict__ A, const unsigned short* __restrict__ W,
    float* __restrict__ C, const float* __restrict__ bias,
    int K, int lda, int ldw, int ldc)
{
    __shared__ unsigned short lds[256 * 64];   // 32 KB; reused as cs[64][128] f32
    const int tid = threadIdx.x;
    const int bm = blockIdx.y * 128, bn = blockIdx.x * 128;
    const int lane = tid & 63, wid = tid >> 6;
    const int wr = wid >> 1, wc = wid & 1;
    const int l16 = lane & 15, lq = lane >> 4;
    const int swz = (l16 & 7) << 3;

    f32x4 acc[4][4];
#pragma unroll
    for (int mi = 0; mi < 4; ++mi)
#pragma unroll
        for (int ni = 0; ni < 4; ++ni) acc[mi][ni] = {0.f, 0.f, 0.f, 0.f};

    for (int k0 = 0; k0 < K; k0 += 64) {
#pragma unroll
        for (int it = 0; it < 8; ++it) {
            const int cid = it * 256 + tid;            // 16B-chunk id
            const int r = cid >> 3, c = cid & 7;
            const int j = c ^ (r & 7);                 // pre-swizzled source chunk
            const unsigned short* gsrc =
                (r < 128 ? A + (size_t)(bm + r) * lda : W + (size_t)(bn + r - 128) * ldw)
                + k0 + j * 8;
            gload_lds16(gsrc, &lds[(size_t)(cid & ~63) * 8]);
        }
        __syncthreads();
#pragma unroll
        for (int ks = 0; ks < 64; ks += 32) {
            bf16x8 af[4], bfr[4];
#pragma unroll
            for (int mi = 0; mi < 4; ++mi) {
                const int r = wr*64 + mi*16 + l16;
                af[mi] = *(const bf16x8*)&lds[r*64 + ((ks + lq*8) ^ swz)];
            }
#pragma unroll
            for (int ni = 0; ni < 4; ++ni) {
                const int r = 128 + wc*64 + ni*16 + l16;
                bfr[ni] = *(const bf16x8*)&lds[r*64 + ((ks + lq*8) ^ swz)];
            }
#pragma unroll
            for (int mi = 0; mi < 4; ++mi)
#pragma unroll
                for (int ni = 0; ni < 4; ++ni)
                    acc[mi][ni] = __builtin_amdgcn_mfma_f32_16x16x32_bf16(
                        af[mi], bfr[ni], acc[mi][ni], 0, 0, 0);
        }
        __syncthreads();
    }
    // bias per output column (frag: col = wc*64 + ni*16 + l16)
    float bj[4];
#pragma unroll
    for (int ni = 0; ni < 4; ++ni)
        bj[ni] = bias ? bias[bn + wc*64 + ni*16 + l16] : 0.f;
    // coalesced epilogue via LDS transpose, one 64-row half at a time
    float* cs = (float*)lds;   // [64][128]
#pragma unroll
    for (int h = 0; h < 2; ++h) {
        __syncthreads();
        if (wr == h) {
#pragma unroll
            for (int mi = 0; mi < 4; ++mi)
#pragma unroll
                for (int ni = 0; ni < 4; ++ni)
#pragma unroll
                    for (int r = 0; r < 4; ++r)
                        cs[(mi*16 + lq*4 + r)*128 + wc*64 + ni*16 + l16]
                            = acc[mi][ni][r] + bj[ni];
        }
        __syncthreads();
#pragma unroll
        for (int j = 0; j < 8; ++j) {
            const int rl = (tid >> 5) + j*8;
            const int cl = (tid & 31) * 4;
            float4 v = *(const float4*)&cs[rl*128 + cl];
            *(float4*)&C[(size_t)(bm + h*64 + rl) * ldc + bn + cl] = v;
        }
    }
}

// ---------------- xdbl split-K GEMM: C[M,64] += A-slice @ W-slice^T ----------------
// grid (16, M/256); each block one K-step of 64. BM=256, BN=64. atomicAdd epilogue.
__global__ __launch_bounds__(256) void gemm_xdbl_sk(
    const unsigned short* __restrict__ A, const unsigned short* __restrict__ W,
    float* __restrict__ C)
{
    __shared__ unsigned short lds[320 * 64];
    const int tid = threadIdx.x;
    const int k0 = blockIdx.x * 64;
    const int bm = blockIdx.y * 256;
    const int lane = tid & 63, wid = tid >> 6;     // wr = wid, wc = 0
    const int l16 = lane & 15, lq = lane >> 4;
    const int swz = (l16 & 7) << 3;
#pragma unroll
    for (int it = 0; it < 10; ++it) {
        const int cid = it * 256 + tid;
        const int r = cid >> 3, c = cid & 7;
        const int j = c ^ (r & 7);
        const unsigned short* gsrc =
            (r < 256 ? A + (size_t)(bm + r) * DI : W + (size_t)(r - 256) * DI) + k0 + j * 8;
        gload_lds16(gsrc, &lds[(size_t)(cid & ~63) * 8]);
    }
    __syncthreads();
    f32x4 acc[4][4];
#pragma unroll
    for (int mi = 0; mi < 4; ++mi)
#pragma unroll
        for (int ni = 0; ni < 4; ++ni) acc[mi][ni] = {0.f, 0.f, 0.f, 0.f};
#pragma unroll
    for (int ks = 0; ks < 64; ks += 32) {
        bf16x8 af[4], bfr[4];
#pragma unroll
        for (int mi = 0; mi < 4; ++mi) {
            const int r = wid*64 + mi*16 + l16;
            af[mi] = *(const bf16x8*)&lds[r*64 + ((ks + lq*8) ^ swz)];
        }
#pragma unroll
        for (int ni = 0; ni < 4; ++ni) {
            const int r = 256 + ni*16 + l16;
            bfr[ni] = *(const bf16x8*)&lds[r*64 + ((ks + lq*8) ^ swz)];
        }
#pragma unroll
        for (int mi = 0; mi < 4; ++mi)
#pragma unroll
            for (int ni = 0; ni < 4; ++ni)
                acc[mi][ni] = __builtin_amdgcn_mfma_f32_16x16x32_bf16(
                    af[mi], bfr[ni], acc[mi][ni], 0, 0, 0);
    }
#pragma unroll
    for (int ni = 0; ni < 4; ++ni) {
        const int col = ni*16 + l16;
#pragma unroll
        for (int mi = 0; mi < 4; ++mi) {
            const int row = bm + wid*64 + mi*16 + lq*4;
#pragma unroll
            for (int r = 0; r < 4; ++r)
                atomicAdd(&C[(size_t)(row + r) * 64 + col], acc[mi][ni][r]);
        }
    }
}

// ---------------- delta GEMM: softplus(xdbl[:,0:32] @ dt_proj_w^T + b) ----------------
// M=8192, N=1024, K=32 -> ONE mfma per 16x16 frag. 128x128 tile, grid (8, 64).
// Staging rows padded to 34 shorts. Epilogue: LDS-transpose + coalesced float4.
__global__ __launch_bounds__(256) void delta_gemm(
    const float* __restrict__ xdbl, const float* __restrict__ dtw,
    const float* __restrict__ dtb, float* __restrict__ delta)
{
    __shared__ char smem[64 * 128 * 4];   // 32 KB: staging (17.4 KB) then cs
    unsigned short* As = (unsigned short*)smem;          // [128][34]
    unsigned short* Ws = As + 128 * 34;                  // [128][34]
    const int tid = threadIdx.x;
    const int bn = blockIdx.x * 128, bm = blockIdx.y * 128;
    for (int i = tid; i < 128 * 8; i += 256) {
        const int r = i >> 3, c4 = (i & 7) * 4;
        float4 va = *(const float4*)(xdbl + (size_t)(bm + r) * 64 + c4);
        ushort4 ha = { f2bf(va.x), f2bf(va.y), f2bf(va.z), f2bf(va.w) };
        *(ushort4*)&As[r * 34 + c4] = ha;
        float4 vw = *(const float4*)(dtw + (size_t)(bn + r) * 32 + c4);
        ushort4 hw = { f2bf(vw.x), f2bf(vw.y), f2bf(vw.z), f2bf(vw.w) };
        *(ushort4*)&Ws[r * 34 + c4] = hw;
    }
    __syncthreads();
    const int lane = tid & 63, wid = tid >> 6;
    const int wr = wid >> 1, wc = wid & 1;
    const int l16 = lane & 15, lq = lane >> 4;
    bf16x8 af[4], wf[4];
#pragma unroll
    for (int mi = 0; mi < 4; ++mi)
        af[mi] = *(const bf16x8*)&As[(wr*64 + mi*16 + l16) * 34 + lq*8];
#pragma unroll
    for (int ni = 0; ni < 4; ++ni)
        wf[ni] = *(const bf16x8*)&Ws[(wc*64 + ni*16 + l16) * 34 + lq*8];
    f32x4 acc[4][4];
#pragma unroll
    for (int mi = 0; mi < 4; ++mi)
#pragma unroll
        for (int ni = 0; ni < 4; ++ni) {
            f32x4 z = {0.f, 0.f, 0.f, 0.f};
            acc[mi][ni] = __builtin_amdgcn_mfma_f32_16x16x32_bf16(af[mi], wf[ni], z, 0, 0, 0);
        }
    float bj[4];
#pragma unroll
    for (int ni = 0; ni < 4; ++ni) bj[ni] = dtb[bn + wc*64 + ni*16 + l16];
    float* cs = (float*)smem;   // [64][128]
#pragma unroll
    for (int h = 0; h < 2; ++h) {
        __syncthreads();
        if (wr == h) {
#pragma unroll
            for (int mi = 0; mi < 4; ++mi)
#pragma unroll
                for (int ni = 0; ni < 4; ++ni)
#pragma unroll
                    for (int r = 0; r < 4; ++r)
                        cs[(mi*16 + lq*4 + r)*128 + wc*64 + ni*16 + l16]
                            = acc[mi][ni][r] + bj[ni];
        }
        __syncthreads();
#pragma unroll
        for (int j = 0; j < 8; ++j) {
            const int rl = (tid >> 5) + j*8;
            const int cl = (tid & 31) * 4;
            float4 v = *(const float4*)&cs[rl*128 + cl];
            v.x = (v.x > 20.f) ? v.x : __logf(1.f + __expf(v.x));
            v.y = (v.y > 20.f) ? v.y : __logf(1.f + __expf(v.y));
            v.z = (v.z > 20.f) ? v.z : __logf(1.f + __expf(v.z));
            v.w = (v.w > 20.f) ? v.w : __logf(1.f + __expf(v.w));
            *(float4*)&delta[(size_t)(bm + h*64 + rl) * DI + bn + cl] = v;
        }
    }
}

// ---------------- small per-output-thread GEMM ----------------
// EPI: 0 none, 1 gelu, 2 sigmoid
template<int EPI>
__global__ __launch_bounds__(256) void small_nt(
    const float* __restrict__ A, const float* __restrict__ W,
    const float* __restrict__ bias, float* __restrict__ C,
    int M, int N, int K, int lda)
{
    const int idx = blockIdx.x * 256 + threadIdx.x;
    if (idx >= M * N) return;
    const int r = idx / N, c = idx - r * N;
    const float* a = A + (size_t)r * lda;
    const float* w = W + (size_t)c * K;
    float acc = 0.f;
    for (int k = 0; k < K; k += 4) {
        float4 av = *(const float4*)(a + k);
        float4 wv = *(const float4*)(w + k);
        acc += av.x*wv.x + av.y*wv.y + av.z*wv.z + av.w*wv.w;
    }
    if (bias) acc += bias[c];
    if (EPI == 1)      acc = geluf(acc);
    else if (EPI == 2) acc = 1.f / (1.f + __expf(-acc));
    C[(size_t)r * N + c] = acc;
}

// ---------------- causal depthwise conv (k=4) + SiLU (f32 + bf16 out) ----------------
__global__ void dwconv_silu(const float* __restrict__ u, const float* __restrict__ cw,
                            const float* __restrict__ cb, float* __restrict__ out,
                            unsigned short* __restrict__ out_bf)
{
    const int idx = blockIdx.x * 256 + threadIdx.x;   // < BL*DI
    const int c = idx & (DI-1);
    const int row = idx >> 10;        // b*L + t
    const int t = row & (LL-1);
    const float* w = cw + c*4;
    float s = cb[c];
#pragma unroll
    for (int j = 0; j < 4; ++j) {
        const int tt = t - 3 + j;
        if (tt >= 0) s = fmaf(u[(size_t)(row - 3 + j) * DI + c], w[j], s);
    }
    const float v = s / (1.f + __expf(-s));   // silu
    out[idx] = v;
    out_bf[idx] = f2bf(v);
}

// ---------------- SSM chunked scan ----------------
__global__ __launch_bounds__(256) void ssm_pass1(
    const float* __restrict__ delta, const float* __restrict__ uact,
    const float* __restrict__ xdbl, const float* __restrict__ A_log,
    float* __restrict__ hseg, float* __restrict__ dsum)
{
    const int tid = threadIdx.x;
    const int ch = blockIdx.x * 256 + tid;
    const int seg = blockIdx.y, b = blockIdx.z;
    const size_t rb = (size_t)b * LL + seg * TSEG;
    __shared__ float sB[TSEG][16];
    for (int i = tid; i < TSEG*16; i += 256) {
        const int tt = i >> 4, s = i & 15;
        sB[tt][s] = xdbl[(rb + tt)*64 + 32 + s];
    }
    float Av[16];
#pragma unroll
    for (int s = 0; s < 16; ++s) Av[s] = -__expf(A_log[ch*16 + s]);
    __syncthreads();
    float h[16] = {};
    float ds = 0.f;
    float d  = delta[rb*DI + ch];
    float uu = uact [rb*DI + ch];
    for (int t = 0; t < TSEG; ++t) {
        const int tn = (t + 1 < TSEG) ? t + 1 : t;
        const float dn = delta[(rb + tn)*DI + ch];
        const float un = uact [(rb + tn)*DI + ch];
        ds += d;
        const float du = d * uu;
#pragma unroll
        for (int s = 0; s < 16; ++s) {
            const float a = __expf(d * Av[s]);
            h[s] = fmaf(a, h[s], du * sB[t][s]);
        }
        d = dn; uu = un;
    }
    float* hp = hseg + (((size_t)b*NSEG + seg)*DI + ch)*16;
    float4 o0 = {h[0],h[1],h[2],h[3]},   o1 = {h[4],h[5],h[6],h[7]};
    float4 o2 = {h[8],h[9],h[10],h[11]}, o3 = {h[12],h[13],h[14],h[15]};
    *(float4*)(hp)    = o0; *(float4*)(hp+4)  = o1;
    *(float4*)(hp+8)  = o2; *(float4*)(hp+12) = o3;
    dsum[((size_t)b*NSEG + seg)*DI + ch] = ds;
}

__global__ __launch_bounds__(256) void ssm_seg_scan(
    const float* __restrict__ A_log, const float* __restrict__ dsum,
    float* __restrict__ hseg)
{
    const int idx = blockIdx.x * 256 + threadIdx.x;
    const int s = idx & 15;
    const int bc = idx >> 4;
    const int ch = bc & (DI-1);
    const int b = bc >> 10;
    const float Av = -__expf(A_log[ch*16 + s]);
    float g = 0.f;
    for (int seg = 0; seg < NSEG; ++seg) {
        const size_t soff = ((size_t)b*NSEG + seg)*DI + ch;
        const float hloc = hseg[soff*16 + s];
        const float a = __expf(Av * dsum[soff]);
        hseg[soff*16 + s] = g;
        g = fmaf(a, g, hloc);
    }
}

// pass2: seeded local scan + C-dot + u*D + silu(z) gate -> y (bf16)
__global__ __launch_bounds__(256) void ssm_pass2(
    const float* __restrict__ delta, const float* __restrict__ uact,
    const float* __restrict__ z, const float* __restrict__ xdbl,
    const float* __restrict__ A_log, const float* __restrict__ ssm_D,
    const float* __restrict__ hin, unsigned short* __restrict__ y)
{
    const int tid = threadIdx.x;
    const int ch = blockIdx.x * 256 + tid;
    const int seg = blockIdx.y, b = blockIdx.z;
    const size_t rb = (size_t)b * LL + seg * TSEG;
    __shared__ float sB[TSEG][16], sC[TSEG][16];
    for (int i = tid; i < TSEG*16; i += 256) {
        const int tt = i >> 4, s = i & 15;
        sB[tt][s] = xdbl[(rb + tt)*64 + 32 + s];
        sC[tt][s] = xdbl[(rb + tt)*64 + 48 + s];
    }
    float Av[16];
#pragma unroll
    for (int s = 0; s < 16; ++s) Av[s] = -__expf(A_log[ch*16 + s]);
    float h[16];
    const float* hp = hin + (((size_t)b*NSEG + seg)*DI + ch)*16;
#pragma unroll
    for (int s = 0; s < 16; ++s) h[s] = hp[s];
    const float Dc = ssm_D[ch];
    __syncthreads();
    float d  = delta[rb*DI + ch];
    float uu = uact [rb*DI + ch];
    float zz = z    [rb*DI + ch];
    for (int t = 0; t < TSEG; ++t) {
        const int tn = (t + 1 < TSEG) ? t + 1 : t;
        const float dn = delta[(rb + tn)*DI + ch];
        const float un = uact [(rb + tn)*DI + ch];
        const float zn = z    [(rb + tn)*DI + ch];
        const float du = d * uu;
        float p = 0.f;
#pragma unroll
        for (int s = 0; s < 16; ++s) {
            const float a = __expf(d * Av[s]);
            h[s] = fmaf(a, h[s], du * sB[t][s]);
            p = fmaf(h[s], sC[t][s], p);
        }
        const float sil = zz / (1.f + __expf(-zz));
        y[(rb + t)*DI + ch] = f2bf((p + uu*Dc) * sil);
        d = dn; uu = un; zz = zn;
    }
}

// ---------------- ln1 * (1+g) + residual -> ln2 (f32 + bf16 out) ----------------
__global__ __launch_bounds__(256) void ln_gate_res_ln2(
    const float* __restrict__ x1raw, const float* __restrict__ xres,
    const float* __restrict__ g,
    const float* __restrict__ w1, const float* __restrict__ b1,
    const float* __restrict__ w2, const float* __restrict__ b2,
    float* __restrict__ x2, unsigned short* __restrict__ x2b)
{
    __shared__ float sred[8];
    const int row = blockIdx.x;
    const int b = row >> 11;
    const int c = threadIdx.x * 2;
    const size_t base = (size_t)row * DD;
    float2 v = *(const float2*)(x1raw + base + c);
    float s = v.x + v.y, ss = v.x*v.x + v.y*v.y;
    block_reduce_sum2(s, ss, sred);
    float mean = s * (1.f/DD);
    float rs = rsqrtf(fmaxf(ss * (1.f/DD) - mean*mean, 0.f) + 1e-5f);
    float2 xr = *(const float2*)(xres + base + c);
    float y0 = ((v.x - mean)*rs*w1[c]   + b1[c]  ) * (1.f + g[b*DD + c])   + xr.x;
    float y1 = ((v.y - mean)*rs*w1[c+1] + b1[c+1]) * (1.f + g[b*DD + c+1]) + xr.y;
    s = y0 + y1; ss = y0*y0 + y1*y1;
    block_reduce_sum2(s, ss, sred);
    mean = s * (1.f/DD);
    rs = rsqrtf(fmaxf(ss * (1.f/DD) - mean*mean, 0.f) + 1e-5f);
    float2 o;
    o.x = (y0 - mean)*rs*w2[c]   + b2[c];
    o.y = (y1 - mean)*rs*w2[c+1] + b2[c+1];
    *(float2*)(x2 + base + c) = o;
    ushort2 ob = { f2bf(o.x), f2bf(o.y) };
    *(ushort2*)(x2b + base + c) = ob;
}

// ---------------- x + broadcast(add[b]) -> LN ----------------
__global__ __launch_bounds__(256) void add_bcast_ln(
    const float* __restrict__ xin, const float* __restrict__ addb,
    const float* __restrict__ w, const float* __restrict__ bb,
    float* __restrict__ out)
{
    __shared__ float sred[8];
    const int row = blockIdx.x, b = row >> 11, c = threadIdx.x * 2;
    const size_t base = (size_t)row * DD;
    float2 v = *(const float2*)(xin + base + c);
    v.x += addb[b*DD + c];
    v.y += addb[b*DD + c + 1];
    float s = v.x + v.y, ss = v.x*v.x + v.y*v.y;
    block_reduce_sum2(s, ss, sred);
    float mean = s * (1.f/DD);
    float rs = rsqrtf(fmaxf(ss * (1.f/DD) - mean*mean, 0.f) + 1e-5f);
    float2 o = { (v.x - mean)*rs*w[c] + bb[c], (v.y - mean)*rs*w[c+1] + bb[c+1] };
    *(float2*)(out + base + c) = o;
}

// ---------------- cross-attention, flash-split ----------------
__global__ __launch_bounds__(256) void attn_part(
    const float* __restrict__ q, const float* __restrict__ kv,
    float* __restrict__ po, float* __restrict__ pms)
{
    const int chunk = blockIdx.x, bh = blockIdx.y;
    const int b = bh >> 2, h = bh & 3;
    const int tid = threadIdx.x;
    __shared__ float sq[128];
    __shared__ float se[64];
    __shared__ float sred[8];
    __shared__ float opart[2][128];
    if (tid < 128) sq[tid] = q[b*DD + h*128 + tid];
    __syncthreads();
    const int r = tid >> 2, p = tid & 3;   // row 0..63, quarter 0..3
    const int trow = chunk*64 + r;
    const float* kr = kv + ((size_t)(b*LL + trow))*1024 + h*128 + p*32;
    float dot = 0.f;
#pragma unroll
    for (int d = 0; d < 32; d += 4) {
        float4 k4 = *(const float4*)(kr + d);
        dot += sq[p*32+d]*k4.x + sq[p*32+d+1]*k4.y + sq[p*32+d+2]*k4.z + sq[p*32+d+3]*k4.w;
    }
    dot += __shfl_xor(dot, 1);
    dot += __shfl_xor(dot, 2);
    if (p == 0) se[r] = dot * 0.088388347648318447f;   // 1/sqrt(128)
    __syncthreads();
    const float lm = (tid < 64) ? se[tid] : -1e30f;
    const float m = block_reduce_max(lm, sred);
    float le = 0.f;
    if (tid < 64) { le = __expf(se[tid] - m); se[tid] = le; }
    const float ssum = block_reduce_sum1(le, sred);
    const int d = tid & 127, half = tid >> 7;
    float acc = 0.f;
    for (int rr = half; rr < 64; rr += 2)
        acc = fmaf(se[rr], kv[((size_t)(b*LL + chunk*64 + rr))*1024 + 512 + h*128 + d], acc);
    opart[half][d] = acc;
    __syncthreads();
    if (tid < 128) po[((size_t)bh*ACH + chunk)*128 + tid] = opart[0][tid] + opart[1][tid];
    if (tid == 0) {
        pms[(bh*ACH + chunk)*2]     = m;
        pms[(bh*ACH + chunk)*2 + 1] = ssum;
    }
}

__global__ __launch_bounds__(128) void attn_combine(
    const float* __restrict__ po, const float* __restrict__ pms,
    float* __restrict__ ob)
{
    const int bh = blockIdx.x, tid = threadIdx.x;
    __shared__ float sm_[ACH], ss_[ACH];
    if (tid < ACH) {
        sm_[tid] = pms[(bh*ACH + tid)*2];
        ss_[tid] = pms[(bh*ACH + tid)*2 + 1];
    }
    __syncthreads();
    float M = -1e30f;
#pragma unroll
    for (int i = 0; i < ACH; ++i) M = fmaxf(M, sm_[i]);
    float S = 0.f, acc = 0.f;
    for (int i = 0; i < ACH; ++i) {
        const float e = __expf(sm_[i] - M);
        S += e * ss_[i];
        acc = fmaf(e, po[((size_t)bh*ACH + i)*128 + tid], acc);
    }
    const int b = bh >> 2, h = bh & 3;
    ob[b*DD + h*128 + tid] = acc / S;
}

// ---------------- grouped temporal conv (k=3,pad=1,groups=4) + BN + GELU + residual ----------------
__global__ __launch_bounds__(256) void teconv_bn_gelu(
    const float* __restrict__ x3, const float* __restrict__ tw,
    const float* __restrict__ tb,
    const float* __restrict__ bng, const float* __restrict__ bnb,
    const float* __restrict__ bnm, const float* __restrict__ bnv,
    float* __restrict__ out)
{
    const int b = blockIdx.y >> 2, gg = blockIdx.y & 3;
    const int t0 = blockIdx.x * 32;
    const int tid = threadIdx.x;
    const int o = tid & 127, th = tid >> 7;
    __shared__ float xs[16][35];
    __shared__ float ws[128][49];
    float acc[16] = {};
    const int og = gg*128 + o;
    for (int i0 = 0; i0 < 128; i0 += 16) {
        __syncthreads();
        for (int i = tid; i < 16*34; i += 256) {
            const int ii = i / 34, tt = i - ii*34;
            const int t = t0 - 1 + tt;
            xs[ii][tt] = (t >= 0 && t < LL)
                       ? x3[((size_t)b*LL + t)*DD + gg*128 + i0 + ii] : 0.f;
        }
        for (int i = tid; i < 128*48; i += 256) {
            const int oo = i / 48, cc = i - oo*48;
            ws[oo][cc] = tw[(size_t)(gg*128 + oo)*384 + i0*3 + cc];
        }
        __syncthreads();
#pragma unroll
        for (int ii = 0; ii < 16; ++ii) {
            const float w0 = ws[o][ii*3+0], w1 = ws[o][ii*3+1], w2 = ws[o][ii*3+2];
            float xv[18];
#pragma unroll
            for (int j = 0; j < 18; ++j) xv[j] = xs[ii][th*16 + j];
#pragma unroll
            for (int j = 0; j < 16; ++j)
                acc[j] = fmaf(w0, xv[j], fmaf(w1, xv[j+1], fmaf(w2, xv[j+2], acc[j])));
        }
    }
    const float scale = bng[og] * rsqrtf(bnv[og] + 1e-5f);
    const float shift = bnb[og] - bnm[og]*scale;
    const float cbv = tb[og];
#pragma unroll
    for (int j = 0; j < 16; ++j) {
        const int t = t0 + th*16 + j;
        const float v = (acc[j] + cbv)*scale + shift;
        const size_t oi = ((size_t)b*LL + t)*DD + og;
        out[oi] = x3[oi] + geluf(v);
    }
}

// ---------------- launch ----------------
extern "C" void kernel_launch(void* const* d_in, const int* in_sizes, int n_in,
                              void* d_out, int out_size, void* d_ws, size_t ws_size,
                              hipStream_t stream)
{
    (void)in_sizes; (void)n_in; (void)out_size; (void)ws_size;
    const float* x         = (const float*)d_in[0];
    const float* freq      = (const float*)d_in[1];
    const float* in_proj_w = (const float*)d_in[2];
    const float* conv_w    = (const float*)d_in[3];
    const float* conv_b    = (const float*)d_in[4];
    const float* x_proj_w  = (const float*)d_in[5];
    const float* dt_proj_w = (const float*)d_in[6];
    const float* dt_proj_b = (const float*)d_in[7];
    const float* A_log     = (const float*)d_in[8];
    const float* ssm_D     = (const float*)d_in[9];
    const float* out_proj_w= (const float*)d_in[10];
    const float* fg_w1     = (const float*)d_in[11];
    const float* fg_b1     = (const float*)d_in[12];
    const float* fg_w2     = (const float*)d_in[13];
    const float* fg_b2     = (const float*)d_in[14];
    const float* attn_in_w = (const float*)d_in[15];
    const float* attn_in_b = (const float*)d_in[16];
    const float* attn_out_w= (const float*)d_in[17];
    const float* attn_out_b= (const float*)d_in[18];
    const float* te_w      = (const float*)d_in[19];
    const float* te_b      = (const float*)d_in[20];
    const float* bn_g      = (const float*)d_in[21];
    const float* bn_b      = (const float*)d_in[22];
    const float* bn_m      = (const float*)d_in[23];
    const float* bn_v      = (const float*)d_in[24];
    const float* ln1w = (const float*)d_in[25];
    const float* ln1b = (const float*)d_in[26];
    const float* ln2w = (const float*)d_in[27];
    const float* ln2b = (const float*)d_in[28];
    const float* ln3w = (const float*)d_in[29];
    const float* ln3b = (const float*)d_in[30];
    float* out = (float*)d_out;

    // ---- workspace layout (lifetime-overlapped), ~150 MB ----
    float* ws = (float*)d_ws;
    const size_t SEG = 8388608;                 // 8192*1024 floats = 32 MiB
    float* S1 = ws;                             // u_raw -> delta -> x2b(bf16)
    float* S2 = ws + SEG;                       // z_raw -> x1 | x3
    float* S3 = ws + 2*SEG;                     // u_act -> x2
    float* S4 = ws + 3*SEG;                     // xb(bf16) -> u_act_bf -> ybuf_bf -> kv
    float* xdbl = ws + 4*SEG;                   // 524288 f; later attn partials
    float* sm   = ws + 4*SEG + 524288;          // small scalars (16384 f)
    float* hseg = sm + 16384;                   // 2097152 f
    float* dsum = hseg + 2097152;               // 131072 f
    unsigned short* wb = (unsigned short*)(dsum + 131072);   // bf16 weights
    unsigned short* ipw_b = wb;                 // 1048576 us (both in_proj halves)
    unsigned short* xpw_b = wb + 1048576;       // 65536 us
    unsigned short* opw_b = wb + 1114112;       // 524288 us
    unsigned short* kvw_b = wb + 1638400;       // 524288 us

    float* u_raw = S1;  float* deltab = S1;
    unsigned short* x2b = (unsigned short*)S1;
    float* z_raw = S2;  float* x1 = S2;  float* x3 = S2 + 4194304;
    float* u_act = S3;  float* x2 = S3;
    unsigned short* xb      = (unsigned short*)S4;
    unsigned short* uact_b  = (unsigned short*)S4;
    unsigned short* ybuf_b  = (unsigned short*)S4;
    float* kv = S4;
    float* hidden = sm;        // 4096
    float* g  = sm + 4096;     // 2048
    float* qb = sm + 6144;     // 2048
    float* ob = sm + 8192;     // 2048
    float* ao = sm + 10240;    // 2048
    float* po  = xdbl;         // attn partial o (xdbl dead by then)
    float* pms = xdbl + 65536; // 1024 f

    dim3 blk(256);

    // 0) bf16 conversions: inputs + weights
    cvt_bf16<<<2048, blk, 0, stream>>>(x, xb, 4194304);
    cvt_bf16<<<512,  blk, 0, stream>>>(in_proj_w, ipw_b, 1048576);
    cvt_bf16<<<32,   blk, 0, stream>>>(x_proj_w, xpw_b, 65536);
    cvt_bf16<<<256,  blk, 0, stream>>>(out_proj_w, opw_b, 524288);
    cvt_bf16<<<256,  blk, 0, stream>>>(attn_in_w + 262144, kvw_b, 524288);

    // 1) in_proj: u and z halves
    gemm_bf16g<<<dim3(8,64), blk, 0, stream>>>(xb, ipw_b,          u_raw, nullptr, DD, DD, DD, DI);
    gemm_bf16g<<<dim3(8,64), blk, 0, stream>>>(xb, ipw_b + 524288, z_raw, nullptr, DD, DD, DD, DI);
    // 2) causal depthwise conv + silu (writes f32 + bf16)
    dwconv_silu<<<(BL*DI)/256, blk, 0, stream>>>(u_raw, conv_w, conv_b, u_act, uact_b);
    // 3) x_dbl = u @ x_proj^T  (split-K 16, atomic accumulate)
    zero_f32<<<512, blk, 0, stream>>>(xdbl, BL*64);
    gemm_xdbl_sk<<<dim3(16, 32), blk, 0, stream>>>(uact_b, xpw_b, xdbl);
    // 4) delta = softplus(dt @ dt_proj^T + b)  (MFMA K=32, coalesced epilogue)
    delta_gemm<<<dim3(8, 64), blk, 0, stream>>>(xdbl, dt_proj_w, dt_proj_b, deltab);
    // 5) selective scan, chunked (pass2 writes bf16 y)
    ssm_pass1<<<dim3(4, NSEG, BB), blk, 0, stream>>>(deltab, u_act, xdbl, A_log, hseg, dsum);
    ssm_seg_scan<<<256, blk, 0, stream>>>(A_log, dsum, hseg);
    ssm_pass2<<<dim3(4, NSEG, BB), blk, 0, stream>>>(deltab, u_act, z_raw, xdbl, A_log, ssm_D, hseg, ybuf_b);
    // 6) out_proj
    gemm_bf16g<<<dim3(4,64), blk, 0, stream>>>(ybuf_b, opw_b, x1, nullptr, DI, DI, DI, DD);
    // 7) freq gate MLP
    small_nt<1><<<16, blk, 0, stream>>>(freq,   fg_w1, fg_b1, hidden, BB, 2*DD, DD, DD);
    small_nt<2><<<8,  blk, 0, stream>>>(hidden, fg_w2, fg_b2, g,      BB, DD, 2*DD, 2*DD);
    // 8) ln1 * (1+g) + residual -> ln2 (writes f32 + bf16)
    ln_gate_res_ln2<<<BL, blk, 0, stream>>>(x1, x, g, ln1w, ln1b, ln2w, ln2b, x2, x2b);
    // 9) attention
    small_nt<0><<<8, blk, 0, stream>>>(freq, attn_in_w, attn_in_b, qb, BB, DD, DD, DD);
    gemm_bf16g<<<dim3(8,64), blk, 0, stream>>>(x2b, kvw_b, kv, attn_in_b + 512, DD, DD, DD, 2*DD);
    attn_part<<<dim3(ACH, BB*4), blk, 0, stream>>>(qb, kv, po, pms);
    attn_combine<<<BB*4, dim3(128), 0, stream>>>(po, pms, ob);
    small_nt<0><<<8, blk, 0, stream>>>(ob, attn_out_w, attn_out_b, ao, BB, DD, DD, DD);
    // 10) ln3(x2 + attn_broadcast)
    add_bcast_ln<<<BL, blk, 0, stream>>>(x2, ao, ln3w, ln3b, x3);
    // 11) temporal conv + BN + gelu + residual
    teconv_bn_gelu<<<dim3(LL/32, BB*4), blk, 0, stream>>>(x3, te_w, te_b, bn_g, bn_b, bn_m, bn_v, out);
}

// Round 8
// 456.233 us; speedup vs baseline: 4.4009x; 1.1025x over previous
//
#include <hip/hip_runtime.h>
#include <hip/hip_bf16.h>

// ---------------- constants ----------------
// B=4, L=2048, D=512, DI=1024, DS=16, DC=4, DTR=32, H=4, DH=128
#define BB 4
#define LL 2048
#define DD 512
#define DI 1024
#define DS 16
#define DTR 32
#define BL (BB*LL)   // 8192
#define NSEG 32
#define TSEG 64      // NSEG*TSEG == LL
#define ACH 32       // attention chunks per (b,h)

using bf16x8 = __attribute__((ext_vector_type(8))) short;
using f32x4  = __attribute__((ext_vector_type(4))) float;

// ---------------- helpers ----------------
__device__ __forceinline__ float geluf(float x) {
    return 0.5f * x * (1.f + erff(x * 0.7071067811865476f));
}

__device__ __forceinline__ unsigned short f2bf(float f) {
    unsigned u = __float_as_uint(f);
    u += 0x7FFFu + ((u >> 16) & 1u);   // round-to-nearest-even
    return (unsigned short)(u >> 16);
}

__device__ __forceinline__ void gload_lds16(const void* g, void* l) {
    __builtin_amdgcn_global_load_lds(
        (__attribute__((address_space(1))) void*)g,
        (__attribute__((address_space(3))) void*)l, 16, 0, 0);
}

__device__ __forceinline__ void block_reduce_sum2(float& a, float& b, float* sred) {
    for (int off = 32; off > 0; off >>= 1) {
        a += __shfl_down(a, off);
        b += __shfl_down(b, off);
    }
    const int lane = threadIdx.x & 63, wid = threadIdx.x >> 6;
    if (lane == 0) { sred[wid*2] = a; sred[wid*2+1] = b; }
    __syncthreads();
    a = sred[0] + sred[2] + sred[4] + sred[6];
    b = sred[1] + sred[3] + sred[5] + sred[7];
    __syncthreads();
}

__device__ __forceinline__ float block_reduce_max(float v, float* sred) {
    for (int off = 32; off > 0; off >>= 1) v = fmaxf(v, __shfl_down(v, off));
    const int lane = threadIdx.x & 63, wid = threadIdx.x >> 6;
    if (lane == 0) sred[wid] = v;
    __syncthreads();
    v = fmaxf(fmaxf(sred[0], sred[1]), fmaxf(sred[2], sred[3]));
    __syncthreads();
    return v;
}

__device__ __forceinline__ float block_reduce_sum1(float v, float* sred) {
    for (int off = 32; off > 0; off >>= 1) v += __shfl_down(v, off);
    const int lane = threadIdx.x & 63, wid = threadIdx.x >> 6;
    if (lane == 0) sred[wid] = v;
    __syncthreads();
    v = sred[0] + sred[1] + sred[2] + sred[3];
    __syncthreads();
    return v;
}

// ---------------- utility kernels ----------------
__global__ __launch_bounds__(256) void zero_f32(float* __restrict__ p, int n) {
    const int i = (blockIdx.x * 256 + threadIdx.x) * 4;
    if (i < n) { float4 z = {0.f,0.f,0.f,0.f}; *(float4*)(p + i) = z; }
}

__global__ __launch_bounds__(256) void cvt_bf16(
    const float* __restrict__ in, unsigned short* __restrict__ out, int n)
{
    const int i = (blockIdx.x * 256 + threadIdx.x) * 8;
    if (i >= n) return;
    float4 a = *(const float4*)(in + i);
    float4 b = *(const float4*)(in + i + 4);
    ushort4 h0 = { f2bf(a.x), f2bf(a.y), f2bf(a.z), f2bf(a.w) };
    ushort4 h1 = { f2bf(b.x), f2bf(b.y), f2bf(b.z), f2bf(b.w) };
    *(ushort4*)(out + i)     = h0;
    *(ushort4*)(out + i + 4) = h1;
}

// te_conv_w [512][128][3] -> wt [512][384] bf16, col = j*128 + ic
__global__ __launch_bounds__(256) void cvt_tew(
    const float* __restrict__ tw, unsigned short* __restrict__ wt)
{
    const int i = blockIdx.x * 256 + threadIdx.x;
    if (i >= 512 * 384) return;
    const int oc = i / 384, rem = i - oc * 384;
    const int j = rem >> 7, ic = rem & 127;
    wt[i] = f2bf(tw[oc * 384 + ic * 3 + j]);
}

// ---------------- bf16 MFMA GEMM 128x128 tile, global_load_lds staging ----------------
__global__ __launch_bounds__(256) void gemm_bf16g(
    const unsigned short* __restrict__ A, const unsigned short* __restrict__ W,
    float* __restrict__ C, const float* __restrict__ bias,
    int K, int lda, int ldw, int ldc)
{
    __shared__ unsigned short lds[256 * 64];   // 32 KB; reused as cs[64][128] f32
    const int tid = threadIdx.x;
    const int bm = blockIdx.y * 128, bn = blockIdx.x * 128;
    const int lane = tid & 63, wid = tid >> 6;
    const int wr = wid >> 1, wc = wid & 1;
    const int l16 = lane & 15, lq = lane >> 4;
    const int swz = (l16 & 7) << 3;

    f32x4 acc[4][4];
#pragma unroll
    for (int mi = 0; mi < 4; ++mi)
#pragma unroll
        for (int ni = 0; ni < 4; ++ni) acc[mi][ni] = {0.f, 0.f, 0.f, 0.f};

    for (int k0 = 0; k0 < K; k0 += 64) {
#pragma unroll
        for (int it = 0; it < 8; ++it) {
            const int cid = it * 256 + tid;            // 16B-chunk id
            const int r = cid >> 3, c = cid & 7;
            const int j = c ^ (r & 7);                 // pre-swizzled source chunk
            const unsigned short* gsrc =
                (r < 128 ? A + (size_t)(bm + r) * lda : W + (size_t)(bn + r - 128) * ldw)
                + k0 + j * 8;
            gload_lds16(gsrc, &lds[(size_t)(cid & ~63) * 8]);
        }
        __syncthreads();
#pragma unroll
        for (int ks = 0; ks < 64; ks += 32) {
            bf16x8 af[4], bfr[4];
#pragma unroll
            for (int mi = 0; mi < 4; ++mi) {
                const int r = wr*64 + mi*16 + l16;
                af[mi] = *(const bf16x8*)&lds[r*64 + ((ks + lq*8) ^ swz)];
            }
#pragma unroll
            for (int ni = 0; ni < 4; ++ni) {
                const int r = 128 + wc*64 + ni*16 + l16;
                bfr[ni] = *(const bf16x8*)&lds[r*64 + ((ks + lq*8) ^ swz)];
            }
#pragma unroll
            for (int mi = 0; mi < 4; ++mi)
#pragma unroll
                for (int ni = 0; ni < 4; ++ni)
                    acc[mi][ni] = __builtin_amdgcn_mfma_f32_16x16x32_bf16(
                        af[mi], bfr[ni], acc[mi][ni], 0, 0, 0);
        }
        __syncthreads();
    }
    float bj[4];
#pragma unroll
    for (int ni = 0; ni < 4; ++ni)
        bj[ni] = bias ? bias[bn + wc*64 + ni*16 + l16] : 0.f;
    float* cs = (float*)lds;   // [64][128]
#pragma unroll
    for (int h = 0; h < 2; ++h) {
        __syncthreads();
        if (wr == h) {
#pragma unroll
            for (int mi = 0; mi < 4; ++mi)
#pragma unroll
                for (int ni = 0; ni < 4; ++ni)
#pragma unroll
                    for (int r = 0; r < 4; ++r)
                        cs[(mi*16 + lq*4 + r)*128 + wc*64 + ni*16 + l16]
                            = acc[mi][ni][r] + bj[ni];
        }
        __syncthreads();
#pragma unroll
        for (int j = 0; j < 8; ++j) {
            const int rl = (tid >> 5) + j*8;
            const int cl = (tid & 31) * 4;
            float4 v = *(const float4*)&cs[rl*128 + cl];
            *(float4*)&C[(size_t)(bm + h*64 + rl) * ldc + bn + cl] = v;
        }
    }
}

// ---------------- xdbl split-K GEMM: C[M,64] += A-slice @ W-slice^T ----------------
__global__ __launch_bounds__(256) void gemm_xdbl_sk(
    const unsigned short* __restrict__ A, const unsigned short* __restrict__ W,
    float* __restrict__ C)
{
    __shared__ unsigned short lds[320 * 64];
    const int tid = threadIdx.x;
    const int k0 = blockIdx.x * 64;
    const int bm = blockIdx.y * 256;
    const int lane = tid & 63, wid = tid >> 6;
    const int l16 = lane & 15, lq = lane >> 4;
    const int swz = (l16 & 7) << 3;
#pragma unroll
    for (int it = 0; it < 10; ++it) {
        const int cid = it * 256 + tid;
        const int r = cid >> 3, c = cid & 7;
        const int j = c ^ (r & 7);
        const unsigned short* gsrc =
            (r < 256 ? A + (size_t)(bm + r) * DI : W + (size_t)(r - 256) * DI) + k0 + j * 8;
        gload_lds16(gsrc, &lds[(size_t)(cid & ~63) * 8]);
    }
    __syncthreads();
    f32x4 acc[4][4];
#pragma unroll
    for (int mi = 0; mi < 4; ++mi)
#pragma unroll
        for (int ni = 0; ni < 4; ++ni) acc[mi][ni] = {0.f, 0.f, 0.f, 0.f};
#pragma unroll
    for (int ks = 0; ks < 64; ks += 32) {
        bf16x8 af[4], bfr[4];
#pragma unroll
        for (int mi = 0; mi < 4; ++mi) {
            const int r = wid*64 + mi*16 + l16;
            af[mi] = *(const bf16x8*)&lds[r*64 + ((ks + lq*8) ^ swz)];
        }
#pragma unroll
        for (int ni = 0; ni < 4; ++ni) {
            const int r = 256 + ni*16 + l16;
            bfr[ni] = *(const bf16x8*)&lds[r*64 + ((ks + lq*8) ^ swz)];
        }
#pragma unroll
        for (int mi = 0; mi < 4; ++mi)
#pragma unroll
            for (int ni = 0; ni < 4; ++ni)
                acc[mi][ni] = __builtin_amdgcn_mfma_f32_16x16x32_bf16(
                    af[mi], bfr[ni], acc[mi][ni], 0, 0, 0);
    }
#pragma unroll
    for (int ni = 0; ni < 4; ++ni) {
        const int col = ni*16 + l16;
#pragma unroll
        for (int mi = 0; mi < 4; ++mi) {
            const int row = bm + wid*64 + mi*16 + lq*4;
#pragma unroll
            for (int r = 0; r < 4; ++r)
                atomicAdd(&C[(size_t)(row + r) * 64 + col], acc[mi][ni][r]);
        }
    }
}

// ---------------- delta GEMM: softplus(xdbl[:,0:32] @ dt_proj_w^T + b) ----------------
__global__ __launch_bounds__(256) void delta_gemm(
    const float* __restrict__ xdbl, const float* __restrict__ dtw,
    const float* __restrict__ dtb, float* __restrict__ delta)
{
    __shared__ char smem[64 * 128 * 4];   // 32 KB: staging then cs
    unsigned short* As = (unsigned short*)smem;          // [128][34]
    unsigned short* Ws = As + 128 * 34;                  // [128][34]
    const int tid = threadIdx.x;
    const int bn = blockIdx.x * 128, bm = blockIdx.y * 128;
    for (int i = tid; i < 128 * 8; i += 256) {
        const int r = i >> 3, c4 = (i & 7) * 4;
        float4 va = *(const float4*)(xdbl + (size_t)(bm + r) * 64 + c4);
        ushort4 ha = { f2bf(va.x), f2bf(va.y), f2bf(va.z), f2bf(va.w) };
        *(ushort4*)&As[r * 34 + c4] = ha;
        float4 vw = *(const float4*)(dtw + (size_t)(bn + r) * 32 + c4);
        ushort4 hw = { f2bf(vw.x), f2bf(vw.y), f2bf(vw.z), f2bf(vw.w) };
        *(ushort4*)&Ws[r * 34 + c4] = hw;
    }
    __syncthreads();
    const int lane = tid & 63, wid = tid >> 6;
    const int wr = wid >> 1, wc = wid & 1;
    const int l16 = lane & 15, lq = lane >> 4;
    bf16x8 af[4], wf[4];
#pragma unroll
    for (int mi = 0; mi < 4; ++mi)
        af[mi] = *(const bf16x8*)&As[(wr*64 + mi*16 + l16) * 34 + lq*8];
#pragma unroll
    for (int ni = 0; ni < 4; ++ni)
        wf[ni] = *(const bf16x8*)&Ws[(wc*64 + ni*16 + l16) * 34 + lq*8];
    f32x4 acc[4][4];
#pragma unroll
    for (int mi = 0; mi < 4; ++mi)
#pragma unroll
        for (int ni = 0; ni < 4; ++ni) {
            f32x4 z = {0.f, 0.f, 0.f, 0.f};
            acc[mi][ni] = __builtin_amdgcn_mfma_f32_16x16x32_bf16(af[mi], wf[ni], z, 0, 0, 0);
        }
    float bj[4];
#pragma unroll
    for (int ni = 0; ni < 4; ++ni) bj[ni] = dtb[bn + wc*64 + ni*16 + l16];
    float* cs = (float*)smem;   // [64][128]
#pragma unroll
    for (int h = 0; h < 2; ++h) {
        __syncthreads();
        if (wr == h) {
#pragma unroll
            for (int mi = 0; mi < 4; ++mi)
#pragma unroll
                for (int ni = 0; ni < 4; ++ni)
#pragma unroll
                    for (int r = 0; r < 4; ++r)
                        cs[(mi*16 + lq*4 + r)*128 + wc*64 + ni*16 + l16]
                            = acc[mi][ni][r] + bj[ni];
        }
        __syncthreads();
#pragma unroll
        for (int j = 0; j < 8; ++j) {
            const int rl = (tid >> 5) + j*8;
            const int cl = (tid & 31) * 4;
            float4 v = *(const float4*)&cs[rl*128 + cl];
            v.x = (v.x > 20.f) ? v.x : __logf(1.f + __expf(v.x));
            v.y = (v.y > 20.f) ? v.y : __logf(1.f + __expf(v.y));
            v.z = (v.z > 20.f) ? v.z : __logf(1.f + __expf(v.z));
            v.w = (v.w > 20.f) ? v.w : __logf(1.f + __expf(v.w));
            *(float4*)&delta[(size_t)(bm + h*64 + rl) * DI + bn + cl] = v;
        }
    }
}

// ---------------- small per-output-thread GEMM ----------------
template<int EPI>
__global__ __launch_bounds__(256) void small_nt(
    const float* __restrict__ A, const float* __restrict__ W,
    const float* __restrict__ bias, float* __restrict__ C,
    int M, int N, int K, int lda)
{
    const int idx = blockIdx.x * 256 + threadIdx.x;
    if (idx >= M * N) return;
    const int r = idx / N, c = idx - r * N;
    const float* a = A + (size_t)r * lda;
    const float* w = W + (size_t)c * K;
    float acc = 0.f;
    for (int k = 0; k < K; k += 4) {
        float4 av = *(const float4*)(a + k);
        float4 wv = *(const float4*)(w + k);
        acc += av.x*wv.x + av.y*wv.y + av.z*wv.z + av.w*wv.w;
    }
    if (bias) acc += bias[c];
    if (EPI == 1)      acc = geluf(acc);
    else if (EPI == 2) acc = 1.f / (1.f + __expf(-acc));
    C[(size_t)r * N + c] = acc;
}

// ---------------- causal depthwise conv (k=4) + SiLU (f32 + bf16 out) ----------------
__global__ void dwconv_silu(const float* __restrict__ u, const float* __restrict__ cw,
                            const float* __restrict__ cb, float* __restrict__ out,
                            unsigned short* __restrict__ out_bf)
{
    const int idx = blockIdx.x * 256 + threadIdx.x;   // < BL*DI
    const int c = idx & (DI-1);
    const int row = idx >> 10;        // b*L + t
    const int t = row & (LL-1);
    const float* w = cw + c*4;
    float s = cb[c];
#pragma unroll
    for (int j = 0; j < 4; ++j) {
        const int tt = t - 3 + j;
        if (tt >= 0) s = fmaf(u[(size_t)(row - 3 + j) * DI + c], w[j], s);
    }
    const float v = s / (1.f + __expf(-s));   // silu
    out[idx] = v;
    out_bf[idx] = f2bf(v);
}

// ---------------- SSM chunked scan ----------------
__global__ __launch_bounds__(256) void ssm_pass1(
    const float* __restrict__ delta, const float* __restrict__ uact,
    const float* __restrict__ xdbl, const float* __restrict__ A_log,
    float* __restrict__ hseg, float* __restrict__ dsum)
{
    const int tid = threadIdx.x;
    const int ch = blockIdx.x * 256 + tid;
    const int seg = blockIdx.y, b = blockIdx.z;
    const size_t rb = (size_t)b * LL + seg * TSEG;
    __shared__ float sB[TSEG][16];
    for (int i = tid; i < TSEG*16; i += 256) {
        const int tt = i >> 4, s = i & 15;
        sB[tt][s] = xdbl[(rb + tt)*64 + 32 + s];
    }
    float Av[16];
#pragma unroll
    for (int s = 0; s < 16; ++s) Av[s] = -__expf(A_log[ch*16 + s]);
    __syncthreads();
    float h[16] = {};
    float ds = 0.f;
    float d  = delta[rb*DI + ch];
    float uu = uact [rb*DI + ch];
    for (int t = 0; t < TSEG; ++t) {
        const int tn = (t + 1 < TSEG) ? t + 1 : t;
        const float dn = delta[(rb + tn)*DI + ch];
        const float un = uact [(rb + tn)*DI + ch];
        ds += d;
        const float du = d * uu;
#pragma unroll
        for (int s = 0; s < 16; ++s) {
            const float a = __expf(d * Av[s]);
            h[s] = fmaf(a, h[s], du * sB[t][s]);
        }
        d = dn; uu = un;
    }
    float* hp = hseg + (((size_t)b*NSEG + seg)*DI + ch)*16;
    float4 o0 = {h[0],h[1],h[2],h[3]},   o1 = {h[4],h[5],h[6],h[7]};
    float4 o2 = {h[8],h[9],h[10],h[11]}, o3 = {h[12],h[13],h[14],h[15]};
    *(float4*)(hp)    = o0; *(float4*)(hp+4)  = o1;
    *(float4*)(hp+8)  = o2; *(float4*)(hp+12) = o3;
    dsum[((size_t)b*NSEG + seg)*DI + ch] = ds;
}

__global__ __launch_bounds__(256) void ssm_seg_scan(
    const float* __restrict__ A_log, const float* __restrict__ dsum,
    float* __restrict__ hseg)
{
    const int idx = blockIdx.x * 256 + threadIdx.x;
    const int s = idx & 15;
    const int bc = idx >> 4;
    const int ch = bc & (DI-1);
    const int b = bc >> 10;
    const float Av = -__expf(A_log[ch*16 + s]);
    float g = 0.f;
    for (int seg = 0; seg < NSEG; ++seg) {
        const size_t soff = ((size_t)b*NSEG + seg)*DI + ch;
        const float hloc = hseg[soff*16 + s];
        const float a = __expf(Av * dsum[soff]);
        hseg[soff*16 + s] = g;
        g = fmaf(a, g, hloc);
    }
}

__global__ __launch_bounds__(256) void ssm_pass2(
    const float* __restrict__ delta, const float* __restrict__ uact,
    const float* __restrict__ z, const float* __restrict__ xdbl,
    const float* __restrict__ A_log, const float* __restrict__ ssm_D,
    const float* __restrict__ hin, unsigned short* __restrict__ y)
{
    const int tid = threadIdx.x;
    const int ch = blockIdx.x * 256 + tid;
    const int seg = blockIdx.y, b = blockIdx.z;
    const size_t rb = (size_t)b * LL + seg * TSEG;
    __shared__ float sB[TSEG][16], sC[TSEG][16];
    for (int i = tid; i < TSEG*16; i += 256) {
        const int tt = i >> 4, s = i & 15;
        sB[tt][s] = xdbl[(rb + tt)*64 + 32 + s];
        sC[tt][s] = xdbl[(rb + tt)*64 + 48 + s];
    }
    float Av[16];
#pragma unroll
    for (int s = 0; s < 16; ++s) Av[s] = -__expf(A_log[ch*16 + s]);
    float h[16];
    const float* hp = hin + (((size_t)b*NSEG + seg)*DI + ch)*16;
#pragma unroll
    for (int s = 0; s < 16; ++s) h[s] = hp[s];
    const float Dc = ssm_D[ch];
    __syncthreads();
    float d  = delta[rb*DI + ch];
    float uu = uact [rb*DI + ch];
    float zz = z    [rb*DI + ch];
    for (int t = 0; t < TSEG; ++t) {
        const int tn = (t + 1 < TSEG) ? t + 1 : t;
        const float dn = delta[(rb + tn)*DI + ch];
        const float un = uact [(rb + tn)*DI + ch];
        const float zn = z    [(rb + tn)*DI + ch];
        const float du = d * uu;
        float p = 0.f;
#pragma unroll
        for (int s = 0; s < 16; ++s) {
            const float a = __expf(d * Av[s]);
            h[s] = fmaf(a, h[s], du * sB[t][s]);
            p = fmaf(h[s], sC[t][s], p);
        }
        const float sil = zz / (1.f + __expf(-zz));
        y[(rb + t)*DI + ch] = f2bf((p + uu*Dc) * sil);
        d = dn; uu = un; zz = zn;
    }
}

// ---------------- ln1 * (1+g) + residual -> ln2 (f32 + bf16 out) ----------------
__global__ __launch_bounds__(256) void ln_gate_res_ln2(
    const float* __restrict__ x1raw, const float* __restrict__ xres,
    const float* __restrict__ g,
    const float* __restrict__ w1, const float* __restrict__ b1,
    const float* __restrict__ w2, const float* __restrict__ b2,
    float* __restrict__ x2, unsigned short* __restrict__ x2b)
{
    __shared__ float sred[8];
    const int row = blockIdx.x;
    const int b = row >> 11;
    const int c = threadIdx.x * 2;
    const size_t base = (size_t)row * DD;
    float2 v = *(const float2*)(x1raw + base + c);
    float s = v.x + v.y, ss = v.x*v.x + v.y*v.y;
    block_reduce_sum2(s, ss, sred);
    float mean = s * (1.f/DD);
    float rs = rsqrtf(fmaxf(ss * (1.f/DD) - mean*mean, 0.f) + 1e-5f);
    float2 xr = *(const float2*)(xres + base + c);
    float y0 = ((v.x - mean)*rs*w1[c]   + b1[c]  ) * (1.f + g[b*DD + c])   + xr.x;
    float y1 = ((v.y - mean)*rs*w1[c+1] + b1[c+1]) * (1.f + g[b*DD + c+1]) + xr.y;
    s = y0 + y1; ss = y0*y0 + y1*y1;
    block_reduce_sum2(s, ss, sred);
    mean = s * (1.f/DD);
    rs = rsqrtf(fmaxf(ss * (1.f/DD) - mean*mean, 0.f) + 1e-5f);
    float2 o;
    o.x = (y0 - mean)*rs*w2[c]   + b2[c];
    o.y = (y1 - mean)*rs*w2[c+1] + b2[c+1];
    *(float2*)(x2 + base + c) = o;
    ushort2 ob = { f2bf(o.x), f2bf(o.y) };
    *(ushort2*)(x2b + base + c) = ob;
}

// ---------------- x + broadcast(add[b]) -> LN (f32 + bf16 out) ----------------
__global__ __launch_bounds__(256) void add_bcast_ln(
    const float* __restrict__ xin, const float* __restrict__ addb,
    const float* __restrict__ w, const float* __restrict__ bb,
    float* __restrict__ out, unsigned short* __restrict__ outb)
{
    __shared__ float sred[8];
    const int row = blockIdx.x, b = row >> 11, c = threadIdx.x * 2;
    const size_t base = (size_t)row * DD;
    float2 v = *(const float2*)(xin + base + c);
    v.x += addb[b*DD + c];
    v.y += addb[b*DD + c + 1];
    float s = v.x + v.y, ss = v.x*v.x + v.y*v.y;
    block_reduce_sum2(s, ss, sred);
    float mean = s * (1.f/DD);
    float rs = rsqrtf(fmaxf(ss * (1.f/DD) - mean*mean, 0.f) + 1e-5f);
    float2 o = { (v.x - mean)*rs*w[c] + bb[c], (v.y - mean)*rs*w[c+1] + bb[c+1] };
    *(float2*)(out + base + c) = o;
    ushort2 ob = { f2bf(o.x), f2bf(o.y) };
    *(ushort2*)(outb + base + c) = ob;
}

// ---------------- cross-attention, flash-split ----------------
__global__ __launch_bounds__(256) void attn_part(
    const float* __restrict__ q, const float* __restrict__ kv,
    float* __restrict__ po, float* __restrict__ pms)
{
    const int chunk = blockIdx.x, bh = blockIdx.y;
    const int b = bh >> 2, h = bh & 3;
    const int tid = threadIdx.x;
    __shared__ float sq[128];
    __shared__ float se[64];
    __shared__ float sred[8];
    __shared__ float opart[2][128];
    if (tid < 128) sq[tid] = q[b*DD + h*128 + tid];
    __syncthreads();
    const int r = tid >> 2, p = tid & 3;
    const int trow = chunk*64 + r;
    const float* kr = kv + ((size_t)(b*LL + trow))*1024 + h*128 + p*32;
    float dot = 0.f;
#pragma unroll
    for (int d = 0; d < 32; d += 4) {
        float4 k4 = *(const float4*)(kr + d);
        dot += sq[p*32+d]*k4.x + sq[p*32+d+1]*k4.y + sq[p*32+d+2]*k4.z + sq[p*32+d+3]*k4.w;
    }
    dot += __shfl_xor(dot, 1);
    dot += __shfl_xor(dot, 2);
    if (p == 0) se[r] = dot * 0.088388347648318447f;
    __syncthreads();
    const float lm = (tid < 64) ? se[tid] : -1e30f;
    const float m = block_reduce_max(lm, sred);
    float le = 0.f;
    if (tid < 64) { le = __expf(se[tid] - m); se[tid] = le; }
    const float ssum = block_reduce_sum1(le, sred);
    const int d = tid & 127, half = tid >> 7;
    float acc = 0.f;
    for (int rr = half; rr < 64; rr += 2)
        acc = fmaf(se[rr], kv[((size_t)(b*LL + chunk*64 + rr))*1024 + 512 + h*128 + d], acc);
    opart[half][d] = acc;
    __syncthreads();
    if (tid < 128) po[((size_t)bh*ACH + chunk)*128 + tid] = opart[0][tid] + opart[1][tid];
    if (tid == 0) {
        pms[(bh*ACH + chunk)*2]     = m;
        pms[(bh*ACH + chunk)*2 + 1] = ssum;
    }
}

__global__ __launch_bounds__(128) void attn_combine(
    const float* __restrict__ po, const float* __restrict__ pms,
    float* __restrict__ ob)
{
    const int bh = blockIdx.x, tid = threadIdx.x;
    __shared__ float sm_[ACH], ss_[ACH];
    if (tid < ACH) {
        sm_[tid] = pms[(bh*ACH + tid)*2];
        ss_[tid] = pms[(bh*ACH + tid)*2 + 1];
    }
    __syncthreads();
    float M = -1e30f;
#pragma unroll
    for (int i = 0; i < ACH; ++i) M = fmaxf(M, sm_[i]);
    float S = 0.f, acc = 0.f;
    for (int i = 0; i < ACH; ++i) {
        const float e = __expf(sm_[i] - M);
        S += e * ss_[i];
        acc = fmaf(e, po[((size_t)bh*ACH + i)*128 + tid], acc);
    }
    const int b = bh >> 2, h = bh & 3;
    ob[b*DD + h*128 + tid] = acc / S;
}

// ---------------- grouped temporal conv via MFMA + BN + GELU + residual ----------------
// grid (16 t-tiles, B*4). Per block: out tile [128 t][128 oc] of group g.
// x tile [130][128] bf16 (halo); W group [128][384] bf16 (tap-major).
// Rows 0..127 staged via global_load_lds (full waves only); rows 128-129 via
// reg-copy ds-write (avoids partial-wave global_load_lds). Halo rows zeroed
// FULLY (32 threads x 4 ushorts = 128). Both LDS tiles row-XOR-swizzled.
__global__ __launch_bounds__(256) void teconv_mfma(
    const unsigned short* __restrict__ x3b, const unsigned short* __restrict__ wt,
    const float* __restrict__ x3, const float* __restrict__ tb,
    const float* __restrict__ bng, const float* __restrict__ bnb,
    const float* __restrict__ bnm, const float* __restrict__ bnv,
    float* __restrict__ out)
{
    __shared__ unsigned short xs[130 * 128];   // 33.3 KB, reused as cs[64][128] f32
    __shared__ unsigned short wsm[128 * 384];  // 96 KB
    const int tid = threadIdx.x;
    const int t0 = blockIdx.x * 128;
    const int b = blockIdx.y >> 2, g = blockIdx.y & 3;
    const int lane = tid & 63, wid = tid >> 6;
    const int wr = wid >> 1, wc = wid & 1;
    const int l16 = lane & 15, lq = lane >> 4;

    // stage x rows 0..127 (2048 chunks, 8 full-wave iterations)
#pragma unroll
    for (int it = 0; it < 8; ++it) {
        const int cid = it * 256 + tid;
        const int r = cid >> 4, c = cid & 15;
        const int j = c ^ (r & 7);
        int t = t0 - 1 + r;
        t = (t < 0) ? 0 : t;                       // r<128 -> t <= t0+126 < LL
        const unsigned short* gsrc = x3b + ((size_t)b*LL + t)*DD + g*128 + j*8;
        gload_lds16(gsrc, &xs[(size_t)(cid & ~63) * 8]);
    }
    // stage W group: 128 rows x 48 chunks (24 full-wave iterations)
#pragma unroll
    for (int it = 0; it < 24; ++it) {
        const int cid = it * 256 + tid;
        const int r = cid / 48, c = cid % 48;
        const int j = c ^ (r & 7);
        const unsigned short* gsrc = wt + (size_t)(g*128 + r)*384 + j*8;
        gload_lds16(gsrc, &wsm[(size_t)(cid & ~63) * 8]);
    }
    // rows 128-129 (32 chunks) via registers -> ds_write
    if (tid < 32) {
        const int cid = 2048 + tid;
        const int r = cid >> 4, c = cid & 15;      // r = 128 or 129
        const int j = c ^ (r & 7);
        int t = t0 - 1 + r;                        // >= 127, only upper clamp
        t = (t > LL-1) ? LL-1 : t;
        uint4 v = *(const uint4*)(x3b + ((size_t)b*LL + t)*DD + g*128 + j*8);
        *(uint4*)&xs[(size_t)cid * 8] = v;
    }
    __syncthreads();
    // zero FULL halo rows outside the sequence (32 thr x 4 ushorts = 128)
    if (t0 == 0 && tid < 32)        *(ushort4*)&xs[tid*4]            = ushort4{0,0,0,0};
    if (t0 == LL-128 && tid < 32)   *(ushort4*)&xs[129*128 + tid*4]  = ushort4{0,0,0,0};
    __syncthreads();

    f32x4 acc[4][4];
#pragma unroll
    for (int mi = 0; mi < 4; ++mi)
#pragma unroll
        for (int ni = 0; ni < 4; ++ni) acc[mi][ni] = {0.f, 0.f, 0.f, 0.f};

#pragma unroll
    for (int tap = 0; tap < 3; ++tap) {
#pragma unroll
        for (int ks = 0; ks < 128; ks += 32) {
            bf16x8 af[4], bfr[4];
#pragma unroll
            for (int mi = 0; mi < 4; ++mi) {
                const int r = wr*64 + mi*16 + l16 + tap;   // x row (t-local + tap)
                af[mi] = *(const bf16x8*)&xs[r*128 + ((ks + lq*8) ^ ((r & 7) << 3))];
            }
#pragma unroll
            for (int ni = 0; ni < 4; ++ni) {
                const int r = wc*64 + ni*16 + l16;         // oc row
                bfr[ni] = *(const bf16x8*)&wsm[r*384 + ((tap*128 + ks + lq*8) ^ ((r & 7) << 3))];
            }
#pragma unroll
            for (int mi = 0; mi < 4; ++mi)
#pragma unroll
                for (int ni = 0; ni < 4; ++ni)
                    acc[mi][ni] = __builtin_amdgcn_mfma_f32_16x16x32_bf16(
                        af[mi], bfr[ni], acc[mi][ni], 0, 0, 0);
        }
    }
    // per-column BN fold: v = (acc + tb)*s + shift = acc*s + c0
    float sj[4], cj[4];
#pragma unroll
    for (int ni = 0; ni < 4; ++ni) {
        const int og = g*128 + wc*64 + ni*16 + l16;
        const float s = bng[og] * rsqrtf(bnv[og] + 1e-5f);
        sj[ni] = s;
        cj[ni] = (tb[og] - bnm[og]) * s + bnb[og];
    }
    float* cs = (float*)xs;   // [64][128]
#pragma unroll
    for (int h = 0; h < 2; ++h) {
        __syncthreads();
        if (wr == h) {
#pragma unroll
            for (int mi = 0; mi < 4; ++mi)
#pragma unroll
                for (int ni = 0; ni < 4; ++ni)
#pragma unroll
                    for (int r = 0; r < 4; ++r)
                        cs[(mi*16 + lq*4 + r)*128 + wc*64 + ni*16 + l16]
                            = acc[mi][ni][r] * sj[ni] + cj[ni];
        }
        __syncthreads();
#pragma unroll
        for (int j = 0; j < 8; ++j) {
            const int rl = (tid >> 5) + j*8;
            const int cl = (tid & 31) * 4;
            float4 v = *(const float4*)&cs[rl*128 + cl];
            const size_t oi = ((size_t)b*LL + t0 + h*64 + rl)*DD + g*128 + cl;
            float4 xr = *(const float4*)&x3[oi];
            v.x = xr.x + geluf(v.x);
            v.y = xr.y + geluf(v.y);
            v.z = xr.z + geluf(v.z);
            v.w = xr.w + geluf(v.w);
            *(float4*)&out[oi] = v;
        }
    }
}

// ---------------- launch ----------------
extern "C" void kernel_launch(void* const* d_in, const int* in_sizes, int n_in,
                              void* d_out, int out_size, void* d_ws, size_t ws_size,
                              hipStream_t stream)
{
    (void)in_sizes; (void)n_in; (void)out_size; (void)ws_size;
    const float* x         = (const float*)d_in[0];
    const float* freq      = (const float*)d_in[1];
    const float* in_proj_w = (const float*)d_in[2];
    const float* conv_w    = (const float*)d_in[3];
    const float* conv_b    = (const float*)d_in[4];
    const float* x_proj_w  = (const float*)d_in[5];
    const float* dt_proj_w = (const float*)d_in[6];
    const float* dt_proj_b = (const float*)d_in[7];
    const float* A_log     = (const float*)d_in[8];
    const float* ssm_D     = (const float*)d_in[9];
    const float* out_proj_w= (const float*)d_in[10];
    const float* fg_w1     = (const float*)d_in[11];
    const float* fg_b1     = (const float*)d_in[12];
    const float* fg_w2     = (const float*)d_in[13];
    const float* fg_b2     = (const float*)d_in[14];
    const float* attn_in_w = (const float*)d_in[15];
    const float* attn_in_b = (const float*)d_in[16];
    const float* attn_out_w= (const float*)d_in[17];
    const float* attn_out_b= (const float*)d_in[18];
    const float* te_w      = (const float*)d_in[19];
    const float* te_b      = (const float*)d_in[20];
    const float* bn_g      = (const float*)d_in[21];
    const float* bn_b      = (const float*)d_in[22];
    const float* bn_m      = (const float*)d_in[23];
    const float* bn_v      = (const float*)d_in[24];
    const float* ln1w = (const float*)d_in[25];
    const float* ln1b = (const float*)d_in[26];
    const float* ln2w = (const float*)d_in[27];
    const float* ln2b = (const float*)d_in[28];
    const float* ln3w = (const float*)d_in[29];
    const float* ln3b = (const float*)d_in[30];
    float* out = (float*)d_out;

    // ---- workspace layout (lifetime-overlapped), ~150 MB ----
    float* ws = (float*)d_ws;
    const size_t SEG = 8388608;                 // 8192*1024 floats = 32 MiB
    float* S1 = ws;                             // u_raw -> delta -> x2b/x3b (bf16)
    float* S2 = ws + SEG;                       // z_raw -> x1 | x3
    float* S3 = ws + 2*SEG;                     // u_act -> x2
    float* S4 = ws + 3*SEG;                     // xb -> uact_b -> ybuf_b -> kv
    float* xdbl = ws + 4*SEG;                   // 524288 f; later attn partials
    float* sm   = ws + 4*SEG + 524288;          // small scalars (16384 f)
    float* hseg = sm + 16384;                   // 2097152 f
    float* dsum = hseg + 2097152;               // 131072 f
    unsigned short* wb = (unsigned short*)(dsum + 131072);   // bf16 weights
    unsigned short* ipw_b = wb;                 // 1048576 us
    unsigned short* xpw_b = wb + 1048576;       // 65536 us
    unsigned short* opw_b = wb + 1114112;       // 524288 us
    unsigned short* kvw_b = wb + 1638400;       // 524288 us
    unsigned short* tew_b = wb + 2162688;       // 196608 us

    float* u_raw = S1;  float* deltab = S1;
    unsigned short* x2b = (unsigned short*)S1;            // first 8 MB of S1
    unsigned short* x3b = (unsigned short*)S1 + 4194304;  // next 8 MB of S1
    float* z_raw = S2;  float* x1 = S2;  float* x3 = S2 + 4194304;
    float* u_act = S3;  float* x2 = S3;
    unsigned short* xb      = (unsigned short*)S4;
    unsigned short* uact_b  = (unsigned short*)S4;
    unsigned short* ybuf_b  = (unsigned short*)S4;
    float* kv = S4;
    float* hidden = sm;        // 4096
    float* g  = sm + 4096;     // 2048
    float* qb = sm + 6144;     // 2048
    float* ob = sm + 8192;     // 2048
    float* ao = sm + 10240;    // 2048
    float* po  = xdbl;         // attn partial o (xdbl dead by then)
    float* pms = xdbl + 65536; // 1024 f

    dim3 blk(256);

    // 0) bf16 conversions: inputs + weights
    cvt_bf16<<<2048, blk, 0, stream>>>(x, xb, 4194304);
    cvt_bf16<<<512,  blk, 0, stream>>>(in_proj_w, ipw_b, 1048576);
    cvt_bf16<<<32,   blk, 0, stream>>>(x_proj_w, xpw_b, 65536);
    cvt_bf16<<<256,  blk, 0, stream>>>(out_proj_w, opw_b, 524288);
    cvt_bf16<<<256,  blk, 0, stream>>>(attn_in_w + 262144, kvw_b, 524288);
    cvt_tew<<<768,   blk, 0, stream>>>(te_w, tew_b);

    // 1) in_proj: u and z halves
    gemm_bf16g<<<dim3(8,64), blk, 0, stream>>>(xb, ipw_b,          u_raw, nullptr, DD, DD, DD, DI);
    gemm_bf16g<<<dim3(8,64), blk, 0, stream>>>(xb, ipw_b + 524288, z_raw, nullptr, DD, DD, DD, DI);
    // 2) causal depthwise conv + silu
    dwconv_silu<<<(BL*DI)/256, blk, 0, stream>>>(u_raw, conv_w, conv_b, u_act, uact_b);
    // 3) x_dbl = u @ x_proj^T  (split-K 16, atomic accumulate)
    zero_f32<<<512, blk, 0, stream>>>(xdbl, BL*64);
    gemm_xdbl_sk<<<dim3(16, 32), blk, 0, stream>>>(uact_b, xpw_b, xdbl);
    // 4) delta = softplus(dt @ dt_proj^T + b)
    delta_gemm<<<dim3(8, 64), blk, 0, stream>>>(xdbl, dt_proj_w, dt_proj_b, deltab);
    // 5) selective scan, chunked
    ssm_pass1<<<dim3(4, NSEG, BB), blk, 0, stream>>>(deltab, u_act, xdbl, A_log, hseg, dsum);
    ssm_seg_scan<<<256, blk, 0, stream>>>(A_log, dsum, hseg);
    ssm_pass2<<<dim3(4, NSEG, BB), blk, 0, stream>>>(deltab, u_act, z_raw, xdbl, A_log, ssm_D, hseg, ybuf_b);
    // 6) out_proj
    gemm_bf16g<<<dim3(4,64), blk, 0, stream>>>(ybuf_b, opw_b, x1, nullptr, DI, DI, DI, DD);
    // 7) freq gate MLP
    small_nt<1><<<16, blk, 0, stream>>>(freq,   fg_w1, fg_b1, hidden, BB, 2*DD, DD, DD);
    small_nt<2><<<8,  blk, 0, stream>>>(hidden, fg_w2, fg_b2, g,      BB, DD, 2*DD, 2*DD);
    // 8) ln1 * (1+g) + residual -> ln2
    ln_gate_res_ln2<<<BL, blk, 0, stream>>>(x1, x, g, ln1w, ln1b, ln2w, ln2b, x2, x2b);
    // 9) attention
    small_nt<0><<<8, blk, 0, stream>>>(freq, attn_in_w, attn_in_b, qb, BB, DD, DD, DD);
    gemm_bf16g<<<dim3(8,64), blk, 0, stream>>>(x2b, kvw_b, kv, attn_in_b + 512, DD, DD, DD, 2*DD);
    attn_part<<<dim3(ACH, BB*4), blk, 0, stream>>>(qb, kv, po, pms);
    attn_combine<<<BB*4, dim3(128), 0, stream>>>(po, pms, ob);
    small_nt<0><<<8, blk, 0, stream>>>(ob, attn_out_w, attn_out_b, ao, BB, DD, DD, DD);
    // 10) ln3(x2 + attn_broadcast), also emits bf16 for the conv
    add_bcast_ln<<<BL, blk, 0, stream>>>(x2, ao, ln3w, ln3b, x3, x3b);
    // 11) temporal conv (MFMA) + BN + gelu + residual
    teconv_mfma<<<dim3(LL/128, BB*4), blk, 0, stream>>>(x3b, tew_b, x3, te_b, bn_g, bn_b, bn_m, bn_v, out);
}

// Round 9
// 419.013 us; speedup vs baseline: 4.7918x; 1.0888x over previous
//
#include <hip/hip_runtime.h>
#include <hip/hip_bf16.h>

// ---------------- constants ----------------
// B=4, L=2048, D=512, DI=1024, DS=16, DC=4, DTR=32, H=4, DH=128
#define BB 4
#define LL 2048
#define DD 512
#define DI 1024
#define DS 16
#define DTR 32
#define BL (BB*LL)   // 8192
#define NSEG 32
#define TSEG 64      // NSEG*TSEG == LL
#define ACH 32       // attention chunks per (b,h)

using bf16x8 = __attribute__((ext_vector_type(8))) short;
using f32x4  = __attribute__((ext_vector_type(4))) float;

// ---------------- helpers ----------------
__device__ __forceinline__ float geluf(float x) {
    return 0.5f * x * (1.f + erff(x * 0.7071067811865476f));
}

__device__ __forceinline__ unsigned short f2bf(float f) {
    unsigned u = __float_as_uint(f);
    u += 0x7FFFu + ((u >> 16) & 1u);   // round-to-nearest-even
    return (unsigned short)(u >> 16);
}

__device__ __forceinline__ void gload_lds16(const void* g, void* l) {
    __builtin_amdgcn_global_load_lds(
        (__attribute__((address_space(1))) void*)g,
        (__attribute__((address_space(3))) void*)l, 16, 0, 0);
}

__device__ __forceinline__ void block_reduce_sum2(float& a, float& b, float* sred) {
    for (int off = 32; off > 0; off >>= 1) {
        a += __shfl_down(a, off);
        b += __shfl_down(b, off);
    }
    const int lane = threadIdx.x & 63, wid = threadIdx.x >> 6;
    if (lane == 0) { sred[wid*2] = a; sred[wid*2+1] = b; }
    __syncthreads();
    a = sred[0] + sred[2] + sred[4] + sred[6];
    b = sred[1] + sred[3] + sred[5] + sred[7];
    __syncthreads();
}

__device__ __forceinline__ float block_reduce_max(float v, float* sred) {
    for (int off = 32; off > 0; off >>= 1) v = fmaxf(v, __shfl_down(v, off));
    const int lane = threadIdx.x & 63, wid = threadIdx.x >> 6;
    if (lane == 0) sred[wid] = v;
    __syncthreads();
    v = fmaxf(fmaxf(sred[0], sred[1]), fmaxf(sred[2], sred[3]));
    __syncthreads();
    return v;
}

__device__ __forceinline__ float block_reduce_sum1(float v, float* sred) {
    for (int off = 32; off > 0; off >>= 1) v += __shfl_down(v, off);
    const int lane = threadIdx.x & 63, wid = threadIdx.x >> 6;
    if (lane == 0) sred[wid] = v;
    __syncthreads();
    v = sred[0] + sred[1] + sred[2] + sred[3];
    __syncthreads();
    return v;
}

// ---------------- utility kernels ----------------
__global__ __launch_bounds__(256) void zero_f32(float* __restrict__ p, int n) {
    const int i = (blockIdx.x * 256 + threadIdx.x) * 4;
    if (i < n) { float4 z = {0.f,0.f,0.f,0.f}; *(float4*)(p + i) = z; }
}

__global__ __launch_bounds__(256) void cvt_bf16(
    const float* __restrict__ in, unsigned short* __restrict__ out, int n)
{
    const int i = (blockIdx.x * 256 + threadIdx.x) * 8;
    if (i >= n) return;
    float4 a = *(const float4*)(in + i);
    float4 b = *(const float4*)(in + i + 4);
    ushort4 h0 = { f2bf(a.x), f2bf(a.y), f2bf(a.z), f2bf(a.w) };
    ushort4 h1 = { f2bf(b.x), f2bf(b.y), f2bf(b.z), f2bf(b.w) };
    *(ushort4*)(out + i)     = h0;
    *(ushort4*)(out + i + 4) = h1;
}

// te_conv_w [512][128][3] -> wt [512][384] bf16, col = j*128 + ic
__global__ __launch_bounds__(256) void cvt_tew(
    const float* __restrict__ tw, unsigned short* __restrict__ wt)
{
    const int i = blockIdx.x * 256 + threadIdx.x;
    if (i >= 512 * 384) return;
    const int oc = i / 384, rem = i - oc * 384;
    const int j = rem >> 7, ic = rem & 127;
    wt[i] = f2bf(tw[oc * 384 + ic * 3 + j]);
}

// ---------------- bf16 MFMA GEMM 128x128 tile, global_load_lds staging ----------------
__global__ __launch_bounds__(256) void gemm_bf16g(
    const unsigned short* __restrict__ A, const unsigned short* __restrict__ W,
    float* __restrict__ C, const float* __restrict__ bias,
    int K, int lda, int ldw, int ldc)
{
    __shared__ unsigned short lds[256 * 64];   // 32 KB; reused as cs[64][128] f32
    const int tid = threadIdx.x;
    const int bm = blockIdx.y * 128, bn = blockIdx.x * 128;
    const int lane = tid & 63, wid = tid >> 6;
    const int wr = wid >> 1, wc = wid & 1;
    const int l16 = lane & 15, lq = lane >> 4;
    const int swz = (l16 & 7) << 3;

    f32x4 acc[4][4];
#pragma unroll
    for (int mi = 0; mi < 4; ++mi)
#pragma unroll
        for (int ni = 0; ni < 4; ++ni) acc[mi][ni] = {0.f, 0.f, 0.f, 0.f};

    for (int k0 = 0; k0 < K; k0 += 64) {
#pragma unroll
        for (int it = 0; it < 8; ++it) {
            const int cid = it * 256 + tid;            // 16B-chunk id
            const int r = cid >> 3, c = cid & 7;
            const int j = c ^ (r & 7);                 // pre-swizzled source chunk
            const unsigned short* gsrc =
                (r < 128 ? A + (size_t)(bm + r) * lda : W + (size_t)(bn + r - 128) * ldw)
                + k0 + j * 8;
            gload_lds16(gsrc, &lds[(size_t)(cid & ~63) * 8]);
        }
        __syncthreads();
#pragma unroll
        for (int ks = 0; ks < 64; ks += 32) {
            bf16x8 af[4], bfr[4];
#pragma unroll
            for (int mi = 0; mi < 4; ++mi) {
                const int r = wr*64 + mi*16 + l16;
                af[mi] = *(const bf16x8*)&lds[r*64 + ((ks + lq*8) ^ swz)];
            }
#pragma unroll
            for (int ni = 0; ni < 4; ++ni) {
                const int r = 128 + wc*64 + ni*16 + l16;
                bfr[ni] = *(const bf16x8*)&lds[r*64 + ((ks + lq*8) ^ swz)];
            }
#pragma unroll
            for (int mi = 0; mi < 4; ++mi)
#pragma unroll
                for (int ni = 0; ni < 4; ++ni)
                    acc[mi][ni] = __builtin_amdgcn_mfma_f32_16x16x32_bf16(
                        af[mi], bfr[ni], acc[mi][ni], 0, 0, 0);
        }
        __syncthreads();
    }
    float bj[4];
#pragma unroll
    for (int ni = 0; ni < 4; ++ni)
        bj[ni] = bias ? bias[bn + wc*64 + ni*16 + l16] : 0.f;
    float* cs = (float*)lds;   // [64][128]
#pragma unroll
    for (int h = 0; h < 2; ++h) {
        __syncthreads();
        if (wr == h) {
#pragma unroll
            for (int mi = 0; mi < 4; ++mi)
#pragma unroll
                for (int ni = 0; ni < 4; ++ni)
#pragma unroll
                    for (int r = 0; r < 4; ++r)
                        cs[(mi*16 + lq*4 + r)*128 + wc*64 + ni*16 + l16]
                            = acc[mi][ni][r] + bj[ni];
        }
        __syncthreads();
#pragma unroll
        for (int j = 0; j < 8; ++j) {
            const int rl = (tid >> 5) + j*8;
            const int cl = (tid & 31) * 4;
            float4 v = *(const float4*)&cs[rl*128 + cl];
            *(float4*)&C[(size_t)(bm + h*64 + rl) * ldc + bn + cl] = v;
        }
    }
}

// ---------------- xdbl split-K GEMM: C[M,64] += A-slice @ W-slice^T ----------------
__global__ __launch_bounds__(256) void gemm_xdbl_sk(
    const unsigned short* __restrict__ A, const unsigned short* __restrict__ W,
    float* __restrict__ C)
{
    __shared__ unsigned short lds[320 * 64];
    const int tid = threadIdx.x;
    const int k0 = blockIdx.x * 64;
    const int bm = blockIdx.y * 256;
    const int lane = tid & 63, wid = tid >> 6;
    const int l16 = lane & 15, lq = lane >> 4;
    const int swz = (l16 & 7) << 3;
#pragma unroll
    for (int it = 0; it < 10; ++it) {
        const int cid = it * 256 + tid;
        const int r = cid >> 3, c = cid & 7;
        const int j = c ^ (r & 7);
        const unsigned short* gsrc =
            (r < 256 ? A + (size_t)(bm + r) * DI : W + (size_t)(r - 256) * DI) + k0 + j * 8;
        gload_lds16(gsrc, &lds[(size_t)(cid & ~63) * 8]);
    }
    __syncthreads();
    f32x4 acc[4][4];
#pragma unroll
    for (int mi = 0; mi < 4; ++mi)
#pragma unroll
        for (int ni = 0; ni < 4; ++ni) acc[mi][ni] = {0.f, 0.f, 0.f, 0.f};
#pragma unroll
    for (int ks = 0; ks < 64; ks += 32) {
        bf16x8 af[4], bfr[4];
#pragma unroll
        for (int mi = 0; mi < 4; ++mi) {
            const int r = wid*64 + mi*16 + l16;
            af[mi] = *(const bf16x8*)&lds[r*64 + ((ks + lq*8) ^ swz)];
        }
#pragma unroll
        for (int ni = 0; ni < 4; ++ni) {
            const int r = 256 + ni*16 + l16;
            bfr[ni] = *(const bf16x8*)&lds[r*64 + ((ks + lq*8) ^ swz)];
        }
#pragma unroll
        for (int mi = 0; mi < 4; ++mi)
#pragma unroll
            for (int ni = 0; ni < 4; ++ni)
                acc[mi][ni] = __builtin_amdgcn_mfma_f32_16x16x32_bf16(
                    af[mi], bfr[ni], acc[mi][ni], 0, 0, 0);
    }
#pragma unroll
    for (int ni = 0; ni < 4; ++ni) {
        const int col = ni*16 + l16;
#pragma unroll
        for (int mi = 0; mi < 4; ++mi) {
            const int row = bm + wid*64 + mi*16 + lq*4;
#pragma unroll
            for (int r = 0; r < 4; ++r)
                atomicAdd(&C[(size_t)(row + r) * 64 + col], acc[mi][ni][r]);
        }
    }
}

// ---------------- delta GEMM: softplus(xdbl[:,0:32] @ dt_proj_w^T + b) ----------------
__global__ __launch_bounds__(256) void delta_gemm(
    const float* __restrict__ xdbl, const float* __restrict__ dtw,
    const float* __restrict__ dtb, float* __restrict__ delta)
{
    __shared__ char smem[64 * 128 * 4];   // 32 KB: staging then cs
    unsigned short* As = (unsigned short*)smem;          // [128][34]
    unsigned short* Ws = As + 128 * 34;                  // [128][34]
    const int tid = threadIdx.x;
    const int bn = blockIdx.x * 128, bm = blockIdx.y * 128;
    for (int i = tid; i < 128 * 8; i += 256) {
        const int r = i >> 3, c4 = (i & 7) * 4;
        float4 va = *(const float4*)(xdbl + (size_t)(bm + r) * 64 + c4);
        ushort4 ha = { f2bf(va.x), f2bf(va.y), f2bf(va.z), f2bf(va.w) };
        *(ushort4*)&As[r * 34 + c4] = ha;
        float4 vw = *(const float4*)(dtw + (size_t)(bn + r) * 32 + c4);
        ushort4 hw = { f2bf(vw.x), f2bf(vw.y), f2bf(vw.z), f2bf(vw.w) };
        *(ushort4*)&Ws[r * 34 + c4] = hw;
    }
    __syncthreads();
    const int lane = tid & 63, wid = tid >> 6;
    const int wr = wid >> 1, wc = wid & 1;
    const int l16 = lane & 15, lq = lane >> 4;
    bf16x8 af[4], wf[4];
#pragma unroll
    for (int mi = 0; mi < 4; ++mi)
        af[mi] = *(const bf16x8*)&As[(wr*64 + mi*16 + l16) * 34 + lq*8];
#pragma unroll
    for (int ni = 0; ni < 4; ++ni)
        wf[ni] = *(const bf16x8*)&Ws[(wc*64 + ni*16 + l16) * 34 + lq*8];
    f32x4 acc[4][4];
#pragma unroll
    for (int mi = 0; mi < 4; ++mi)
#pragma unroll
        for (int ni = 0; ni < 4; ++ni) {
            f32x4 z = {0.f, 0.f, 0.f, 0.f};
            acc[mi][ni] = __builtin_amdgcn_mfma_f32_16x16x32_bf16(af[mi], wf[ni], z, 0, 0, 0);
        }
    float bj[4];
#pragma unroll
    for (int ni = 0; ni < 4; ++ni) bj[ni] = dtb[bn + wc*64 + ni*16 + l16];
    float* cs = (float*)smem;   // [64][128]
#pragma unroll
    for (int h = 0; h < 2; ++h) {
        __syncthreads();
        if (wr == h) {
#pragma unroll
            for (int mi = 0; mi < 4; ++mi)
#pragma unroll
                for (int ni = 0; ni < 4; ++ni)
#pragma unroll
                    for (int r = 0; r < 4; ++r)
                        cs[(mi*16 + lq*4 + r)*128 + wc*64 + ni*16 + l16]
                            = acc[mi][ni][r] + bj[ni];
        }
        __syncthreads();
#pragma unroll
        for (int j = 0; j < 8; ++j) {
            const int rl = (tid >> 5) + j*8;
            const int cl = (tid & 31) * 4;
            float4 v = *(const float4*)&cs[rl*128 + cl];
            v.x = (v.x > 20.f) ? v.x : __logf(1.f + __expf(v.x));
            v.y = (v.y > 20.f) ? v.y : __logf(1.f + __expf(v.y));
            v.z = (v.z > 20.f) ? v.z : __logf(1.f + __expf(v.z));
            v.w = (v.w > 20.f) ? v.w : __logf(1.f + __expf(v.w));
            *(float4*)&delta[(size_t)(bm + h*64 + rl) * DI + bn + cl] = v;
        }
    }
}

// ---------------- small per-output-thread GEMM ----------------
template<int EPI>
__global__ __launch_bounds__(256) void small_nt(
    const float* __restrict__ A, const float* __restrict__ W,
    const float* __restrict__ bias, float* __restrict__ C,
    int M, int N, int K, int lda)
{
    const int idx = blockIdx.x * 256 + threadIdx.x;
    if (idx >= M * N) return;
    const int r = idx / N, c = idx - r * N;
    const float* a = A + (size_t)r * lda;
    const float* w = W + (size_t)c * K;
    float acc = 0.f;
    for (int k = 0; k < K; k += 4) {
        float4 av = *(const float4*)(a + k);
        float4 wv = *(const float4*)(w + k);
        acc += av.x*wv.x + av.y*wv.y + av.z*wv.z + av.w*wv.w;
    }
    if (bias) acc += bias[c];
    if (EPI == 1)      acc = geluf(acc);
    else if (EPI == 2) acc = 1.f / (1.f + __expf(-acc));
    C[(size_t)r * N + c] = acc;
}

// ---------------- causal depthwise conv (k=4) + SiLU, 4 t per thread ----------------
__global__ __launch_bounds__(256) void dwconv_silu(
    const float* __restrict__ u, const float* __restrict__ cw,
    const float* __restrict__ cb, float* __restrict__ out,
    unsigned short* __restrict__ out_bf)
{
    const int idx = blockIdx.x * 256 + threadIdx.x;   // < BL*DI/4
    const int c = idx & (DI-1);
    const int rg = idx >> 10;          // 0..2047
    const int b = rg >> 9;
    const int t4 = (rg & 511) * 4;
    const size_t base = ((size_t)b*LL + t4)*DI + c;
    const float4 w = *(const float4*)(cw + c*4);
    const float bb = cb[c];
    float x[7];
#pragma unroll
    for (int j = 0; j < 7; ++j) {
        const int t = t4 - 3 + j;
        x[j] = (t >= 0) ? u[base + (size_t)(j-3)*DI] : 0.f;
    }
#pragma unroll
    for (int i = 0; i < 4; ++i) {
        float s = bb;
        s = fmaf(w.x, x[i],   s);
        s = fmaf(w.y, x[i+1], s);
        s = fmaf(w.z, x[i+2], s);
        s = fmaf(w.w, x[i+3], s);
        const float v = s / (1.f + __expf(-s));
        out[base + (size_t)i*DI] = v;
        out_bf[base + (size_t)i*DI] = f2bf(v);
    }
}

// ---------------- SSM chunked scan ----------------
__global__ __launch_bounds__(256) void ssm_pass1(
    const float* __restrict__ delta, const float* __restrict__ uact,
    const float* __restrict__ xdbl, const float* __restrict__ A_log,
    float* __restrict__ hseg, float* __restrict__ dsum)
{
    const int tid = threadIdx.x;
    const int ch = blockIdx.x * 256 + tid;
    const int seg = blockIdx.y, b = blockIdx.z;
    const size_t rb = (size_t)b * LL + seg * TSEG;
    __shared__ float sB[TSEG][16];
    for (int i = tid; i < TSEG*16; i += 256) {
        const int tt = i >> 4, s = i & 15;
        sB[tt][s] = xdbl[(rb + tt)*64 + 32 + s];
    }
    float Av[16];
#pragma unroll
    for (int s = 0; s < 16; ++s) Av[s] = -__expf(A_log[ch*16 + s]);
    __syncthreads();
    float h[16] = {};
    float ds = 0.f;
    float d  = delta[rb*DI + ch];
    float uu = uact [rb*DI + ch];
    for (int t = 0; t < TSEG; ++t) {
        const int tn = (t + 1 < TSEG) ? t + 1 : t;
        const float dn = delta[(rb + tn)*DI + ch];
        const float un = uact [(rb + tn)*DI + ch];
        ds += d;
        const float du = d * uu;
#pragma unroll
        for (int s = 0; s < 16; ++s) {
            const float a = __expf(d * Av[s]);
            h[s] = fmaf(a, h[s], du * sB[t][s]);
        }
        d = dn; uu = un;
    }
    float* hp = hseg + (((size_t)b*NSEG + seg)*DI + ch)*16;
    float4 o0 = {h[0],h[1],h[2],h[3]},   o1 = {h[4],h[5],h[6],h[7]};
    float4 o2 = {h[8],h[9],h[10],h[11]}, o3 = {h[12],h[13],h[14],h[15]};
    *(float4*)(hp)    = o0; *(float4*)(hp+4)  = o1;
    *(float4*)(hp+8)  = o2; *(float4*)(hp+12) = o3;
    dsum[((size_t)b*NSEG + seg)*DI + ch] = ds;
}

__global__ __launch_bounds__(256) void ssm_seg_scan(
    const float* __restrict__ A_log, const float* __restrict__ dsum,
    float* __restrict__ hseg)
{
    const int idx = blockIdx.x * 256 + threadIdx.x;
    const int s = idx & 15;
    const int bc = idx >> 4;
    const int ch = bc & (DI-1);
    const int b = bc >> 10;
    const float Av = -__expf(A_log[ch*16 + s]);
    float g = 0.f;
    for (int seg = 0; seg < NSEG; ++seg) {
        const size_t soff = ((size_t)b*NSEG + seg)*DI + ch;
        const float hloc = hseg[soff*16 + s];
        const float a = __expf(Av * dsum[soff]);
        hseg[soff*16 + s] = g;
        g = fmaf(a, g, hloc);
    }
}

__global__ __launch_bounds__(256) void ssm_pass2(
    const float* __restrict__ delta, const float* __restrict__ uact,
    const float* __restrict__ z, const float* __restrict__ xdbl,
    const float* __restrict__ A_log, const float* __restrict__ ssm_D,
    const float* __restrict__ hin, unsigned short* __restrict__ y)
{
    const int tid = threadIdx.x;
    const int ch = blockIdx.x * 256 + tid;
    const int seg = blockIdx.y, b = blockIdx.z;
    const size_t rb = (size_t)b * LL + seg * TSEG;
    __shared__ float sB[TSEG][16], sC[TSEG][16];
    for (int i = tid; i < TSEG*16; i += 256) {
        const int tt = i >> 4, s = i & 15;
        sB[tt][s] = xdbl[(rb + tt)*64 + 32 + s];
        sC[tt][s] = xdbl[(rb + tt)*64 + 48 + s];
    }
    float Av[16];
#pragma unroll
    for (int s = 0; s < 16; ++s) Av[s] = -__expf(A_log[ch*16 + s]);
    float h[16];
    const float* hp = hin + (((size_t)b*NSEG + seg)*DI + ch)*16;
#pragma unroll
    for (int s = 0; s < 16; ++s) h[s] = hp[s];
    const float Dc = ssm_D[ch];
    __syncthreads();
    float d  = delta[rb*DI + ch];
    float uu = uact [rb*DI + ch];
    float zz = z    [rb*DI + ch];
    for (int t = 0; t < TSEG; ++t) {
        const int tn = (t + 1 < TSEG) ? t + 1 : t;
        const float dn = delta[(rb + tn)*DI + ch];
        const float un = uact [(rb + tn)*DI + ch];
        const float zn = z    [(rb + tn)*DI + ch];
        const float du = d * uu;
        float p = 0.f;
#pragma unroll
        for (int s = 0; s < 16; ++s) {
            const float a = __expf(d * Av[s]);
            h[s] = fmaf(a, h[s], du * sB[t][s]);
            p = fmaf(h[s], sC[t][s], p);
        }
        const float sil = zz / (1.f + __expf(-zz));
        y[(rb + t)*DI + ch] = f2bf((p + uu*Dc) * sil);
        d = dn; uu = un; zz = zn;
    }
}

// ---------------- ln1 * (1+g) + residual -> ln2 (f32 + bf16 out) ----------------
__global__ __launch_bounds__(256) void ln_gate_res_ln2(
    const float* __restrict__ x1raw, const float* __restrict__ xres,
    const float* __restrict__ g,
    const float* __restrict__ w1, const float* __restrict__ b1,
    const float* __restrict__ w2, const float* __restrict__ b2,
    float* __restrict__ x2, unsigned short* __restrict__ x2b)
{
    __shared__ float sred[8];
    const int row = blockIdx.x;
    const int b = row >> 11;
    const int c = threadIdx.x * 2;
    const size_t base = (size_t)row * DD;
    float2 v = *(const float2*)(x1raw + base + c);
    float s = v.x + v.y, ss = v.x*v.x + v.y*v.y;
    block_reduce_sum2(s, ss, sred);
    float mean = s * (1.f/DD);
    float rs = rsqrtf(fmaxf(ss * (1.f/DD) - mean*mean, 0.f) + 1e-5f);
    float2 xr = *(const float2*)(xres + base + c);
    float y0 = ((v.x - mean)*rs*w1[c]   + b1[c]  ) * (1.f + g[b*DD + c])   + xr.x;
    float y1 = ((v.y - mean)*rs*w1[c+1] + b1[c+1]) * (1.f + g[b*DD + c+1]) + xr.y;
    s = y0 + y1; ss = y0*y0 + y1*y1;
    block_reduce_sum2(s, ss, sred);
    mean = s * (1.f/DD);
    rs = rsqrtf(fmaxf(ss * (1.f/DD) - mean*mean, 0.f) + 1e-5f);
    float2 o;
    o.x = (y0 - mean)*rs*w2[c]   + b2[c];
    o.y = (y1 - mean)*rs*w2[c+1] + b2[c+1];
    *(float2*)(x2 + base + c) = o;
    ushort2 ob = { f2bf(o.x), f2bf(o.y) };
    *(ushort2*)(x2b + base + c) = ob;
}

// ---------------- x + broadcast(add[b]) -> LN (f32 + bf16 out) ----------------
__global__ __launch_bounds__(256) void add_bcast_ln(
    const float* __restrict__ xin, const float* __restrict__ addb,
    const float* __restrict__ w, const float* __restrict__ bb,
    float* __restrict__ out, unsigned short* __restrict__ outb)
{
    __shared__ float sred[8];
    const int row = blockIdx.x, b = row >> 11, c = threadIdx.x * 2;
    const size_t base = (size_t)row * DD;
    float2 v = *(const float2*)(xin + base + c);
    v.x += addb[b*DD + c];
    v.y += addb[b*DD + c + 1];
    float s = v.x + v.y, ss = v.x*v.x + v.y*v.y;
    block_reduce_sum2(s, ss, sred);
    float mean = s * (1.f/DD);
    float rs = rsqrtf(fmaxf(ss * (1.f/DD) - mean*mean, 0.f) + 1e-5f);
    float2 o = { (v.x - mean)*rs*w[c] + bb[c], (v.y - mean)*rs*w[c+1] + bb[c+1] };
    *(float2*)(out + base + c) = o;
    ushort2 ob = { f2bf(o.x), f2bf(o.y) };
    *(ushort2*)(outb + base + c) = ob;
}

// ---------------- cross-attention, flash-split ----------------
__global__ __launch_bounds__(256) void attn_part(
    const float* __restrict__ q, const float* __restrict__ kv,
    float* __restrict__ po, float* __restrict__ pms)
{
    const int chunk = blockIdx.x, bh = blockIdx.y;
    const int b = bh >> 2, h = bh & 3;
    const int tid = threadIdx.x;
    __shared__ float sq[128];
    __shared__ float se[64];
    __shared__ float sred[8];
    __shared__ float opart[2][128];
    if (tid < 128) sq[tid] = q[b*DD + h*128 + tid];
    __syncthreads();
    const int r = tid >> 2, p = tid & 3;
    const int trow = chunk*64 + r;
    const float* kr = kv + ((size_t)(b*LL + trow))*1024 + h*128 + p*32;
    float dot = 0.f;
#pragma unroll
    for (int d = 0; d < 32; d += 4) {
        float4 k4 = *(const float4*)(kr + d);
        dot += sq[p*32+d]*k4.x + sq[p*32+d+1]*k4.y + sq[p*32+d+2]*k4.z + sq[p*32+d+3]*k4.w;
    }
    dot += __shfl_xor(dot, 1);
    dot += __shfl_xor(dot, 2);
    if (p == 0) se[r] = dot * 0.088388347648318447f;
    __syncthreads();
    const float lm = (tid < 64) ? se[tid] : -1e30f;
    const float m = block_reduce_max(lm, sred);
    float le = 0.f;
    if (tid < 64) { le = __expf(se[tid] - m); se[tid] = le; }
    const float ssum = block_reduce_sum1(le, sred);
    const int d = tid & 127, half = tid >> 7;
    float acc = 0.f;
    for (int rr = half; rr < 64; rr += 2)
        acc = fmaf(se[rr], kv[((size_t)(b*LL + chunk*64 + rr))*1024 + 512 + h*128 + d], acc);
    opart[half][d] = acc;
    __syncthreads();
    if (tid < 128) po[((size_t)bh*ACH + chunk)*128 + tid] = opart[0][tid] + opart[1][tid];
    if (tid == 0) {
        pms[(bh*ACH + chunk)*2]     = m;
        pms[(bh*ACH + chunk)*2 + 1] = ssum;
    }
}

__global__ __launch_bounds__(128) void attn_combine(
    const float* __restrict__ po, const float* __restrict__ pms,
    float* __restrict__ ob)
{
    const int bh = blockIdx.x, tid = threadIdx.x;
    __shared__ float sm_[ACH], ss_[ACH];
    if (tid < ACH) {
        sm_[tid] = pms[(bh*ACH + tid)*2];
        ss_[tid] = pms[(bh*ACH + tid)*2 + 1];
    }
    __syncthreads();
    float M = -1e30f;
#pragma unroll
    for (int i = 0; i < ACH; ++i) M = fmaxf(M, sm_[i]);
    float S = 0.f, acc = 0.f;
    for (int i = 0; i < ACH; ++i) {
        const float e = __expf(sm_[i] - M);
        S += e * ss_[i];
        acc = fmaf(e, po[((size_t)bh*ACH + i)*128 + tid], acc);
    }
    const int b = bh >> 2, h = bh & 3;
    ob[b*DD + h*128 + tid] = acc / S;
}

// ---------------- grouped temporal conv via MFMA, K-looped (v2) ----------------
// grid (32 t-tiles of 64, B*4). Block: out tile [64 t][128 oc] of group g.
// K = 384 (3 taps x 128 ic), K-steps of 64. Per step stage A (64 rows of
// x3b, t = t0 + r + tap - 1 clamped) + W (128 rows of wt) = 192x64 ushorts
// = 24 KB via pre-swizzled global_load_lds. Sequence-edge rows zeroed
// between barriers (1 row max per affected step). Waves 2x2 on 32x64 tiles.
__global__ __launch_bounds__(256) void teconv_mfma(
    const unsigned short* __restrict__ x3b, const unsigned short* __restrict__ wt,
    const float* __restrict__ x3, const float* __restrict__ tb,
    const float* __restrict__ bng, const float* __restrict__ bnb,
    const float* __restrict__ bnm, const float* __restrict__ bnv,
    float* __restrict__ out)
{
    __shared__ unsigned short lds[192 * 64];   // 24 KB; reused as cs[32][128] f32
    const int tid = threadIdx.x;
    const int t0 = blockIdx.x * 64;
    const int b = blockIdx.y >> 2, g = blockIdx.y & 3;
    const int lane = tid & 63, wid = tid >> 6;
    const int wr = wid >> 1, wc = wid & 1;
    const int l16 = lane & 15, lq = lane >> 4;
    const int swz = (l16 & 7) << 3;

    f32x4 acc[2][4];
#pragma unroll
    for (int mi = 0; mi < 2; ++mi)
#pragma unroll
        for (int ni = 0; ni < 4; ++ni) acc[mi][ni] = {0.f, 0.f, 0.f, 0.f};

#pragma unroll
    for (int kk = 0; kk < 6; ++kk) {
        const int tap = kk >> 1, ks0 = (kk & 1) * 64;
        // stage 192 rows x 8 chunks (6 full-wave iterations)
#pragma unroll
        for (int it = 0; it < 6; ++it) {
            const int cid = it * 256 + tid;
            const int r = cid >> 3, c = cid & 7;
            const int j = c ^ (r & 7);
            const unsigned short* gsrc;
            if (r < 64) {
                int t = t0 + r + tap - 1;
                t = (t < 0) ? 0 : ((t > LL-1) ? LL-1 : t);
                gsrc = x3b + ((size_t)b*LL + t)*DD + g*128 + ks0 + j*8;
            } else {
                gsrc = wt + (size_t)(g*128 + r - 64)*384 + tap*128 + ks0 + j*8;
            }
            gload_lds16(gsrc, &lds[(size_t)(cid & ~63) * 8]);
        }
        __syncthreads();
        // zero the single out-of-sequence A row (block-uniform condition)
        const bool zlow  = (t0 == 0      && tap == 0);   // row 0  -> t = -1
        const bool zhigh = (t0 == LL-64  && tap == 2);   // row 63 -> t = LL
        if (zlow || zhigh) {
            const int zr = zlow ? 0 : 63;
            if (tid < 16) *(ushort4*)&lds[zr*64 + tid*4] = ushort4{0,0,0,0};
            __syncthreads();
        }
#pragma unroll
        for (int ks = 0; ks < 64; ks += 32) {
            bf16x8 af[2], bfr[4];
#pragma unroll
            for (int mi = 0; mi < 2; ++mi) {
                const int r = wr*32 + mi*16 + l16;
                af[mi] = *(const bf16x8*)&lds[r*64 + ((ks + lq*8) ^ swz)];
            }
#pragma unroll
            for (int ni = 0; ni < 4; ++ni) {
                const int r = 64 + wc*64 + ni*16 + l16;
                bfr[ni] = *(const bf16x8*)&lds[r*64 + ((ks + lq*8) ^ swz)];
            }
#pragma unroll
            for (int mi = 0; mi < 2; ++mi)
#pragma unroll
                for (int ni = 0; ni < 4; ++ni)
                    acc[mi][ni] = __builtin_amdgcn_mfma_f32_16x16x32_bf16(
                        af[mi], bfr[ni], acc[mi][ni], 0, 0, 0);
        }
        __syncthreads();
    }
    // BN fold: v = acc*s + ((tb - bnm)*s + bnb)
    float sj[4], cj[4];
#pragma unroll
    for (int ni = 0; ni < 4; ++ni) {
        const int og = g*128 + wc*64 + ni*16 + l16;
        const float s = bng[og] * rsqrtf(bnv[og] + 1e-5f);
        sj[ni] = s;
        cj[ni] = (tb[og] - bnm[og]) * s + bnb[og];
    }
    float* cs = (float*)lds;   // [32][128]
#pragma unroll
    for (int h = 0; h < 2; ++h) {
        __syncthreads();
        if (wr == h) {
#pragma unroll
            for (int mi = 0; mi < 2; ++mi)
#pragma unroll
                for (int ni = 0; ni < 4; ++ni)
#pragma unroll
                    for (int r = 0; r < 4; ++r)
                        cs[(mi*16 + lq*4 + r)*128 + wc*64 + ni*16 + l16]
                            = acc[mi][ni][r] * sj[ni] + cj[ni];
        }
        __syncthreads();
#pragma unroll
        for (int j = 0; j < 4; ++j) {
            const int rl = (tid >> 5) + j*8;
            const int cl = (tid & 31) * 4;
            float4 v = *(const float4*)&cs[rl*128 + cl];
            const size_t oi = ((size_t)b*LL + t0 + h*32 + rl)*DD + g*128 + cl;
            float4 xr = *(const float4*)&x3[oi];
            v.x = xr.x + geluf(v.x);
            v.y = xr.y + geluf(v.y);
            v.z = xr.z + geluf(v.z);
            v.w = xr.w + geluf(v.w);
            *(float4*)&out[oi] = v;
        }
    }
}

// ---------------- launch ----------------
extern "C" void kernel_launch(void* const* d_in, const int* in_sizes, int n_in,
                              void* d_out, int out_size, void* d_ws, size_t ws_size,
                              hipStream_t stream)
{
    (void)in_sizes; (void)n_in; (void)out_size; (void)ws_size;
    const float* x         = (const float*)d_in[0];
    const float* freq      = (const float*)d_in[1];
    const float* in_proj_w = (const float*)d_in[2];
    const float* conv_w    = (const float*)d_in[3];
    const float* conv_b    = (const float*)d_in[4];
    const float* x_proj_w  = (const float*)d_in[5];
    const float* dt_proj_w = (const float*)d_in[6];
    const float* dt_proj_b = (const float*)d_in[7];
    const float* A_log     = (const float*)d_in[8];
    const float* ssm_D     = (const float*)d_in[9];
    const float* out_proj_w= (const float*)d_in[10];
    const float* fg_w1     = (const float*)d_in[11];
    const float* fg_b1     = (const float*)d_in[12];
    const float* fg_w2     = (const float*)d_in[13];
    const float* fg_b2     = (const float*)d_in[14];
    const float* attn_in_w = (const float*)d_in[15];
    const float* attn_in_b = (const float*)d_in[16];
    const float* attn_out_w= (const float*)d_in[17];
    const float* attn_out_b= (const float*)d_in[18];
    const float* te_w      = (const float*)d_in[19];
    const float* te_b      = (const float*)d_in[20];
    const float* bn_g      = (const float*)d_in[21];
    const float* bn_b      = (const float*)d_in[22];
    const float* bn_m      = (const float*)d_in[23];
    const float* bn_v      = (const float*)d_in[24];
    const float* ln1w = (const float*)d_in[25];
    const float* ln1b = (const float*)d_in[26];
    const float* ln2w = (const float*)d_in[27];
    const float* ln2b = (const float*)d_in[28];
    const float* ln3w = (const float*)d_in[29];
    const float* ln3b = (const float*)d_in[30];
    float* out = (float*)d_out;

    // ---- workspace layout (lifetime-overlapped), ~150 MB ----
    float* ws = (float*)d_ws;
    const size_t SEG = 8388608;                 // 8192*1024 floats = 32 MiB
    float* S1 = ws;                             // u_raw -> delta -> x2b/x3b (bf16)
    float* S2 = ws + SEG;                       // z_raw -> x1 | x3
    float* S3 = ws + 2*SEG;                     // u_act -> x2
    float* S4 = ws + 3*SEG;                     // xb -> uact_b -> ybuf_b -> kv
    float* xdbl = ws + 4*SEG;                   // 524288 f; later attn partials
    float* sm   = ws + 4*SEG + 524288;          // small scalars (16384 f)
    float* hseg = sm + 16384;                   // 2097152 f
    float* dsum = hseg + 2097152;               // 131072 f
    unsigned short* wb = (unsigned short*)(dsum + 131072);   // bf16 weights
    unsigned short* ipw_b = wb;                 // 1048576 us
    unsigned short* xpw_b = wb + 1048576;       // 65536 us
    unsigned short* opw_b = wb + 1114112;       // 524288 us
    unsigned short* kvw_b = wb + 1638400;       // 524288 us
    unsigned short* tew_b = wb + 2162688;       // 196608 us

    float* u_raw = S1;  float* deltab = S1;
    unsigned short* x2b = (unsigned short*)S1;            // first 8 MB of S1
    unsigned short* x3b = (unsigned short*)S1 + 4194304;  // next 8 MB of S1
    float* z_raw = S2;  float* x1 = S2;  float* x3 = S2 + 4194304;
    float* u_act = S3;  float* x2 = S3;
    unsigned short* xb      = (unsigned short*)S4;
    unsigned short* uact_b  = (unsigned short*)S4;
    unsigned short* ybuf_b  = (unsigned short*)S4;
    float* kv = S4;
    float* hidden = sm;        // 4096
    float* g  = sm + 4096;     // 2048
    float* qb = sm + 6144;     // 2048
    float* ob = sm + 8192;     // 2048
    float* ao = sm + 10240;    // 2048
    float* po  = xdbl;         // attn partial o (xdbl dead by then)
    float* pms = xdbl + 65536; // 1024 f

    dim3 blk(256);

    // 0) bf16 conversions: inputs + weights
    cvt_bf16<<<2048, blk, 0, stream>>>(x, xb, 4194304);
    cvt_bf16<<<512,  blk, 0, stream>>>(in_proj_w, ipw_b, 1048576);
    cvt_bf16<<<32,   blk, 0, stream>>>(x_proj_w, xpw_b, 65536);
    cvt_bf16<<<256,  blk, 0, stream>>>(out_proj_w, opw_b, 524288);
    cvt_bf16<<<256,  blk, 0, stream>>>(attn_in_w + 262144, kvw_b, 524288);
    cvt_tew<<<768,   blk, 0, stream>>>(te_w, tew_b);

    // 1) in_proj: u and z halves
    gemm_bf16g<<<dim3(8,64), blk, 0, stream>>>(xb, ipw_b,          u_raw, nullptr, DD, DD, DD, DI);
    gemm_bf16g<<<dim3(8,64), blk, 0, stream>>>(xb, ipw_b + 524288, z_raw, nullptr, DD, DD, DD, DI);
    // 2) causal depthwise conv + silu (4 t per thread)
    dwconv_silu<<<(BL*DI/4)/256, blk, 0, stream>>>(u_raw, conv_w, conv_b, u_act, uact_b);
    // 3) x_dbl = u @ x_proj^T  (split-K 16, atomic accumulate)
    zero_f32<<<512, blk, 0, stream>>>(xdbl, BL*64);
    gemm_xdbl_sk<<<dim3(16, 32), blk, 0, stream>>>(uact_b, xpw_b, xdbl);
    // 4) delta = softplus(dt @ dt_proj^T + b)
    delta_gemm<<<dim3(8, 64), blk, 0, stream>>>(xdbl, dt_proj_w, dt_proj_b, deltab);
    // 5) selective scan, chunked
    ssm_pass1<<<dim3(4, NSEG, BB), blk, 0, stream>>>(deltab, u_act, xdbl, A_log, hseg, dsum);
    ssm_seg_scan<<<256, blk, 0, stream>>>(A_log, dsum, hseg);
    ssm_pass2<<<dim3(4, NSEG, BB), blk, 0, stream>>>(deltab, u_act, z_raw, xdbl, A_log, ssm_D, hseg, ybuf_b);
    // 6) out_proj
    gemm_bf16g<<<dim3(4,64), blk, 0, stream>>>(ybuf_b, opw_b, x1, nullptr, DI, DI, DI, DD);
    // 7) freq gate MLP
    small_nt<1><<<16, blk, 0, stream>>>(freq,   fg_w1, fg_b1, hidden, BB, 2*DD, DD, DD);
    small_nt<2><<<8,  blk, 0, stream>>>(hidden, fg_w2, fg_b2, g,      BB, DD, 2*DD, 2*DD);
    // 8) ln1 * (1+g) + residual -> ln2
    ln_gate_res_ln2<<<BL, blk, 0, stream>>>(x1, x, g, ln1w, ln1b, ln2w, ln2b, x2, x2b);
    // 9) attention
    small_nt<0><<<8, blk, 0, stream>>>(freq, attn_in_w, attn_in_b, qb, BB, DD, DD, DD);
    gemm_bf16g<<<dim3(8,64), blk, 0, stream>>>(x2b, kvw_b, kv, attn_in_b + 512, DD, DD, DD, 2*DD);
    attn_part<<<dim3(ACH, BB*4), blk, 0, stream>>>(qb, kv, po, pms);
    attn_combine<<<BB*4, dim3(128), 0, stream>>>(po, pms, ob);
    small_nt<0><<<8, blk, 0, stream>>>(ob, attn_out_w, attn_out_b, ao, BB, DD, DD, DD);
    // 10) ln3(x2 + attn_broadcast), also emits bf16 for the conv
    add_bcast_ln<<<BL, blk, 0, stream>>>(x2, ao, ln3w, ln3b, x3, x3b);
    // 11) temporal conv (MFMA, K-looped) + BN + gelu + residual
    teconv_mfma<<<dim3(LL/64, BB*4), blk, 0, stream>>>(x3b, tew_b, x3, te_b, bn_g, bn_b, bn_m, bn_v, out);
}

// Round 10
// 313.022 us; speedup vs baseline: 6.4144x; 1.3386x over previous
//
#include <hip/hip_runtime.h>
#include <hip/hip_bf16.h>

// ---------------- constants ----------------
// B=4, L=2048, D=512, DI=1024, DS=16, DC=4, DTR=32, H=4, DH=128
#define BB 4
#define LL 2048
#define DD 512
#define DI 1024
#define DS 16
#define DTR 32
#define BL (BB*LL)   // 8192
#define NSEG 32
#define TSEG 64      // NSEG*TSEG == LL
#define ACH 32       // attention chunks per (b,h)

using bf16x8 = __attribute__((ext_vector_type(8))) short;
using f32x4  = __attribute__((ext_vector_type(4))) float;

// ---------------- helpers ----------------
__device__ __forceinline__ float geluf(float x) {
    return 0.5f * x * (1.f + erff(x * 0.7071067811865476f));
}

__device__ __forceinline__ unsigned short f2bf(float f) {
    unsigned u = __float_as_uint(f);
    u += 0x7FFFu + ((u >> 16) & 1u);   // round-to-nearest-even
    return (unsigned short)(u >> 16);
}

__device__ __forceinline__ void gload_lds16(const void* g, void* l) {
    __builtin_amdgcn_global_load_lds(
        (__attribute__((address_space(1))) void*)g,
        (__attribute__((address_space(3))) void*)l, 16, 0, 0);
}

__device__ __forceinline__ void block_reduce_sum2(float& a, float& b, float* sred) {
    for (int off = 32; off > 0; off >>= 1) {
        a += __shfl_down(a, off);
        b += __shfl_down(b, off);
    }
    const int lane = threadIdx.x & 63, wid = threadIdx.x >> 6;
    if (lane == 0) { sred[wid*2] = a; sred[wid*2+1] = b; }
    __syncthreads();
    a = sred[0] + sred[2] + sred[4] + sred[6];
    b = sred[1] + sred[3] + sred[5] + sred[7];
    __syncthreads();
}

__device__ __forceinline__ float block_reduce_max(float v, float* sred) {
    for (int off = 32; off > 0; off >>= 1) v = fmaxf(v, __shfl_down(v, off));
    const int lane = threadIdx.x & 63, wid = threadIdx.x >> 6;
    if (lane == 0) sred[wid] = v;
    __syncthreads();
    v = fmaxf(fmaxf(sred[0], sred[1]), fmaxf(sred[2], sred[3]));
    __syncthreads();
    return v;
}

__device__ __forceinline__ float block_reduce_sum1(float v, float* sred) {
    for (int off = 32; off > 0; off >>= 1) v += __shfl_down(v, off);
    const int lane = threadIdx.x & 63, wid = threadIdx.x >> 6;
    if (lane == 0) sred[wid] = v;
    __syncthreads();
    v = sred[0] + sred[1] + sred[2] + sred[3];
    __syncthreads();
    return v;
}

// ---------------- utility kernels ----------------
__global__ __launch_bounds__(256) void zero_f32(float* __restrict__ p, int n) {
    const int i = (blockIdx.x * 256 + threadIdx.x) * 4;
    if (i < n) { float4 z = {0.f,0.f,0.f,0.f}; *(float4*)(p + i) = z; }
}

__global__ __launch_bounds__(256) void cvt_bf16(
    const float* __restrict__ in, unsigned short* __restrict__ out, int n)
{
    const int i = (blockIdx.x * 256 + threadIdx.x) * 8;
    if (i >= n) return;
    float4 a = *(const float4*)(in + i);
    float4 b = *(const float4*)(in + i + 4);
    ushort4 h0 = { f2bf(a.x), f2bf(a.y), f2bf(a.z), f2bf(a.w) };
    ushort4 h1 = { f2bf(b.x), f2bf(b.y), f2bf(b.z), f2bf(b.w) };
    *(ushort4*)(out + i)     = h0;
    *(ushort4*)(out + i + 4) = h1;
}

// te_conv_w [512][128][3] -> wt [512][384] bf16, col = j*128 + ic
__global__ __launch_bounds__(256) void cvt_tew(
    const float* __restrict__ tw, unsigned short* __restrict__ wt)
{
    const int i = blockIdx.x * 256 + threadIdx.x;
    if (i >= 512 * 384) return;
    const int oc = i / 384, rem = i - oc * 384;
    const int j = rem >> 7, ic = rem & 127;
    wt[i] = f2bf(tw[oc * 384 + ic * 3 + j]);
}

// init C[4][N] buffers with their bias rows (exactly once, before split-K)
__global__ __launch_bounds__(256) void init_bias_all(
    const float* __restrict__ fg_b1, const float* __restrict__ fg_b2,
    const float* __restrict__ attn_in_b, const float* __restrict__ attn_out_b,
    float* __restrict__ hidden, float* __restrict__ g,
    float* __restrict__ qb, float* __restrict__ ao)
{
    const int i = blockIdx.x * 256 + threadIdx.x;   // 0..2559
    if (i < 1024) {
        const float b = fg_b1[i];
        hidden[i] = b; hidden[1024+i] = b; hidden[2048+i] = b; hidden[3072+i] = b;
    } else if (i < 1536) {
        const int c = i - 1024; const float b = fg_b2[c];
        g[c] = b; g[512+c] = b; g[1024+c] = b; g[1536+c] = b;
    } else if (i < 2048) {
        const int c = i - 1536; const float b = attn_in_b[c];
        qb[c] = b; qb[512+c] = b; qb[1024+c] = b; qb[1536+c] = b;
    } else if (i < 2560) {
        const int c = i - 2048; const float b = attn_out_b[c];
        ao[c] = b; ao[512+c] = b; ao[1024+c] = b; ao[1536+c] = b;
    }
}

// ---------------- tiny M=4 GEMM, split-K with atomics ----------------
// C[4,N] += epiA(A[4,k-chunk]) @ W[N,k-chunk]^T. grid (N/64, K/64).
// EPI_A: 0 none, 1 gelu (applied to A on load).
template<int EPI_A>
__global__ __launch_bounds__(256) void tiny_sk(
    const float* __restrict__ A, const float* __restrict__ W,
    float* __restrict__ C, int N, int K, int lda)
{
    __shared__ float sA[4][68];
    const int tid = threadIdx.x;
    const int n0 = blockIdx.x * 64, k0 = blockIdx.y * 64;
    if (tid < 4*64) {
        const int r = tid >> 6, k = tid & 63;
        float v = A[(size_t)r * lda + k0 + k];
        if (EPI_A == 1) v = geluf(v);
        sA[r][k] = v;
    }
    __syncthreads();
    const int col = tid >> 2, kq = tid & 3;
    const float* wrow = W + (size_t)(n0 + col) * K + k0 + kq * 16;
    float a0 = 0.f, a1 = 0.f, a2 = 0.f, a3 = 0.f;
#pragma unroll
    for (int i = 0; i < 16; i += 4) {
        const float4 wv = *(const float4*)(wrow + i);
        const int k = kq * 16 + i;
        a0 += wv.x*sA[0][k] + wv.y*sA[0][k+1] + wv.z*sA[0][k+2] + wv.w*sA[0][k+3];
        a1 += wv.x*sA[1][k] + wv.y*sA[1][k+1] + wv.z*sA[1][k+2] + wv.w*sA[1][k+3];
        a2 += wv.x*sA[2][k] + wv.y*sA[2][k+1] + wv.z*sA[2][k+2] + wv.w*sA[2][k+3];
        a3 += wv.x*sA[3][k] + wv.y*sA[3][k+1] + wv.z*sA[3][k+2] + wv.w*sA[3][k+3];
    }
    a0 += __shfl_xor(a0, 1); a0 += __shfl_xor(a0, 2);
    a1 += __shfl_xor(a1, 1); a1 += __shfl_xor(a1, 2);
    a2 += __shfl_xor(a2, 1); a2 += __shfl_xor(a2, 2);
    a3 += __shfl_xor(a3, 1); a3 += __shfl_xor(a3, 2);
    if (kq == 0) {
        atomicAdd(&C[0*N + n0 + col], a0);
        atomicAdd(&C[1*N + n0 + col], a1);
        atomicAdd(&C[2*N + n0 + col], a2);
        atomicAdd(&C[3*N + n0 + col], a3);
    }
}

// ---------------- bf16 MFMA GEMM 128x128 tile, global_load_lds staging ----------------
__global__ __launch_bounds__(256) void gemm_bf16g(
    const unsigned short* __restrict__ A, const unsigned short* __restrict__ W,
    float* __restrict__ C, const float* __restrict__ bias,
    int K, int lda, int ldw, int ldc)
{
    __shared__ unsigned short lds[256 * 64];   // 32 KB; reused as cs[64][128] f32
    const int tid = threadIdx.x;
    const int bm = blockIdx.y * 128, bn = blockIdx.x * 128;
    const int lane = tid & 63, wid = tid >> 6;
    const int wr = wid >> 1, wc = wid & 1;
    const int l16 = lane & 15, lq = lane >> 4;
    const int swz = (l16 & 7) << 3;

    f32x4 acc[4][4];
#pragma unroll
    for (int mi = 0; mi < 4; ++mi)
#pragma unroll
        for (int ni = 0; ni < 4; ++ni) acc[mi][ni] = {0.f, 0.f, 0.f, 0.f};

    for (int k0 = 0; k0 < K; k0 += 64) {
#pragma unroll
        for (int it = 0; it < 8; ++it) {
            const int cid = it * 256 + tid;            // 16B-chunk id
            const int r = cid >> 3, c = cid & 7;
            const int j = c ^ (r & 7);                 // pre-swizzled source chunk
            const unsigned short* gsrc =
                (r < 128 ? A + (size_t)(bm + r) * lda : W + (size_t)(bn + r - 128) * ldw)
                + k0 + j * 8;
            gload_lds16(gsrc, &lds[(size_t)(cid & ~63) * 8]);
        }
        __syncthreads();
#pragma unroll
        for (int ks = 0; ks < 64; ks += 32) {
            bf16x8 af[4], bfr[4];
#pragma unroll
            for (int mi = 0; mi < 4; ++mi) {
                const int r = wr*64 + mi*16 + l16;
                af[mi] = *(const bf16x8*)&lds[r*64 + ((ks + lq*8) ^ swz)];
            }
#pragma unroll
            for (int ni = 0; ni < 4; ++ni) {
                const int r = 128 + wc*64 + ni*16 + l16;
                bfr[ni] = *(const bf16x8*)&lds[r*64 + ((ks + lq*8) ^ swz)];
            }
#pragma unroll
            for (int mi = 0; mi < 4; ++mi)
#pragma unroll
                for (int ni = 0; ni < 4; ++ni)
                    acc[mi][ni] = __builtin_amdgcn_mfma_f32_16x16x32_bf16(
                        af[mi], bfr[ni], acc[mi][ni], 0, 0, 0);
        }
        __syncthreads();
    }
    float bj[4];
#pragma unroll
    for (int ni = 0; ni < 4; ++ni)
        bj[ni] = bias ? bias[bn + wc*64 + ni*16 + l16] : 0.f;
    float* cs = (float*)lds;   // [64][128]
#pragma unroll
    for (int h = 0; h < 2; ++h) {
        __syncthreads();
        if (wr == h) {
#pragma unroll
            for (int mi = 0; mi < 4; ++mi)
#pragma unroll
                for (int ni = 0; ni < 4; ++ni)
#pragma unroll
                    for (int r = 0; r < 4; ++r)
                        cs[(mi*16 + lq*4 + r)*128 + wc*64 + ni*16 + l16]
                            = acc[mi][ni][r] + bj[ni];
        }
        __syncthreads();
#pragma unroll
        for (int j = 0; j < 8; ++j) {
            const int rl = (tid >> 5) + j*8;
            const int cl = (tid & 31) * 4;
            float4 v = *(const float4*)&cs[rl*128 + cl];
            *(float4*)&C[(size_t)(bm + h*64 + rl) * ldc + bn + cl] = v;
        }
    }
}

// ---------------- xdbl split-K GEMM: C[M,64] += A-slice @ W-slice^T ----------------
__global__ __launch_bounds__(256) void gemm_xdbl_sk(
    const unsigned short* __restrict__ A, const unsigned short* __restrict__ W,
    float* __restrict__ C)
{
    __shared__ unsigned short lds[320 * 64];
    const int tid = threadIdx.x;
    const int k0 = blockIdx.x * 64;
    const int bm = blockIdx.y * 256;
    const int lane = tid & 63, wid = tid >> 6;
    const int l16 = lane & 15, lq = lane >> 4;
    const int swz = (l16 & 7) << 3;
#pragma unroll
    for (int it = 0; it < 10; ++it) {
        const int cid = it * 256 + tid;
        const int r = cid >> 3, c = cid & 7;
        const int j = c ^ (r & 7);
        const unsigned short* gsrc =
            (r < 256 ? A + (size_t)(bm + r) * DI : W + (size_t)(r - 256) * DI) + k0 + j * 8;
        gload_lds16(gsrc, &lds[(size_t)(cid & ~63) * 8]);
    }
    __syncthreads();
    f32x4 acc[4][4];
#pragma unroll
    for (int mi = 0; mi < 4; ++mi)
#pragma unroll
        for (int ni = 0; ni < 4; ++ni) acc[mi][ni] = {0.f, 0.f, 0.f, 0.f};
#pragma unroll
    for (int ks = 0; ks < 64; ks += 32) {
        bf16x8 af[4], bfr[4];
#pragma unroll
        for (int mi = 0; mi < 4; ++mi) {
            const int r = wid*64 + mi*16 + l16;
            af[mi] = *(const bf16x8*)&lds[r*64 + ((ks + lq*8) ^ swz)];
        }
#pragma unroll
        for (int ni = 0; ni < 4; ++ni) {
            const int r = 256 + ni*16 + l16;
            bfr[ni] = *(const bf16x8*)&lds[r*64 + ((ks + lq*8) ^ swz)];
        }
#pragma unroll
        for (int mi = 0; mi < 4; ++mi)
#pragma unroll
            for (int ni = 0; ni < 4; ++ni)
                acc[mi][ni] = __builtin_amdgcn_mfma_f32_16x16x32_bf16(
                    af[mi], bfr[ni], acc[mi][ni], 0, 0, 0);
    }
#pragma unroll
    for (int ni = 0; ni < 4; ++ni) {
        const int col = ni*16 + l16;
#pragma unroll
        for (int mi = 0; mi < 4; ++mi) {
            const int row = bm + wid*64 + mi*16 + lq*4;
#pragma unroll
            for (int r = 0; r < 4; ++r)
                atomicAdd(&C[(size_t)(row + r) * 64 + col], acc[mi][ni][r]);
        }
    }
}

// ---------------- delta GEMM: softplus(xdbl[:,0:32] @ dt_proj_w^T + b) ----------------
__global__ __launch_bounds__(256) void delta_gemm(
    const float* __restrict__ xdbl, const float* __restrict__ dtw,
    const float* __restrict__ dtb, float* __restrict__ delta)
{
    __shared__ char smem[64 * 128 * 4];   // 32 KB: staging then cs
    unsigned short* As = (unsigned short*)smem;          // [128][34]
    unsigned short* Ws = As + 128 * 34;                  // [128][34]
    const int tid = threadIdx.x;
    const int bn = blockIdx.x * 128, bm = blockIdx.y * 128;
    for (int i = tid; i < 128 * 8; i += 256) {
        const int r = i >> 3, c4 = (i & 7) * 4;
        float4 va = *(const float4*)(xdbl + (size_t)(bm + r) * 64 + c4);
        ushort4 ha = { f2bf(va.x), f2bf(va.y), f2bf(va.z), f2bf(va.w) };
        *(ushort4*)&As[r * 34 + c4] = ha;
        float4 vw = *(const float4*)(dtw + (size_t)(bn + r) * 32 + c4);
        ushort4 hw = { f2bf(vw.x), f2bf(vw.y), f2bf(vw.z), f2bf(vw.w) };
        *(ushort4*)&Ws[r * 34 + c4] = hw;
    }
    __syncthreads();
    const int lane = tid & 63, wid = tid >> 6;
    const int wr = wid >> 1, wc = wid & 1;
    const int l16 = lane & 15, lq = lane >> 4;
    bf16x8 af[4], wf[4];
#pragma unroll
    for (int mi = 0; mi < 4; ++mi)
        af[mi] = *(const bf16x8*)&As[(wr*64 + mi*16 + l16) * 34 + lq*8];
#pragma unroll
    for (int ni = 0; ni < 4; ++ni)
        wf[ni] = *(const bf16x8*)&Ws[(wc*64 + ni*16 + l16) * 34 + lq*8];
    f32x4 acc[4][4];
#pragma unroll
    for (int mi = 0; mi < 4; ++mi)
#pragma unroll
        for (int ni = 0; ni < 4; ++ni) {
            f32x4 z = {0.f, 0.f, 0.f, 0.f};
            acc[mi][ni] = __builtin_amdgcn_mfma_f32_16x16x32_bf16(af[mi], wf[ni], z, 0, 0, 0);
        }
    float bj[4];
#pragma unroll
    for (int ni = 0; ni < 4; ++ni) bj[ni] = dtb[bn + wc*64 + ni*16 + l16];
    float* cs = (float*)smem;   // [64][128]
#pragma unroll
    for (int h = 0; h < 2; ++h) {
        __syncthreads();
        if (wr == h) {
#pragma unroll
            for (int mi = 0; mi < 4; ++mi)
#pragma unroll
                for (int ni = 0; ni < 4; ++ni)
#pragma unroll
                    for (int r = 0; r < 4; ++r)
                        cs[(mi*16 + lq*4 + r)*128 + wc*64 + ni*16 + l16]
                            = acc[mi][ni][r] + bj[ni];
        }
        __syncthreads();
#pragma unroll
        for (int j = 0; j < 8; ++j) {
            const int rl = (tid >> 5) + j*8;
            const int cl = (tid & 31) * 4;
            float4 v = *(const float4*)&cs[rl*128 + cl];
            v.x = (v.x > 20.f) ? v.x : __logf(1.f + __expf(v.x));
            v.y = (v.y > 20.f) ? v.y : __logf(1.f + __expf(v.y));
            v.z = (v.z > 20.f) ? v.z : __logf(1.f + __expf(v.z));
            v.w = (v.w > 20.f) ? v.w : __logf(1.f + __expf(v.w));
            *(float4*)&delta[(size_t)(bm + h*64 + rl) * DI + bn + cl] = v;
        }
    }
}

// ---------------- causal depthwise conv (k=4) + SiLU, 4 t per thread ----------------
__global__ __launch_bounds__(256) void dwconv_silu(
    const float* __restrict__ u, const float* __restrict__ cw,
    const float* __restrict__ cb, float* __restrict__ out,
    unsigned short* __restrict__ out_bf)
{
    const int idx = blockIdx.x * 256 + threadIdx.x;   // < BL*DI/4
    const int c = idx & (DI-1);
    const int rg = idx >> 10;          // 0..2047
    const int b = rg >> 9;
    const int t4 = (rg & 511) * 4;
    const size_t base = ((size_t)b*LL + t4)*DI + c;
    const float4 w = *(const float4*)(cw + c*4);
    const float bb = cb[c];
    float x[7];
#pragma unroll
    for (int j = 0; j < 7; ++j) {
        const int t = t4 - 3 + j;
        x[j] = (t >= 0) ? u[base + (size_t)(j-3)*DI] : 0.f;
    }
#pragma unroll
    for (int i = 0; i < 4; ++i) {
        float s = bb;
        s = fmaf(w.x, x[i],   s);
        s = fmaf(w.y, x[i+1], s);
        s = fmaf(w.z, x[i+2], s);
        s = fmaf(w.w, x[i+3], s);
        const float v = s / (1.f + __expf(-s));
        out[base + (size_t)i*DI] = v;
        out_bf[base + (size_t)i*DI] = f2bf(v);
    }
}

// ---------------- SSM chunked scan ----------------
__global__ __launch_bounds__(256) void ssm_pass1(
    const float* __restrict__ delta, const float* __restrict__ uact,
    const float* __restrict__ xdbl, const float* __restrict__ A_log,
    float* __restrict__ hseg, float* __restrict__ dsum)
{
    const int tid = threadIdx.x;
    const int ch = blockIdx.x * 256 + tid;
    const int seg = blockIdx.y, b = blockIdx.z;
    const size_t rb = (size_t)b * LL + seg * TSEG;
    __shared__ float sB[TSEG][16];
    for (int i = tid; i < TSEG*16; i += 256) {
        const int tt = i >> 4, s = i & 15;
        sB[tt][s] = xdbl[(rb + tt)*64 + 32 + s];
    }
    float Av[16];
#pragma unroll
    for (int s = 0; s < 16; ++s) Av[s] = -__expf(A_log[ch*16 + s]);
    __syncthreads();
    float h[16] = {};
    float ds = 0.f;
    float d  = delta[rb*DI + ch];
    float uu = uact [rb*DI + ch];
    for (int t = 0; t < TSEG; ++t) {
        const int tn = (t + 1 < TSEG) ? t + 1 : t;
        const float dn = delta[(rb + tn)*DI + ch];
        const float un = uact [(rb + tn)*DI + ch];
        ds += d;
        const float du = d * uu;
#pragma unroll
        for (int s = 0; s < 16; ++s) {
            const float a = __expf(d * Av[s]);
            h[s] = fmaf(a, h[s], du * sB[t][s]);
        }
        d = dn; uu = un;
    }
    float* hp = hseg + (((size_t)b*NSEG + seg)*DI + ch)*16;
    float4 o0 = {h[0],h[1],h[2],h[3]},   o1 = {h[4],h[5],h[6],h[7]};
    float4 o2 = {h[8],h[9],h[10],h[11]}, o3 = {h[12],h[13],h[14],h[15]};
    *(float4*)(hp)    = o0; *(float4*)(hp+4)  = o1;
    *(float4*)(hp+8)  = o2; *(float4*)(hp+12) = o3;
    dsum[((size_t)b*NSEG + seg)*DI + ch] = ds;
}

__global__ __launch_bounds__(256) void ssm_seg_scan(
    const float* __restrict__ A_log, const float* __restrict__ dsum,
    float* __restrict__ hseg)
{
    const int idx = blockIdx.x * 256 + threadIdx.x;
    const int s = idx & 15;
    const int bc = idx >> 4;
    const int ch = bc & (DI-1);
    const int b = bc >> 10;
    const float Av = -__expf(A_log[ch*16 + s]);
    float g = 0.f;
    for (int seg = 0; seg < NSEG; ++seg) {
        const size_t soff = ((size_t)b*NSEG + seg)*DI + ch;
        const float hloc = hseg[soff*16 + s];
        const float a = __expf(Av * dsum[soff]);
        hseg[soff*16 + s] = g;
        g = fmaf(a, g, hloc);
    }
}

__global__ __launch_bounds__(256) void ssm_pass2(
    const float* __restrict__ delta, const float* __restrict__ uact,
    const float* __restrict__ z, const float* __restrict__ xdbl,
    const float* __restrict__ A_log, const float* __restrict__ ssm_D,
    const float* __restrict__ hin, unsigned short* __restrict__ y)
{
    const int tid = threadIdx.x;
    const int ch = blockIdx.x * 256 + tid;
    const int seg = blockIdx.y, b = blockIdx.z;
    const size_t rb = (size_t)b * LL + seg * TSEG;
    __shared__ float sB[TSEG][16], sC[TSEG][16];
    for (int i = tid; i < TSEG*16; i += 256) {
        const int tt = i >> 4, s = i & 15;
        sB[tt][s] = xdbl[(rb + tt)*64 + 32 + s];
        sC[tt][s] = xdbl[(rb + tt)*64 + 48 + s];
    }
    float Av[16];
#pragma unroll
    for (int s = 0; s < 16; ++s) Av[s] = -__expf(A_log[ch*16 + s]);
    float h[16];
    const float* hp = hin + (((size_t)b*NSEG + seg)*DI + ch)*16;
#pragma unroll
    for (int s = 0; s < 16; ++s) h[s] = hp[s];
    const float Dc = ssm_D[ch];
    __syncthreads();
    float d  = delta[rb*DI + ch];
    float uu = uact [rb*DI + ch];
    float zz = z    [rb*DI + ch];
    for (int t = 0; t < TSEG; ++t) {
        const int tn = (t + 1 < TSEG) ? t + 1 : t;
        const float dn = delta[(rb + tn)*DI + ch];
        const float un = uact [(rb + tn)*DI + ch];
        const float zn = z    [(rb + tn)*DI + ch];
        const float du = d * uu;
        float p = 0.f;
#pragma unroll
        for (int s = 0; s < 16; ++s) {
            const float a = __expf(d * Av[s]);
            h[s] = fmaf(a, h[s], du * sB[t][s]);
            p = fmaf(h[s], sC[t][s], p);
        }
        const float sil = zz / (1.f + __expf(-zz));
        y[(rb + t)*DI + ch] = f2bf((p + uu*Dc) * sil);
        d = dn; uu = un; zz = zn;
    }
}

// ---------------- ln1 * (1+sigmoid(graw)) + residual -> ln2 (f32 + bf16 out) ----------------
__global__ __launch_bounds__(256) void ln_gate_res_ln2(
    const float* __restrict__ x1raw, const float* __restrict__ xres,
    const float* __restrict__ graw,
    const float* __restrict__ w1, const float* __restrict__ b1,
    const float* __restrict__ w2, const float* __restrict__ b2,
    float* __restrict__ x2, unsigned short* __restrict__ x2b)
{
    __shared__ float sred[8];
    const int row = blockIdx.x;
    const int b = row >> 11;
    const int c = threadIdx.x * 2;
    const size_t base = (size_t)row * DD;
    float2 v = *(const float2*)(x1raw + base + c);
    float s = v.x + v.y, ss = v.x*v.x + v.y*v.y;
    block_reduce_sum2(s, ss, sred);
    float mean = s * (1.f/DD);
    float rs = rsqrtf(fmaxf(ss * (1.f/DD) - mean*mean, 0.f) + 1e-5f);
    float2 xr = *(const float2*)(xres + base + c);
    const float g0 = 1.f + 1.f/(1.f + __expf(-graw[b*DD + c]));
    const float g1 = 1.f + 1.f/(1.f + __expf(-graw[b*DD + c + 1]));
    float y0 = ((v.x - mean)*rs*w1[c]   + b1[c]  ) * g0 + xr.x;
    float y1 = ((v.y - mean)*rs*w1[c+1] + b1[c+1]) * g1 + xr.y;
    s = y0 + y1; ss = y0*y0 + y1*y1;
    block_reduce_sum2(s, ss, sred);
    mean = s * (1.f/DD);
    rs = rsqrtf(fmaxf(ss * (1.f/DD) - mean*mean, 0.f) + 1e-5f);
    float2 o;
    o.x = (y0 - mean)*rs*w2[c]   + b2[c];
    o.y = (y1 - mean)*rs*w2[c+1] + b2[c+1];
    *(float2*)(x2 + base + c) = o;
    ushort2 ob = { f2bf(o.x), f2bf(o.y) };
    *(ushort2*)(x2b + base + c) = ob;
}

// ---------------- x + broadcast(add[b]) -> LN (f32 + bf16 out) ----------------
__global__ __launch_bounds__(256) void add_bcast_ln(
    const float* __restrict__ xin, const float* __restrict__ addb,
    const float* __restrict__ w, const float* __restrict__ bb,
    float* __restrict__ out, unsigned short* __restrict__ outb)
{
    __shared__ float sred[8];
    const int row = blockIdx.x, b = row >> 11, c = threadIdx.x * 2;
    const size_t base = (size_t)row * DD;
    float2 v = *(const float2*)(xin + base + c);
    v.x += addb[b*DD + c];
    v.y += addb[b*DD + c + 1];
    float s = v.x + v.y, ss = v.x*v.x + v.y*v.y;
    block_reduce_sum2(s, ss, sred);
    float mean = s * (1.f/DD);
    float rs = rsqrtf(fmaxf(ss * (1.f/DD) - mean*mean, 0.f) + 1e-5f);
    float2 o = { (v.x - mean)*rs*w[c] + bb[c], (v.y - mean)*rs*w[c+1] + bb[c+1] };
    *(float2*)(out + base + c) = o;
    ushort2 ob = { f2bf(o.x), f2bf(o.y) };
    *(ushort2*)(outb + base + c) = ob;
}

// ---------------- cross-attention, flash-split ----------------
__global__ __launch_bounds__(256) void attn_part(
    const float* __restrict__ q, const float* __restrict__ kv,
    float* __restrict__ po, float* __restrict__ pms)
{
    const int chunk = blockIdx.x, bh = blockIdx.y;
    const int b = bh >> 2, h = bh & 3;
    const int tid = threadIdx.x;
    __shared__ float sq[128];
    __shared__ float se[64];
    __shared__ float sred[8];
    __shared__ float opart[2][128];
    if (tid < 128) sq[tid] = q[b*DD + h*128 + tid];
    __syncthreads();
    const int r = tid >> 2, p = tid & 3;
    const int trow = chunk*64 + r;
    const float* kr = kv + ((size_t)(b*LL + trow))*1024 + h*128 + p*32;
    float dot = 0.f;
#pragma unroll
    for (int d = 0; d < 32; d += 4) {
        float4 k4 = *(const float4*)(kr + d);
        dot += sq[p*32+d]*k4.x + sq[p*32+d+1]*k4.y + sq[p*32+d+2]*k4.z + sq[p*32+d+3]*k4.w;
    }
    dot += __shfl_xor(dot, 1);
    dot += __shfl_xor(dot, 2);
    if (p == 0) se[r] = dot * 0.088388347648318447f;
    __syncthreads();
    const float lm = (tid < 64) ? se[tid] : -1e30f;
    const float m = block_reduce_max(lm, sred);
    float le = 0.f;
    if (tid < 64) { le = __expf(se[tid] - m); se[tid] = le; }
    const float ssum = block_reduce_sum1(le, sred);
    const int d = tid & 127, half = tid >> 7;
    float acc = 0.f;
    for (int rr = half; rr < 64; rr += 2)
        acc = fmaf(se[rr], kv[((size_t)(b*LL + chunk*64 + rr))*1024 + 512 + h*128 + d], acc);
    opart[half][d] = acc;
    __syncthreads();
    if (tid < 128) po[((size_t)bh*ACH + chunk)*128 + tid] = opart[0][tid] + opart[1][tid];
    if (tid == 0) {
        pms[(bh*ACH + chunk)*2]     = m;
        pms[(bh*ACH + chunk)*2 + 1] = ssum;
    }
}

__global__ __launch_bounds__(128) void attn_combine(
    const float* __restrict__ po, const float* __restrict__ pms,
    float* __restrict__ ob)
{
    const int bh = blockIdx.x, tid = threadIdx.x;
    __shared__ float sm_[ACH], ss_[ACH];
    if (tid < ACH) {
        sm_[tid] = pms[(bh*ACH + tid)*2];
        ss_[tid] = pms[(bh*ACH + tid)*2 + 1];
    }
    __syncthreads();
    float M = -1e30f;
#pragma unroll
    for (int i = 0; i < ACH; ++i) M = fmaxf(M, sm_[i]);
    float S = 0.f, acc = 0.f;
    for (int i = 0; i < ACH; ++i) {
        const float e = __expf(sm_[i] - M);
        S += e * ss_[i];
        acc = fmaf(e, po[((size_t)bh*ACH + i)*128 + tid], acc);
    }
    const int b = bh >> 2, h = bh & 3;
    ob[b*DD + h*128 + tid] = acc / S;
}

// ---------------- grouped temporal conv via MFMA, K-looped (v2) ----------------
__global__ __launch_bounds__(256) void teconv_mfma(
    const unsigned short* __restrict__ x3b, const unsigned short* __restrict__ wt,
    const float* __restrict__ x3, const float* __restrict__ tb,
    const float* __restrict__ bng, const float* __restrict__ bnb,
    const float* __restrict__ bnm, const float* __restrict__ bnv,
    float* __restrict__ out)
{
    __shared__ unsigned short lds[192 * 64];   // 24 KB; reused as cs[32][128] f32
    const int tid = threadIdx.x;
    const int t0 = blockIdx.x * 64;
    const int b = blockIdx.y >> 2, g = blockIdx.y & 3;
    const int lane = tid & 63, wid = tid >> 6;
    const int wr = wid >> 1, wc = wid & 1;
    const int l16 = lane & 15, lq = lane >> 4;
    const int swz = (l16 & 7) << 3;

    f32x4 acc[2][4];
#pragma unroll
    for (int mi = 0; mi < 2; ++mi)
#pragma unroll
        for (int ni = 0; ni < 4; ++ni) acc[mi][ni] = {0.f, 0.f, 0.f, 0.f};

#pragma unroll
    for (int kk = 0; kk < 6; ++kk) {
        const int tap = kk >> 1, ks0 = (kk & 1) * 64;
#pragma unroll
        for (int it = 0; it < 6; ++it) {
            const int cid = it * 256 + tid;
            const int r = cid >> 3, c = cid & 7;
            const int j = c ^ (r & 7);
            const unsigned short* gsrc;
            if (r < 64) {
                int t = t0 + r + tap - 1;
                t = (t < 0) ? 0 : ((t > LL-1) ? LL-1 : t);
                gsrc = x3b + ((size_t)b*LL + t)*DD + g*128 + ks0 + j*8;
            } else {
                gsrc = wt + (size_t)(g*128 + r - 64)*384 + tap*128 + ks0 + j*8;
            }
            gload_lds16(gsrc, &lds[(size_t)(cid & ~63) * 8]);
        }
        __syncthreads();
        const bool zlow  = (t0 == 0      && tap == 0);   // row 0  -> t = -1
        const bool zhigh = (t0 == LL-64  && tap == 2);   // row 63 -> t = LL
        if (zlow || zhigh) {
            const int zr = zlow ? 0 : 63;
            if (tid < 16) *(ushort4*)&lds[zr*64 + tid*4] = ushort4{0,0,0,0};
            __syncthreads();
        }
#pragma unroll
        for (int ks = 0; ks < 64; ks += 32) {
            bf16x8 af[2], bfr[4];
#pragma unroll
            for (int mi = 0; mi < 2; ++mi) {
                const int r = wr*32 + mi*16 + l16;
                af[mi] = *(const bf16x8*)&lds[r*64 + ((ks + lq*8) ^ swz)];
            }
#pragma unroll
            for (int ni = 0; ni < 4; ++ni) {
                const int r = 64 + wc*64 + ni*16 + l16;
                bfr[ni] = *(const bf16x8*)&lds[r*64 + ((ks + lq*8) ^ swz)];
            }
#pragma unroll
            for (int mi = 0; mi < 2; ++mi)
#pragma unroll
                for (int ni = 0; ni < 4; ++ni)
                    acc[mi][ni] = __builtin_amdgcn_mfma_f32_16x16x32_bf16(
                        af[mi], bfr[ni], acc[mi][ni], 0, 0, 0);
        }
        __syncthreads();
    }
    float sj[4], cj[4];
#pragma unroll
    for (int ni = 0; ni < 4; ++ni) {
        const int og = g*128 + wc*64 + ni*16 + l16;
        const float s = bng[og] * rsqrtf(bnv[og] + 1e-5f);
        sj[ni] = s;
        cj[ni] = (tb[og] - bnm[og]) * s + bnb[og];
    }
    float* cs = (float*)lds;   // [32][128]
#pragma unroll
    for (int h = 0; h < 2; ++h) {
        __syncthreads();
        if (wr == h) {
#pragma unroll
            for (int mi = 0; mi < 2; ++mi)
#pragma unroll
                for (int ni = 0; ni < 4; ++ni)
#pragma unroll
                    for (int r = 0; r < 4; ++r)
                        cs[(mi*16 + lq*4 + r)*128 + wc*64 + ni*16 + l16]
                            = acc[mi][ni][r] * sj[ni] + cj[ni];
        }
        __syncthreads();
#pragma unroll
        for (int j = 0; j < 4; ++j) {
            const int rl = (tid >> 5) + j*8;
            const int cl = (tid & 31) * 4;
            float4 v = *(const float4*)&cs[rl*128 + cl];
            const size_t oi = ((size_t)b*LL + t0 + h*32 + rl)*DD + g*128 + cl;
            float4 xr = *(const float4*)&x3[oi];
            v.x = xr.x + geluf(v.x);
            v.y = xr.y + geluf(v.y);
            v.z = xr.z + geluf(v.z);
            v.w = xr.w + geluf(v.w);
            *(float4*)&out[oi] = v;
        }
    }
}

// ---------------- launch ----------------
extern "C" void kernel_launch(void* const* d_in, const int* in_sizes, int n_in,
                              void* d_out, int out_size, void* d_ws, size_t ws_size,
                              hipStream_t stream)
{
    (void)in_sizes; (void)n_in; (void)out_size; (void)ws_size;
    const float* x         = (const float*)d_in[0];
    const float* freq      = (const float*)d_in[1];
    const float* in_proj_w = (const float*)d_in[2];
    const float* conv_w    = (const float*)d_in[3];
    const float* conv_b    = (const float*)d_in[4];
    const float* x_proj_w  = (const float*)d_in[5];
    const float* dt_proj_w = (const float*)d_in[6];
    const float* dt_proj_b = (const float*)d_in[7];
    const float* A_log     = (const float*)d_in[8];
    const float* ssm_D     = (const float*)d_in[9];
    const float* out_proj_w= (const float*)d_in[10];
    const float* fg_w1     = (const float*)d_in[11];
    const float* fg_b1     = (const float*)d_in[12];
    const float* fg_w2     = (const float*)d_in[13];
    const float* fg_b2     = (const float*)d_in[14];
    const float* attn_in_w = (const float*)d_in[15];
    const float* attn_in_b = (const float*)d_in[16];
    const float* attn_out_w= (const float*)d_in[17];
    const float* attn_out_b= (const float*)d_in[18];
    const float* te_w      = (const float*)d_in[19];
    const float* te_b      = (const float*)d_in[20];
    const float* bn_g      = (const float*)d_in[21];
    const float* bn_b      = (const float*)d_in[22];
    const float* bn_m      = (const float*)d_in[23];
    const float* bn_v      = (const float*)d_in[24];
    const float* ln1w = (const float*)d_in[25];
    const float* ln1b = (const float*)d_in[26];
    const float* ln2w = (const float*)d_in[27];
    const float* ln2b = (const float*)d_in[28];
    const float* ln3w = (const float*)d_in[29];
    const float* ln3b = (const float*)d_in[30];
    float* out = (float*)d_out;

    // ---- workspace layout (lifetime-overlapped), ~150 MB ----
    float* ws = (float*)d_ws;
    const size_t SEG = 8388608;                 // 8192*1024 floats = 32 MiB
    float* S1 = ws;                             // u_raw -> delta -> x2b/x3b (bf16)
    float* S2 = ws + SEG;                       // z_raw -> x1 | x3
    float* S3 = ws + 2*SEG;                     // u_act -> x2
    float* S4 = ws + 3*SEG;                     // xb -> uact_b -> ybuf_b -> kv
    float* xdbl = ws + 4*SEG;                   // 524288 f; later attn partials
    float* sm   = ws + 4*SEG + 524288;          // small scalars (16384 f)
    float* hseg = sm + 16384;                   // 2097152 f
    float* dsum = hseg + 2097152;               // 131072 f
    unsigned short* wb = (unsigned short*)(dsum + 131072);   // bf16 weights
    unsigned short* ipw_b = wb;                 // 1048576 us
    unsigned short* xpw_b = wb + 1048576;       // 65536 us
    unsigned short* opw_b = wb + 1114112;       // 524288 us
    unsigned short* kvw_b = wb + 1638400;       // 524288 us
    unsigned short* tew_b = wb + 2162688;       // 196608 us

    float* u_raw = S1;  float* deltab = S1;
    unsigned short* x2b = (unsigned short*)S1;            // first 8 MB of S1
    unsigned short* x3b = (unsigned short*)S1 + 4194304;  // next 8 MB of S1
    float* z_raw = S2;  float* x1 = S2;  float* x3 = S2 + 4194304;
    float* u_act = S3;  float* x2 = S3;
    unsigned short* xb      = (unsigned short*)S4;
    unsigned short* uact_b  = (unsigned short*)S4;
    unsigned short* ybuf_b  = (unsigned short*)S4;
    float* kv = S4;
    float* hidden = sm;        // 4096
    float* g  = sm + 4096;     // 2048
    float* qb = sm + 6144;     // 2048
    float* ob = sm + 8192;     // 2048
    float* ao = sm + 10240;    // 2048
    float* po  = xdbl;         // attn partial o (xdbl dead by then)
    float* pms = xdbl + 65536; // 1024 f

    dim3 blk(256);

    // 0) bf16 conversions + bias inits for tiny split-K GEMMs
    cvt_bf16<<<2048, blk, 0, stream>>>(x, xb, 4194304);
    cvt_bf16<<<512,  blk, 0, stream>>>(in_proj_w, ipw_b, 1048576);
    cvt_bf16<<<32,   blk, 0, stream>>>(x_proj_w, xpw_b, 65536);
    cvt_bf16<<<256,  blk, 0, stream>>>(out_proj_w, opw_b, 524288);
    cvt_bf16<<<256,  blk, 0, stream>>>(attn_in_w + 262144, kvw_b, 524288);
    cvt_tew<<<768,   blk, 0, stream>>>(te_w, tew_b);
    init_bias_all<<<10, blk, 0, stream>>>(fg_b1, fg_b2, attn_in_b, attn_out_b,
                                          hidden, g, qb, ao);

    // 1) in_proj: u and z halves
    gemm_bf16g<<<dim3(8,64), blk, 0, stream>>>(xb, ipw_b,          u_raw, nullptr, DD, DD, DD, DI);
    gemm_bf16g<<<dim3(8,64), blk, 0, stream>>>(xb, ipw_b + 524288, z_raw, nullptr, DD, DD, DD, DI);
    // 2) causal depthwise conv + silu (4 t per thread)
    dwconv_silu<<<(BL*DI/4)/256, blk, 0, stream>>>(u_raw, conv_w, conv_b, u_act, uact_b);
    // 3) x_dbl = u @ x_proj^T  (split-K 16, atomic accumulate)
    zero_f32<<<512, blk, 0, stream>>>(xdbl, BL*64);
    gemm_xdbl_sk<<<dim3(16, 32), blk, 0, stream>>>(uact_b, xpw_b, xdbl);
    // 4) delta = softplus(dt @ dt_proj^T + b)
    delta_gemm<<<dim3(8, 64), blk, 0, stream>>>(xdbl, dt_proj_w, dt_proj_b, deltab);
    // 5) selective scan, chunked
    ssm_pass1<<<dim3(4, NSEG, BB), blk, 0, stream>>>(deltab, u_act, xdbl, A_log, hseg, dsum);
    ssm_seg_scan<<<256, blk, 0, stream>>>(A_log, dsum, hseg);
    ssm_pass2<<<dim3(4, NSEG, BB), blk, 0, stream>>>(deltab, u_act, z_raw, xdbl, A_log, ssm_D, hseg, ybuf_b);
    // 6) out_proj
    gemm_bf16g<<<dim3(4,64), blk, 0, stream>>>(ybuf_b, opw_b, x1, nullptr, DI, DI, DI, DD);
    // 7) freq gate MLP (split-K atomics; hidden raw, gelu applied on layer2 A-load)
    tiny_sk<0><<<dim3(16, 8), blk, 0, stream>>>(freq,   fg_w1, hidden, 2*DD, DD, DD);
    tiny_sk<1><<<dim3(8, 16), blk, 0, stream>>>(hidden, fg_w2, g,      DD, 2*DD, 2*DD);
    // 8) ln1 * (1+sigmoid(g)) + residual -> ln2
    ln_gate_res_ln2<<<BL, blk, 0, stream>>>(x1, x, g, ln1w, ln1b, ln2w, ln2b, x2, x2b);
    // 9) attention
    tiny_sk<0><<<dim3(8, 8), blk, 0, stream>>>(freq, attn_in_w, qb, DD, DD, DD);
    gemm_bf16g<<<dim3(8,64), blk, 0, stream>>>(x2b, kvw_b, kv, attn_in_b + 512, DD, DD, DD, 2*DD);
    attn_part<<<dim3(ACH, BB*4), blk, 0, stream>>>(qb, kv, po, pms);
    attn_combine<<<BB*4, dim3(128), 0, stream>>>(po, pms, ob);
    tiny_sk<0><<<dim3(8, 8), blk, 0, stream>>>(ob, attn_out_w, ao, DD, DD, DD);
    // 10) ln3(x2 + attn_broadcast), also emits bf16 for the conv
    add_bcast_ln<<<BL, blk, 0, stream>>>(x2, ao, ln3w, ln3b, x3, x3b);
    // 11) temporal conv (MFMA, K-looped) + BN + gelu + residual
    teconv_mfma<<<dim3(LL/64, BB*4), blk, 0, stream>>>(x3b, tew_b, x3, te_b, bn_g, bn_b, bn_m, bn_v, out);
}